// Round 1
// baseline (1048.181 us; speedup 1.0000x reference)
//
#include <hip/hip_runtime.h>
#include <hip/hip_bf16.h>
#include <math.h>

// ---------------------------------------------------------------------------
// RankGNN: 3x GCN(128) + MLP(128->128->32->1) + graph-mean pool + pair sigmoid
// Round 1: correct fp32 implementation, CSR-based aggregation (atomic-free).
// ---------------------------------------------------------------------------

#define U 128

// ---------------- degree histogram ----------------
__global__ void k_deg(const int* __restrict__ dst, int* __restrict__ deg, int E) {
    int e = blockIdx.x * 256 + threadIdx.x;
    if (e < E) atomicAdd(&deg[dst[e]], 1);
}

__global__ void k_dinv(const int* __restrict__ deg, float* __restrict__ dinv, int N) {
    int i = blockIdx.x * 256 + threadIdx.x;
    if (i < N) dinv[i] = rsqrtf((float)deg[i] + 1.0f);
}

// ---------------- exclusive scan (rowptr) ----------------
// scan1: per-block (1024 elems) inclusive scan -> rowptr[1+i], block sums -> bsum
__global__ __launch_bounds__(256) void k_scan1(const int* __restrict__ deg,
                                               int* __restrict__ rowptr1,
                                               int* __restrict__ bsum, int N) {
    __shared__ int sc[256];
    int t = threadIdx.x, b = blockIdx.x;
    int base = b * 1024 + t * 4;
    int v[4];
    int s = 0;
    #pragma unroll
    for (int j = 0; j < 4; ++j) {
        int idx = base + j;
        int d = (idx < N) ? deg[idx] : 0;
        s += d;
        v[j] = s;
    }
    sc[t] = s;
    __syncthreads();
    for (int off = 1; off < 256; off <<= 1) {
        int x = (t >= off) ? sc[t - off] : 0;
        __syncthreads();
        sc[t] += x;
        __syncthreads();
    }
    int excl = sc[t] - s;
    #pragma unroll
    for (int j = 0; j < 4; ++j) {
        int idx = base + j;
        if (idx < N) rowptr1[idx] = v[j] + excl;
    }
    if (t == 255) bsum[b] = sc[255];
}

// scan2: single block, exclusive scan of block sums (nb <= 256)
__global__ __launch_bounds__(256) void k_scan2(int* __restrict__ bsum, int nb) {
    __shared__ int sc[256];
    int t = threadIdx.x;
    int v = (t < nb) ? bsum[t] : 0;
    sc[t] = v;
    __syncthreads();
    for (int off = 1; off < 256; off <<= 1) {
        int x = (t >= off) ? sc[t - off] : 0;
        __syncthreads();
        sc[t] += x;
        __syncthreads();
    }
    if (t < nb) bsum[t] = sc[t] - v;  // exclusive
}

// scan3: add block offsets; write rowptr[0] = 0
__global__ void k_scan3(int* __restrict__ rowptr, const int* __restrict__ boff, int N) {
    int i = blockIdx.x * 256 + threadIdx.x;
    if (i < N) rowptr[1 + i] += boff[i >> 10];
    if (i == 0) rowptr[0] = 0;
}

// ---------------- CSR scatter ----------------
__global__ void k_scatter(const int* __restrict__ src, const int* __restrict__ dst,
                          const float* __restrict__ dinv, const int* __restrict__ rowptr,
                          int* __restrict__ cursor, int* __restrict__ csr_src,
                          float* __restrict__ csr_w, int E) {
    int e = blockIdx.x * 256 + threadIdx.x;
    if (e < E) {
        int d = dst[e], s = src[e];
        int pos = atomicAdd(&cursor[d], 1);
        int o = rowptr[d] + pos;
        csr_src[o] = s;
        csr_w[o] = dinv[s] * dinv[d];
    }
}

// ---------------- per-graph node counts ----------------
__global__ void k_counts(const int* __restrict__ batch, int* __restrict__ cnt, int N) {
    int i = blockIdx.x * 256 + threadIdx.x;
    if (i < N) atomicAdd(&cnt[batch[i]], 1);
}

// ---------------- input GEMM: x (N x 9) @ W_in (9 x 128) -> B ----------------
__global__ void k_gemm_in(const float* __restrict__ x, const float* __restrict__ Wi,
                          float* __restrict__ B, int N) {
    int t = blockIdx.x * 256 + threadIdx.x;
    if (t < N * U) {
        int n = t >> 7, c = t & 127;
        const float* xr = x + n * 9;
        float acc = 0.0f;
        #pragma unroll
        for (int k = 0; k < 9; ++k) acc += xr[k] * Wi[k * U + c];
        B[t] = acc;
    }
}

// ---------------- 128x128 GEMM: B = A @ W (no bias; bias fused in agg) -------
// 64 rows x 128 cols per block of 256 threads; 8x4 register tile per thread.
#define KT 32
#define AS_STRIDE 68  // floats; 272 B rows keep float4 alignment

__global__ __launch_bounds__(256) void k_gemm128(const float* __restrict__ A,
                                                 const float* __restrict__ W,
                                                 float* __restrict__ B, int N) {
    __shared__ float As[KT * AS_STRIDE];  // transposed: As[k][r]
    __shared__ float Ws[KT * U];          // Ws[k][c]
    const int tid = threadIdx.x;
    const int ct = tid & 31;   // 32 col-threads * 4 cols = 128
    const int rt = tid >> 5;   // 8 row-threads * 8 rows = 64
    const int row0 = blockIdx.x * 64;
    float acc[8][4] = {};
    for (int kt = 0; kt < U; kt += KT) {
        #pragma unroll
        for (int j = 0; j < 8; ++j) {
            int e = tid + j * 256;
            int r = e >> 5, k = e & 31;
            int gr = row0 + r;
            As[k * AS_STRIDE + r] = (gr < N) ? A[gr * U + kt + k] : 0.0f;
        }
        #pragma unroll
        for (int j = 0; j < 16; ++j) {
            int e = tid + j * 256;
            int k = e >> 7, c = e & 127;
            Ws[k * U + c] = W[(kt + k) * U + c];
        }
        __syncthreads();
        #pragma unroll
        for (int k = 0; k < KT; ++k) {
            float4 w = *(const float4*)&Ws[k * U + ct * 4];
            float4 a0 = *(const float4*)&As[k * AS_STRIDE + rt * 8];
            float4 a1 = *(const float4*)&As[k * AS_STRIDE + rt * 8 + 4];
            float av[8] = {a0.x, a0.y, a0.z, a0.w, a1.x, a1.y, a1.z, a1.w};
            #pragma unroll
            for (int r = 0; r < 8; ++r) {
                acc[r][0] += av[r] * w.x;
                acc[r][1] += av[r] * w.y;
                acc[r][2] += av[r] * w.z;
                acc[r][3] += av[r] * w.w;
            }
        }
        __syncthreads();
    }
    #pragma unroll
    for (int r = 0; r < 8; ++r) {
        int gr = row0 + rt * 8 + r;
        if (gr < N) {
            float4 v = {acc[r][0], acc[r][1], acc[r][2], acc[r][3]};
            *(float4*)&B[gr * U + ct * 4] = v;
        }
    }
}

// ---------------- aggregation + self + bias + tanh ----------------
// one wave (64 lanes) per dst node, float2 per lane covers 128 feats
__global__ __launch_bounds__(256) void k_agg(const float* __restrict__ T,
                                             const int* __restrict__ rowptr,
                                             const int* __restrict__ csr_src,
                                             const float* __restrict__ csr_w,
                                             const float* __restrict__ dinv,
                                             const float* __restrict__ bias,
                                             float* __restrict__ Out, int N) {
    int node = blockIdx.x * 4 + (threadIdx.x >> 6);
    if (node >= N) return;
    int lane = threadIdx.x & 63;
    float ax = 0.0f, ay = 0.0f;
    int s = rowptr[node], e = rowptr[node + 1];
    for (int i = s; i < e; ++i) {
        int sr = csr_src[i];
        float w = csr_w[i];
        float2 v = *(const float2*)&T[sr * U + lane * 2];
        ax += v.x * w;
        ay += v.y * w;
    }
    float dv = dinv[node];
    float sn = dv * dv;
    float2 t = *(const float2*)&T[node * U + lane * 2];
    float2 bb = *(const float2*)&bias[lane * 2];
    float2 o;
    o.x = tanhf(ax + t.x * sn + bb.x);
    o.y = tanhf(ay + t.y * sn + bb.y);
    *(float2*)&Out[node * U + lane * 2] = o;
}

// ---------------- fused MLP head + pooled sum ----------------
// 16 nodes per block of 128 threads
__global__ __launch_bounds__(128) void k_mlp(const float* __restrict__ H,
                                             const float* __restrict__ Wf1, const float* __restrict__ bf1,
                                             const float* __restrict__ Wf2, const float* __restrict__ bf2,
                                             const float* __restrict__ Wf3, const float* __restrict__ bf3,
                                             const int* __restrict__ batch,
                                             float* __restrict__ util_sum, int N) {
    __shared__ float hs[16][U];
    __shared__ float h2[16][U];
    __shared__ float h3[16][32];
    int tid = threadIdx.x;
    int n0 = blockIdx.x * 16;
    #pragma unroll
    for (int i = 0; i < 16; ++i) {
        int n = n0 + i;
        hs[i][tid] = (n < N) ? H[n * U + tid] : 0.0f;
    }
    __syncthreads();
    {   // layer 1: 128 -> 128
        float acc[16] = {};
        float b = bf1[tid];
        for (int k = 0; k < U; ++k) {
            float w = Wf1[k * U + tid];
            #pragma unroll
            for (int i = 0; i < 16; ++i) acc[i] += hs[i][k] * w;
        }
        #pragma unroll
        for (int i = 0; i < 16; ++i) h2[i][tid] = tanhf(acc[i] + b);
    }
    __syncthreads();
    {   // layer 2: 128 -> 32
        int c = tid & 31, ig = tid >> 5;  // 4 node-groups x 4 nodes
        float acc[4] = {};
        float b = bf2[c];
        for (int k = 0; k < U; ++k) {
            float w = Wf2[k * 32 + c];
            #pragma unroll
            for (int j = 0; j < 4; ++j) acc[j] += h2[ig * 4 + j][k] * w;
        }
        #pragma unroll
        for (int j = 0; j < 4; ++j) h3[ig * 4 + j][c] = tanhf(acc[j] + b);
    }
    __syncthreads();
    if (tid < 16) {  // layer 3: 32 -> 1 + pooled atomic
        int n = n0 + tid;
        if (n < N) {
            float s = bf3[0];
            #pragma unroll
            for (int k = 0; k < 32; ++k) s += h3[tid][k] * Wf3[k];
            atomicAdd(&util_sum[batch[n]], s);
        }
    }
}

// ---------------- util = sum / max(cnt,1) ----------------
__global__ void k_util(const float* __restrict__ util_sum, const int* __restrict__ cnt,
                       float* __restrict__ out_util, int G) {
    int g = blockIdx.x * 256 + threadIdx.x;
    if (g < G) {
        float c = (float)cnt[g];
        out_util[g] = util_sum[g] / fmaxf(c, 1.0f);
    }
}

// ---------------- pair sigmoid ----------------
__global__ void k_pairs(const float* __restrict__ u, const int* __restrict__ ia,
                        const int* __restrict__ ib, float* __restrict__ out, int P) {
    int p = blockIdx.x * 256 + threadIdx.x;
    if (p < P) {
        float d = u[ib[p]] - u[ia[p]];
        out[p] = 1.0f / (1.0f + expf(-d));
    }
}

extern "C" void kernel_launch(void* const* d_in, const int* in_sizes, int n_in,
                              void* d_out, int out_size, void* d_ws, size_t ws_size,
                              hipStream_t stream) {
    const float* x     = (const float*)d_in[0];
    const int*   eidx  = (const int*)d_in[1];
    const int*   batch = (const int*)d_in[2];
    const int*   idx_a = (const int*)d_in[3];
    const int*   idx_b = (const int*)d_in[4];
    const float* W_in  = (const float*)d_in[5];
    const float* b_in  = (const float*)d_in[6];
    const float* W1    = (const float*)d_in[7];
    const float* b1    = (const float*)d_in[8];
    const float* W2    = (const float*)d_in[9];
    const float* b2    = (const float*)d_in[10];
    const float* Wf1   = (const float*)d_in[11];
    const float* bf1   = (const float*)d_in[12];
    const float* Wf2   = (const float*)d_in[13];
    const float* bf2   = (const float*)d_in[14];
    const float* Wf3   = (const float*)d_in[15];
    const float* bf3   = (const float*)d_in[16];
    float* out = (float*)d_out;

    const int N = in_sizes[0] / 9;
    const int E = in_sizes[1] / 2;
    const int P = in_sizes[3];
    const int G = out_size - P;

    const int* src = eidx;
    const int* dst = eidx + E;

    // ---- workspace carve-out ----
    char* ws = (char*)d_ws;
    size_t off = 0;
    auto take = [&](size_t bytes) -> void* {
        void* p = ws + off;
        off = (off + bytes + 255) & ~(size_t)255;
        return p;
    };
    int*   deg      = (int*)  take((size_t)N * 4);
    float* dinv     = (float*)take((size_t)N * 4);
    int*   rowptr   = (int*)  take((size_t)(N + 1) * 4);
    int*   bsum     = (int*)  take(256 * 4);
    int*   cursor   = (int*)  take((size_t)N * 4);
    int*   csr_src  = (int*)  take((size_t)E * 4);
    float* csr_w    = (float*)take((size_t)E * 4);
    float* bufA     = (float*)take((size_t)N * U * 4);
    float* bufB     = (float*)take((size_t)N * U * 4);
    float* util_sum = (float*)take((size_t)G * 4);
    int*   cnt      = (int*)  take((size_t)G * 4);
    (void)ws_size;

    hipMemsetAsync(deg, 0, (size_t)N * 4, stream);
    hipMemsetAsync(cursor, 0, (size_t)N * 4, stream);
    hipMemsetAsync(util_sum, 0, (size_t)G * 4, stream);
    hipMemsetAsync(cnt, 0, (size_t)G * 4, stream);

    const int nb = (N + 1023) / 1024;  // scan blocks

    // ---- CSR build ----
    k_deg<<<(E + 255) / 256, 256, 0, stream>>>(dst, deg, E);
    k_dinv<<<(N + 255) / 256, 256, 0, stream>>>(deg, dinv, N);
    k_scan1<<<nb, 256, 0, stream>>>(deg, rowptr + 1, bsum, N);
    k_scan2<<<1, 256, 0, stream>>>(bsum, nb);
    k_scan3<<<(N + 255) / 256, 256, 0, stream>>>(rowptr, bsum, N);
    k_scatter<<<(E + 255) / 256, 256, 0, stream>>>(src, dst, dinv, rowptr, cursor,
                                                   csr_src, csr_w, E);
    k_counts<<<(N + 255) / 256, 256, 0, stream>>>(batch, cnt, N);

    const int aggGrid  = (N + 3) / 4;
    const int gemmGrid = (N + 63) / 64;

    // ---- GCN layer 1 (9 -> 128) ----
    k_gemm_in<<<((size_t)N * U + 255) / 256, 256, 0, stream>>>(x, W_in, bufB, N);
    k_agg<<<aggGrid, 256, 0, stream>>>(bufB, rowptr, csr_src, csr_w, dinv, b_in, bufA, N);
    // ---- GCN layer 2 ----
    k_gemm128<<<gemmGrid, 256, 0, stream>>>(bufA, W1, bufB, N);
    k_agg<<<aggGrid, 256, 0, stream>>>(bufB, rowptr, csr_src, csr_w, dinv, b1, bufA, N);
    // ---- GCN layer 3 ----
    k_gemm128<<<gemmGrid, 256, 0, stream>>>(bufA, W2, bufB, N);
    k_agg<<<aggGrid, 256, 0, stream>>>(bufB, rowptr, csr_src, csr_w, dinv, b2, bufA, N);

    // ---- MLP head + pooled sums ----
    k_mlp<<<(N + 15) / 16, 128, 0, stream>>>(bufA, Wf1, bf1, Wf2, bf2, Wf3, bf3,
                                             batch, util_sum, N);

    // ---- util + pairs ----
    k_util<<<(G + 255) / 256, 256, 0, stream>>>(util_sum, cnt, out + P, G);
    k_pairs<<<(P + 255) / 256, 256, 0, stream>>>(out + P, idx_a, idx_b, out, P);
}

// Round 2
// 856.492 us; speedup vs baseline: 1.2238x; 1.2238x over previous
//
#include <hip/hip_runtime.h>
#include <hip/hip_bf16.h>
#include <math.h>

// ---------------------------------------------------------------------------
// RankGNN R2: layer-1 agg moved before GEMM (9-wide gather), bf16 neighbor
// tables for layers 2/3 (halved gather traffic), widened MLP head tiles.
// ---------------------------------------------------------------------------

#define U 128

__device__ __forceinline__ unsigned short f2bf(float f) {
    unsigned u = __float_as_uint(f);
    unsigned r = (u + 0x7fffu + ((u >> 16) & 1u)) >> 16;  // RNE
    return (unsigned short)r;
}

// ---------------- degree histogram ----------------
__global__ void k_deg(const int* __restrict__ dst, int* __restrict__ deg, int E) {
    int e = blockIdx.x * 256 + threadIdx.x;
    if (e < E) atomicAdd(&deg[dst[e]], 1);
}

__global__ void k_dinv(const int* __restrict__ deg, float* __restrict__ dinv, int N) {
    int i = blockIdx.x * 256 + threadIdx.x;
    if (i < N) dinv[i] = rsqrtf((float)deg[i] + 1.0f);
}

// ---------------- exclusive scan (rowptr) ----------------
__global__ __launch_bounds__(256) void k_scan1(const int* __restrict__ deg,
                                               int* __restrict__ rowptr1,
                                               int* __restrict__ bsum, int N) {
    __shared__ int sc[256];
    int t = threadIdx.x, b = blockIdx.x;
    int base = b * 1024 + t * 4;
    int v[4];
    int s = 0;
    #pragma unroll
    for (int j = 0; j < 4; ++j) {
        int idx = base + j;
        int d = (idx < N) ? deg[idx] : 0;
        s += d;
        v[j] = s;
    }
    sc[t] = s;
    __syncthreads();
    for (int off = 1; off < 256; off <<= 1) {
        int x = (t >= off) ? sc[t - off] : 0;
        __syncthreads();
        sc[t] += x;
        __syncthreads();
    }
    int excl = sc[t] - s;
    #pragma unroll
    for (int j = 0; j < 4; ++j) {
        int idx = base + j;
        if (idx < N) rowptr1[idx] = v[j] + excl;
    }
    if (t == 255) bsum[b] = sc[255];
}

__global__ __launch_bounds__(256) void k_scan2(int* __restrict__ bsum, int nb) {
    __shared__ int sc[256];
    int t = threadIdx.x;
    int v = (t < nb) ? bsum[t] : 0;
    sc[t] = v;
    __syncthreads();
    for (int off = 1; off < 256; off <<= 1) {
        int x = (t >= off) ? sc[t - off] : 0;
        __syncthreads();
        sc[t] += x;
        __syncthreads();
    }
    if (t < nb) bsum[t] = sc[t] - v;  // exclusive
}

__global__ void k_scan3(int* __restrict__ rowptr, const int* __restrict__ boff, int N) {
    int i = blockIdx.x * 256 + threadIdx.x;
    if (i < N) rowptr[1 + i] += boff[i >> 10];
    if (i == 0) rowptr[0] = 0;
}

// ---------------- CSR scatter ----------------
__global__ void k_scatter(const int* __restrict__ src, const int* __restrict__ dst,
                          const float* __restrict__ dinv, const int* __restrict__ rowptr,
                          int* __restrict__ cursor, int* __restrict__ csr_src,
                          float* __restrict__ csr_w, int E) {
    int e = blockIdx.x * 256 + threadIdx.x;
    if (e < E) {
        int d = dst[e], s = src[e];
        int pos = atomicAdd(&cursor[d], 1);
        int o = rowptr[d] + pos;
        csr_src[o] = s;
        csr_w[o] = dinv[s] * dinv[d];
    }
}

// ---------------- per-graph node counts ----------------
__global__ void k_counts(const int* __restrict__ batch, int* __restrict__ cnt, int N) {
    int i = blockIdx.x * 256 + threadIdx.x;
    if (i < N) atomicAdd(&cnt[batch[i]], 1);
}

// ---------------- layer-1: aggregate raw x (N x 9) ----------------
// xa[n][c] = sum_edges w * x[src][c] + self_norm * x[n][c]
__global__ __launch_bounds__(256) void k_aggx(const float* __restrict__ x,
                                              const int* __restrict__ rowptr,
                                              const int* __restrict__ csr_src,
                                              const float* __restrict__ csr_w,
                                              const float* __restrict__ dinv,
                                              float* __restrict__ xa, int N) {
    int node = blockIdx.x * 16 + (threadIdx.x >> 4);
    if (node >= N) return;
    int lane = threadIdx.x & 15;
    bool act = lane < 9;
    int s = rowptr[node], e = rowptr[node + 1];
    float acc = 0.0f;
    for (int i = s; i < e; ++i) {
        int sr = csr_src[i];
        float w = csr_w[i];
        if (act) acc += x[sr * 9 + lane] * w;
    }
    if (act) {
        float dv = dinv[node];
        xa[node * 9 + lane] = acc + dv * dv * x[node * 9 + lane];
    }
}

// ---------------- layer-1 GEMM: tanh(xa @ W_in + b) -> T (fp32) -------------
__global__ void k_gemm_in9(const float* __restrict__ xa, const float* __restrict__ Wi,
                           const float* __restrict__ bi, float* __restrict__ T, int N) {
    int t = blockIdx.x * 256 + threadIdx.x;
    if (t < N * U) {
        int n = t >> 7, c = t & 127;
        const float* xr = xa + n * 9;
        float acc = bi[c];
        #pragma unroll
        for (int k = 0; k < 9; ++k) acc += xr[k] * Wi[k * U + c];
        T[t] = tanhf(acc);
    }
}

// ---------------- 128x128 GEMM: Tb(bf16) = A @ W ----------------
#define KT 32
#define AS_STRIDE 68

__global__ __launch_bounds__(256) void k_gemm128(const float* __restrict__ A,
                                                 const float* __restrict__ W,
                                                 unsigned short* __restrict__ Tb, int N) {
    __shared__ float As[KT * AS_STRIDE];  // transposed: As[k][r]
    __shared__ float Ws[KT * U];          // Ws[k][c]
    const int tid = threadIdx.x;
    const int ct = tid & 31;
    const int rt = tid >> 5;
    const int row0 = blockIdx.x * 64;
    float acc[8][4] = {};
    for (int kt = 0; kt < U; kt += KT) {
        #pragma unroll
        for (int j = 0; j < 8; ++j) {
            int e = tid + j * 256;
            int r = e >> 5, k = e & 31;
            int gr = row0 + r;
            As[k * AS_STRIDE + r] = (gr < N) ? A[gr * U + kt + k] : 0.0f;
        }
        #pragma unroll
        for (int j = 0; j < 16; ++j) {
            int e = tid + j * 256;
            int k = e >> 7, c = e & 127;
            Ws[k * U + c] = W[(kt + k) * U + c];
        }
        __syncthreads();
        #pragma unroll
        for (int k = 0; k < KT; ++k) {
            float4 w = *(const float4*)&Ws[k * U + ct * 4];
            float4 a0 = *(const float4*)&As[k * AS_STRIDE + rt * 8];
            float4 a1 = *(const float4*)&As[k * AS_STRIDE + rt * 8 + 4];
            float av[8] = {a0.x, a0.y, a0.z, a0.w, a1.x, a1.y, a1.z, a1.w};
            #pragma unroll
            for (int r = 0; r < 8; ++r) {
                acc[r][0] += av[r] * w.x;
                acc[r][1] += av[r] * w.y;
                acc[r][2] += av[r] * w.z;
                acc[r][3] += av[r] * w.w;
            }
        }
        __syncthreads();
    }
    #pragma unroll
    for (int r = 0; r < 8; ++r) {
        int gr = row0 + rt * 8 + r;
        if (gr < N) {
            unsigned a01 = (unsigned)f2bf(acc[r][0]) | ((unsigned)f2bf(acc[r][1]) << 16);
            unsigned a23 = (unsigned)f2bf(acc[r][2]) | ((unsigned)f2bf(acc[r][3]) << 16);
            *(uint2*)&Tb[gr * U + ct * 4] = make_uint2(a01, a23);
        }
    }
}

// ---------------- aggregation (bf16 table) + self + bias + tanh -------------
// one wave per dst node; lane covers 2 cols via one 4B load (2x bf16)
__global__ __launch_bounds__(256) void k_aggb(const unsigned short* __restrict__ Tb,
                                              const int* __restrict__ rowptr,
                                              const int* __restrict__ csr_src,
                                              const float* __restrict__ csr_w,
                                              const float* __restrict__ dinv,
                                              const float* __restrict__ bias,
                                              float* __restrict__ Out, int N) {
    int node = blockIdx.x * 4 + (threadIdx.x >> 6);
    if (node >= N) return;
    int lane = threadIdx.x & 63;
    const unsigned* T32 = (const unsigned*)Tb;
    float ax = 0.0f, ay = 0.0f;
    int s = rowptr[node], e = rowptr[node + 1];
    int i = s;
    for (; i + 2 <= e; i += 2) {
        int s0 = csr_src[i], s1 = csr_src[i + 1];
        float w0 = csr_w[i], w1 = csr_w[i + 1];
        unsigned u0 = T32[s0 * 64 + lane];
        unsigned u1 = T32[s1 * 64 + lane];
        ax += __uint_as_float(u0 << 16) * w0 + __uint_as_float(u1 << 16) * w1;
        ay += __uint_as_float(u0 & 0xffff0000u) * w0 + __uint_as_float(u1 & 0xffff0000u) * w1;
    }
    if (i < e) {
        int s0 = csr_src[i];
        float w0 = csr_w[i];
        unsigned u0 = T32[s0 * 64 + lane];
        ax += __uint_as_float(u0 << 16) * w0;
        ay += __uint_as_float(u0 & 0xffff0000u) * w0;
    }
    float dv = dinv[node];
    float sn = dv * dv;
    unsigned su = T32[node * 64 + lane];
    float2 bb = *(const float2*)&bias[lane * 2];
    float ox = tanhf(ax + __uint_as_float(su << 16) * sn + bb.x);
    float oy = tanhf(ay + __uint_as_float(su & 0xffff0000u) * sn + bb.y);
    *(float2*)&Out[node * U + lane * 2] = make_float2(ox, oy);
}

// ---------------- fused MLP head + pooled sum (32 nodes/block) --------------
__global__ __launch_bounds__(128) void k_mlp(const float* __restrict__ H,
                                             const float* __restrict__ Wf1, const float* __restrict__ bf1,
                                             const float* __restrict__ Wf2, const float* __restrict__ bf2,
                                             const float* __restrict__ Wf3, const float* __restrict__ bf3,
                                             const int* __restrict__ batch,
                                             float* __restrict__ util_sum, int N) {
    __shared__ float hs[32][U];
    __shared__ float h2[32][U];
    __shared__ float h3[32][32];
    int tid = threadIdx.x;
    int n0 = blockIdx.x * 32;
    #pragma unroll
    for (int i = 0; i < 32; ++i) {
        int n = n0 + i;
        hs[i][tid] = (n < N) ? H[n * U + tid] : 0.0f;
    }
    __syncthreads();
    {   // layer 1: 128 -> 128
        float acc[32] = {};
        float b = bf1[tid];
        for (int k = 0; k < U; k += 4) {
            float w0 = Wf1[k * U + tid];
            float w1 = Wf1[(k + 1) * U + tid];
            float w2 = Wf1[(k + 2) * U + tid];
            float w3 = Wf1[(k + 3) * U + tid];
            #pragma unroll
            for (int i = 0; i < 32; ++i) {
                float4 h = *(const float4*)&hs[i][k];
                acc[i] += h.x * w0 + h.y * w1 + h.z * w2 + h.w * w3;
            }
        }
        #pragma unroll
        for (int i = 0; i < 32; ++i) h2[i][tid] = tanhf(acc[i] + b);
    }
    __syncthreads();
    {   // layer 2: 128 -> 32; 4 col-groups x 8 nodes
        int c = tid & 31, ig = tid >> 5;
        float a2[8] = {};
        float bb = bf2[c];
        for (int k = 0; k < U; k += 4) {
            float w0 = Wf2[k * 32 + c];
            float w1 = Wf2[(k + 1) * 32 + c];
            float w2 = Wf2[(k + 2) * 32 + c];
            float w3 = Wf2[(k + 3) * 32 + c];
            #pragma unroll
            for (int j = 0; j < 8; ++j) {
                float4 h = *(const float4*)&h2[ig * 8 + j][k];
                a2[j] += h.x * w0 + h.y * w1 + h.z * w2 + h.w * w3;
            }
        }
        #pragma unroll
        for (int j = 0; j < 8; ++j) h3[ig * 8 + j][c] = tanhf(a2[j] + bb);
    }
    __syncthreads();
    if (tid < 32) {  // layer 3: 32 -> 1 + pooled atomic
        int n = n0 + tid;
        if (n < N) {
            float s = bf3[0];
            #pragma unroll
            for (int k = 0; k < 32; ++k) s += h3[tid][k] * Wf3[k];
            atomicAdd(&util_sum[batch[n]], s);
        }
    }
}

// ---------------- util = sum / max(cnt,1) ----------------
__global__ void k_util(const float* __restrict__ util_sum, const int* __restrict__ cnt,
                       float* __restrict__ out_util, int G) {
    int g = blockIdx.x * 256 + threadIdx.x;
    if (g < G) {
        float c = (float)cnt[g];
        out_util[g] = util_sum[g] / fmaxf(c, 1.0f);
    }
}

// ---------------- pair sigmoid ----------------
__global__ void k_pairs(const float* __restrict__ u, const int* __restrict__ ia,
                        const int* __restrict__ ib, float* __restrict__ out, int P) {
    int p = blockIdx.x * 256 + threadIdx.x;
    if (p < P) {
        float d = u[ib[p]] - u[ia[p]];
        out[p] = 1.0f / (1.0f + expf(-d));
    }
}

extern "C" void kernel_launch(void* const* d_in, const int* in_sizes, int n_in,
                              void* d_out, int out_size, void* d_ws, size_t ws_size,
                              hipStream_t stream) {
    const float* x     = (const float*)d_in[0];
    const int*   eidx  = (const int*)d_in[1];
    const int*   batch = (const int*)d_in[2];
    const int*   idx_a = (const int*)d_in[3];
    const int*   idx_b = (const int*)d_in[4];
    const float* W_in  = (const float*)d_in[5];
    const float* b_in  = (const float*)d_in[6];
    const float* W1    = (const float*)d_in[7];
    const float* b1    = (const float*)d_in[8];
    const float* W2    = (const float*)d_in[9];
    const float* b2    = (const float*)d_in[10];
    const float* Wf1   = (const float*)d_in[11];
    const float* bf1   = (const float*)d_in[12];
    const float* Wf2   = (const float*)d_in[13];
    const float* bf2   = (const float*)d_in[14];
    const float* Wf3   = (const float*)d_in[15];
    const float* bf3   = (const float*)d_in[16];
    float* out = (float*)d_out;

    const int N = in_sizes[0] / 9;
    const int E = in_sizes[1] / 2;
    const int P = in_sizes[3];
    const int G = out_size - P;

    const int* src = eidx;
    const int* dst = eidx + E;

    // ---- workspace carve-out ----
    char* ws = (char*)d_ws;
    size_t off = 0;
    auto take = [&](size_t bytes) -> void* {
        void* p = ws + off;
        off = (off + bytes + 255) & ~(size_t)255;
        return p;
    };
    int*   deg      = (int*)  take((size_t)N * 4);
    float* dinv     = (float*)take((size_t)N * 4);
    int*   rowptr   = (int*)  take((size_t)(N + 1) * 4);
    int*   bsum     = (int*)  take(256 * 4);
    int*   cursor   = (int*)  take((size_t)N * 4);
    int*   csr_src  = (int*)  take((size_t)E * 4);
    float* csr_w    = (float*)take((size_t)E * 4);
    float* xa       = (float*)take((size_t)N * 9 * 4);
    float* bufA     = (float*)take((size_t)N * U * 4);      // fp32 activations
    unsigned short* Tb = (unsigned short*)take((size_t)N * U * 2);  // bf16 table
    float* util_sum = (float*)take((size_t)G * 4);
    int*   cnt      = (int*)  take((size_t)G * 4);
    (void)ws_size;

    hipMemsetAsync(deg, 0, (size_t)N * 4, stream);
    hipMemsetAsync(cursor, 0, (size_t)N * 4, stream);
    hipMemsetAsync(util_sum, 0, (size_t)G * 4, stream);
    hipMemsetAsync(cnt, 0, (size_t)G * 4, stream);

    const int nb = (N + 1023) / 1024;

    // ---- CSR build ----
    k_deg<<<(E + 255) / 256, 256, 0, stream>>>(dst, deg, E);
    k_dinv<<<(N + 255) / 256, 256, 0, stream>>>(deg, dinv, N);
    k_scan1<<<nb, 256, 0, stream>>>(deg, rowptr + 1, bsum, N);
    k_scan2<<<1, 256, 0, stream>>>(bsum, nb);
    k_scan3<<<(N + 255) / 256, 256, 0, stream>>>(rowptr, bsum, N);
    k_scatter<<<(E + 255) / 256, 256, 0, stream>>>(src, dst, dinv, rowptr, cursor,
                                                   csr_src, csr_w, E);
    k_counts<<<(N + 255) / 256, 256, 0, stream>>>(batch, cnt, N);

    const int aggGrid  = (N + 3) / 4;
    const int gemmGrid = (N + 63) / 64;

    // ---- GCN layer 1: aggregate x first (9-wide), then GEMM+bias+tanh ----
    k_aggx<<<(N + 15) / 16, 256, 0, stream>>>(x, rowptr, csr_src, csr_w, dinv, xa, N);
    k_gemm_in9<<<((size_t)N * U + 255) / 256, 256, 0, stream>>>(xa, W_in, b_in, bufA, N);

    // ---- GCN layer 2 ----
    k_gemm128<<<gemmGrid, 256, 0, stream>>>(bufA, W1, Tb, N);
    k_aggb<<<aggGrid, 256, 0, stream>>>(Tb, rowptr, csr_src, csr_w, dinv, b1, bufA, N);
    // ---- GCN layer 3 ----
    k_gemm128<<<gemmGrid, 256, 0, stream>>>(bufA, W2, Tb, N);
    k_aggb<<<aggGrid, 256, 0, stream>>>(Tb, rowptr, csr_src, csr_w, dinv, b2, bufA, N);

    // ---- MLP head + pooled sums ----
    k_mlp<<<(N + 31) / 32, 128, 0, stream>>>(bufA, Wf1, bf1, Wf2, bf2, Wf3, bf3,
                                             batch, util_sum, N);

    // ---- util + pairs ----
    k_util<<<(G + 255) / 256, 256, 0, stream>>>(util_sum, cnt, out + P, G);
    k_pairs<<<(P + 255) / 256, 256, 0, stream>>>(out + P, idx_a, idx_b, out, P);
}

// Round 3
// 753.652 us; speedup vs baseline: 1.3908x; 1.1365x over previous
//
#include <hip/hip_runtime.h>
#include <hip/hip_bf16.h>
#include <math.h>

// ---------------------------------------------------------------------------
// RankGNN R3: MFMA bf16 for layer GEMMs + MLP head; bf16 activations
// end-to-end; weights pre-transposed to bf16 [n][k] tables (L1-resident
// b-frag loads, no W staging in LDS).
// ---------------------------------------------------------------------------

#define U 128
#define LDA 136  // LDS row stride in bf16 elems (128 + 8 pad): 2-way banks = free

typedef __attribute__((ext_vector_type(8))) short bf16x8;
typedef __attribute__((ext_vector_type(4))) float f32x4;

__device__ __forceinline__ unsigned short f2bf(float f) {
    unsigned u = __float_as_uint(f);
    unsigned r = (u + 0x7fffu + ((u >> 16) & 1u)) >> 16;  // RNE
    return (unsigned short)r;
}

// ---------------- degree histogram ----------------
__global__ void k_deg(const int* __restrict__ dst, int* __restrict__ deg, int E) {
    int e = blockIdx.x * 256 + threadIdx.x;
    if (e < E) atomicAdd(&deg[dst[e]], 1);
}

__global__ void k_dinv(const int* __restrict__ deg, float* __restrict__ dinv, int N) {
    int i = blockIdx.x * 256 + threadIdx.x;
    if (i < N) dinv[i] = rsqrtf((float)deg[i] + 1.0f);
}

// ---------------- exclusive scan (rowptr) ----------------
__global__ __launch_bounds__(256) void k_scan1(const int* __restrict__ deg,
                                               int* __restrict__ rowptr1,
                                               int* __restrict__ bsum, int N) {
    __shared__ int sc[256];
    int t = threadIdx.x, b = blockIdx.x;
    int base = b * 1024 + t * 4;
    int v[4];
    int s = 0;
    #pragma unroll
    for (int j = 0; j < 4; ++j) {
        int idx = base + j;
        int d = (idx < N) ? deg[idx] : 0;
        s += d;
        v[j] = s;
    }
    sc[t] = s;
    __syncthreads();
    for (int off = 1; off < 256; off <<= 1) {
        int x = (t >= off) ? sc[t - off] : 0;
        __syncthreads();
        sc[t] += x;
        __syncthreads();
    }
    int excl = sc[t] - s;
    #pragma unroll
    for (int j = 0; j < 4; ++j) {
        int idx = base + j;
        if (idx < N) rowptr1[idx] = v[j] + excl;
    }
    if (t == 255) bsum[b] = sc[255];
}

__global__ __launch_bounds__(256) void k_scan2(int* __restrict__ bsum, int nb) {
    __shared__ int sc[256];
    int t = threadIdx.x;
    int v = (t < nb) ? bsum[t] : 0;
    sc[t] = v;
    __syncthreads();
    for (int off = 1; off < 256; off <<= 1) {
        int x = (t >= off) ? sc[t - off] : 0;
        __syncthreads();
        sc[t] += x;
        __syncthreads();
    }
    if (t < nb) bsum[t] = sc[t] - v;  // exclusive
}

__global__ void k_scan3(int* __restrict__ rowptr, const int* __restrict__ boff, int N) {
    int i = blockIdx.x * 256 + threadIdx.x;
    if (i < N) rowptr[1 + i] += boff[i >> 10];
    if (i == 0) rowptr[0] = 0;
}

// ---------------- CSR scatter ----------------
__global__ void k_scatter(const int* __restrict__ src, const int* __restrict__ dst,
                          const float* __restrict__ dinv, const int* __restrict__ rowptr,
                          int* __restrict__ cursor, int* __restrict__ csr_src,
                          float* __restrict__ csr_w, int E) {
    int e = blockIdx.x * 256 + threadIdx.x;
    if (e < E) {
        int d = dst[e], s = src[e];
        int pos = atomicAdd(&cursor[d], 1);
        int o = rowptr[d] + pos;
        csr_src[o] = s;
        csr_w[o] = dinv[s] * dinv[d];
    }
}

// ---------------- per-graph node counts ----------------
__global__ void k_counts(const int* __restrict__ batch, int* __restrict__ cnt, int N) {
    int i = blockIdx.x * 256 + threadIdx.x;
    if (i < N) atomicAdd(&cnt[batch[i]], 1);
}

// ---------------- weight prep: transpose + bf16 ----------------
// W1t/W2t/Wf1t: [n=128][k=128]; Wf2t: [n=32][k=128]
__global__ void k_prep_w(const float* __restrict__ W1, const float* __restrict__ W2,
                         const float* __restrict__ Wf1, const float* __restrict__ Wf2,
                         unsigned short* __restrict__ W1t, unsigned short* __restrict__ W2t,
                         unsigned short* __restrict__ Wf1t, unsigned short* __restrict__ Wf2t) {
    int t = blockIdx.x * 256 + threadIdx.x;
    if (t < 16384) {
        int n = t >> 7, k = t & 127;
        W1t[n * 128 + k] = f2bf(W1[k * 128 + n]);
    } else if (t < 32768) {
        int i = t - 16384, n = i >> 7, k = i & 127;
        W2t[n * 128 + k] = f2bf(W2[k * 128 + n]);
    } else if (t < 49152) {
        int i = t - 32768, n = i >> 7, k = i & 127;
        Wf1t[n * 128 + k] = f2bf(Wf1[k * 128 + n]);
    } else if (t < 53248) {
        int i = t - 49152, n = i >> 7, k = i & 127;
        Wf2t[n * 128 + k] = f2bf(Wf2[k * 32 + n]);
    }
}

// ---------------- layer-1: aggregate raw x (N x 9) ----------------
__global__ __launch_bounds__(256) void k_aggx(const float* __restrict__ x,
                                              const int* __restrict__ rowptr,
                                              const int* __restrict__ csr_src,
                                              const float* __restrict__ csr_w,
                                              const float* __restrict__ dinv,
                                              float* __restrict__ xa, int N) {
    int node = blockIdx.x * 16 + (threadIdx.x >> 4);
    if (node >= N) return;
    int lane = threadIdx.x & 15;
    bool act = lane < 9;
    int s = rowptr[node], e = rowptr[node + 1];
    float acc = 0.0f;
    for (int i = s; i < e; ++i) {
        int sr = csr_src[i];
        float w = csr_w[i];
        if (act) acc += x[sr * 9 + lane] * w;
    }
    if (act) {
        float dv = dinv[node];
        xa[node * 9 + lane] = acc + dv * dv * x[node * 9 + lane];
    }
}

// ---------------- layer-1 GEMM: bf16(tanh(xa @ W_in + b)) ----------------
__global__ void k_gemm_in9(const float* __restrict__ xa, const float* __restrict__ Wi,
                           const float* __restrict__ bi, unsigned short* __restrict__ T,
                           int N) {
    int t = blockIdx.x * 256 + threadIdx.x;
    if (t < N * U) {
        int n = t >> 7, c = t & 127;
        const float* xr = xa + n * 9;
        float acc = bi[c];
        #pragma unroll
        for (int k = 0; k < 9; ++k) acc += xr[k] * Wi[k * U + c];
        T[t] = f2bf(tanhf(acc));
    }
}

// ---------------- MFMA GEMM: Out(bf16) = A(bf16) @ Wt^T ----------------
// 64 rows x 128 cols per block (4 waves); b-frags straight from global Wt
__global__ __launch_bounds__(256) void k_gemm_mfma(const unsigned short* __restrict__ A,
                                                   const unsigned short* __restrict__ Wt,
                                                   unsigned short* __restrict__ Out, int N) {
    __shared__ unsigned short As[64 * LDA];
    const int tid = threadIdx.x;
    const int row0 = blockIdx.x * 64;
    const unsigned* A32 = (const unsigned*)A;
    #pragma unroll
    for (int j = 0; j < 16; ++j) {
        int idx = tid + j * 256;
        int r = idx >> 6, kd = idx & 63;
        unsigned v = (row0 + r < N) ? A32[(size_t)(row0 + r) * 64 + kd] : 0u;
        *(unsigned*)&As[r * LDA + kd * 2] = v;
    }
    __syncthreads();
    const int wave = tid >> 6, lane = tid & 63;
    const int m16 = lane & 15, q = lane >> 4;
    f32x4 acc[8];
    #pragma unroll
    for (int t = 0; t < 8; ++t) acc[t] = (f32x4){0.f, 0.f, 0.f, 0.f};
    const unsigned short* arow = &As[(wave * 16 + m16) * LDA + q * 8];
    #pragma unroll
    for (int kc = 0; kc < 4; ++kc) {
        bf16x8 af = *(const bf16x8*)(arow + kc * 32);
        #pragma unroll
        for (int t = 0; t < 8; ++t) {
            bf16x8 bfr = *(const bf16x8*)(Wt + ((t * 16 + m16) * 128 + kc * 32 + q * 8));
            acc[t] = __builtin_amdgcn_mfma_f32_16x16x32_bf16(af, bfr, acc[t], 0, 0, 0);
        }
    }
    #pragma unroll
    for (int t = 0; t < 8; ++t) {
        #pragma unroll
        for (int r = 0; r < 4; ++r) {
            int gr = row0 + wave * 16 + q * 4 + r;
            if (gr < N) Out[(size_t)gr * U + t * 16 + m16] = f2bf(acc[t][r]);
        }
    }
}

// ---------------- aggregation (bf16 table) -> bf16 activations --------------
__global__ __launch_bounds__(256) void k_aggb(const unsigned short* __restrict__ Tb,
                                              const int* __restrict__ rowptr,
                                              const int* __restrict__ csr_src,
                                              const float* __restrict__ csr_w,
                                              const float* __restrict__ dinv,
                                              const float* __restrict__ bias,
                                              unsigned short* __restrict__ Out, int N) {
    int node = blockIdx.x * 4 + (threadIdx.x >> 6);
    if (node >= N) return;
    int lane = threadIdx.x & 63;
    const unsigned* T32 = (const unsigned*)Tb;
    float ax = 0.0f, ay = 0.0f;
    int s = rowptr[node], e = rowptr[node + 1];
    int i = s;
    for (; i + 2 <= e; i += 2) {
        int s0 = csr_src[i], s1 = csr_src[i + 1];
        float w0 = csr_w[i], w1 = csr_w[i + 1];
        unsigned u0 = T32[s0 * 64 + lane];
        unsigned u1 = T32[s1 * 64 + lane];
        ax += __uint_as_float(u0 << 16) * w0 + __uint_as_float(u1 << 16) * w1;
        ay += __uint_as_float(u0 & 0xffff0000u) * w0 + __uint_as_float(u1 & 0xffff0000u) * w1;
    }
    if (i < e) {
        int s0 = csr_src[i];
        float w0 = csr_w[i];
        unsigned u0 = T32[s0 * 64 + lane];
        ax += __uint_as_float(u0 << 16) * w0;
        ay += __uint_as_float(u0 & 0xffff0000u) * w0;
    }
    float dv = dinv[node];
    float sn = dv * dv;
    unsigned su = T32[node * 64 + lane];
    float2 bb = *(const float2*)&bias[lane * 2];
    float ox = tanhf(ax + __uint_as_float(su << 16) * sn + bb.x);
    float oy = tanhf(ay + __uint_as_float(su & 0xffff0000u) * sn + bb.y);
    unsigned o = (unsigned)f2bf(ox) | ((unsigned)f2bf(oy) << 16);
    ((unsigned*)Out)[node * 64 + lane] = o;
}

// ---------------- fused MFMA MLP head + pooled sum ----------------
// 64 nodes/block, 4 waves. L1: 128->128 MFMA; L2: 128->32 MFMA; L3: dot 32.
__global__ __launch_bounds__(256) void k_mlp(const unsigned short* __restrict__ H,
                                             const unsigned short* __restrict__ Wf1t,
                                             const float* __restrict__ bf1,
                                             const unsigned short* __restrict__ Wf2t,
                                             const float* __restrict__ bf2,
                                             const float* __restrict__ Wf3,
                                             const float* __restrict__ bf3,
                                             const int* __restrict__ batch,
                                             float* __restrict__ util_sum, int N) {
    __shared__ unsigned short As[64 * LDA];
    __shared__ unsigned short H2[64 * LDA];
    __shared__ float H3[64][36];
    const int tid = threadIdx.x;
    const int row0 = blockIdx.x * 64;
    const unsigned* H32 = (const unsigned*)H;
    #pragma unroll
    for (int j = 0; j < 16; ++j) {
        int idx = tid + j * 256;
        int r = idx >> 6, kd = idx & 63;
        unsigned v = (row0 + r < N) ? H32[(size_t)(row0 + r) * 64 + kd] : 0u;
        *(unsigned*)&As[r * LDA + kd * 2] = v;
    }
    __syncthreads();
    const int wave = tid >> 6, lane = tid & 63;
    const int m16 = lane & 15, q = lane >> 4;
    // ---- layer 1: 128 -> 128 ----
    {
        f32x4 acc[8];
        #pragma unroll
        for (int t = 0; t < 8; ++t) acc[t] = (f32x4){0.f, 0.f, 0.f, 0.f};
        const unsigned short* arow = &As[(wave * 16 + m16) * LDA + q * 8];
        #pragma unroll
        for (int kc = 0; kc < 4; ++kc) {
            bf16x8 af = *(const bf16x8*)(arow + kc * 32);
            #pragma unroll
            for (int t = 0; t < 8; ++t) {
                bf16x8 bfr = *(const bf16x8*)(Wf1t + ((t * 16 + m16) * 128 + kc * 32 + q * 8));
                acc[t] = __builtin_amdgcn_mfma_f32_16x16x32_bf16(af, bfr, acc[t], 0, 0, 0);
            }
        }
        #pragma unroll
        for (int t = 0; t < 8; ++t) {
            float b = bf1[t * 16 + m16];
            #pragma unroll
            for (int r = 0; r < 4; ++r) {
                int lr = wave * 16 + q * 4 + r;
                H2[lr * LDA + t * 16 + m16] = f2bf(tanhf(acc[t][r] + b));
            }
        }
    }
    __syncthreads();
    // ---- layer 2: 128 -> 32 ----
    {
        f32x4 acc2[2];
        acc2[0] = (f32x4){0.f, 0.f, 0.f, 0.f};
        acc2[1] = (f32x4){0.f, 0.f, 0.f, 0.f};
        const unsigned short* arow = &H2[(wave * 16 + m16) * LDA + q * 8];
        #pragma unroll
        for (int kc = 0; kc < 4; ++kc) {
            bf16x8 af = *(const bf16x8*)(arow + kc * 32);
            #pragma unroll
            for (int t = 0; t < 2; ++t) {
                bf16x8 bfr = *(const bf16x8*)(Wf2t + ((t * 16 + m16) * 128 + kc * 32 + q * 8));
                acc2[t] = __builtin_amdgcn_mfma_f32_16x16x32_bf16(af, bfr, acc2[t], 0, 0, 0);
            }
        }
        #pragma unroll
        for (int t = 0; t < 2; ++t) {
            float b = bf2[t * 16 + m16];
            #pragma unroll
            for (int r = 0; r < 4; ++r) {
                int lr = wave * 16 + q * 4 + r;
                H3[lr][t * 16 + m16] = tanhf(acc2[t][r] + b);
            }
        }
    }
    __syncthreads();
    // ---- layer 3 + pooled atomic ----
    if (tid < 64) {
        int n = row0 + tid;
        if (n < N) {
            float s = bf3[0];
            #pragma unroll
            for (int k = 0; k < 32; ++k) s += H3[tid][k] * Wf3[k];
            atomicAdd(&util_sum[batch[n]], s);
        }
    }
}

// ---------------- util = sum / max(cnt,1) ----------------
__global__ void k_util(const float* __restrict__ util_sum, const int* __restrict__ cnt,
                       float* __restrict__ out_util, int G) {
    int g = blockIdx.x * 256 + threadIdx.x;
    if (g < G) {
        float c = (float)cnt[g];
        out_util[g] = util_sum[g] / fmaxf(c, 1.0f);
    }
}

// ---------------- pair sigmoid ----------------
__global__ void k_pairs(const float* __restrict__ u, const int* __restrict__ ia,
                        const int* __restrict__ ib, float* __restrict__ out, int P) {
    int p = blockIdx.x * 256 + threadIdx.x;
    if (p < P) {
        float d = u[ib[p]] - u[ia[p]];
        out[p] = 1.0f / (1.0f + expf(-d));
    }
}

extern "C" void kernel_launch(void* const* d_in, const int* in_sizes, int n_in,
                              void* d_out, int out_size, void* d_ws, size_t ws_size,
                              hipStream_t stream) {
    const float* x     = (const float*)d_in[0];
    const int*   eidx  = (const int*)d_in[1];
    const int*   batch = (const int*)d_in[2];
    const int*   idx_a = (const int*)d_in[3];
    const int*   idx_b = (const int*)d_in[4];
    const float* W_in  = (const float*)d_in[5];
    const float* b_in  = (const float*)d_in[6];
    const float* W1    = (const float*)d_in[7];
    const float* b1    = (const float*)d_in[8];
    const float* W2    = (const float*)d_in[9];
    const float* b2    = (const float*)d_in[10];
    const float* Wf1   = (const float*)d_in[11];
    const float* bf1   = (const float*)d_in[12];
    const float* Wf2   = (const float*)d_in[13];
    const float* bf2   = (const float*)d_in[14];
    const float* Wf3   = (const float*)d_in[15];
    const float* bf3   = (const float*)d_in[16];
    float* out = (float*)d_out;

    const int N = in_sizes[0] / 9;
    const int E = in_sizes[1] / 2;
    const int P = in_sizes[3];
    const int G = out_size - P;

    const int* src = eidx;
    const int* dst = eidx + E;

    // ---- workspace carve-out ----
    char* ws = (char*)d_ws;
    size_t off = 0;
    auto take = [&](size_t bytes) -> void* {
        void* p = ws + off;
        off = (off + bytes + 255) & ~(size_t)255;
        return p;
    };
    int*   deg      = (int*)  take((size_t)N * 4);
    float* dinv     = (float*)take((size_t)N * 4);
    int*   rowptr   = (int*)  take((size_t)(N + 1) * 4);
    int*   bsum     = (int*)  take(256 * 4);
    int*   cursor   = (int*)  take((size_t)N * 4);
    int*   csr_src  = (int*)  take((size_t)E * 4);
    float* csr_w    = (float*)take((size_t)E * 4);
    float* xa       = (float*)take((size_t)N * 9 * 4);
    unsigned short* bufA = (unsigned short*)take((size_t)N * U * 2);  // bf16 acts
    unsigned short* Tb   = (unsigned short*)take((size_t)N * U * 2);  // bf16 table
    unsigned short* W1t  = (unsigned short*)take(128 * 128 * 2);
    unsigned short* W2t  = (unsigned short*)take(128 * 128 * 2);
    unsigned short* Wf1t = (unsigned short*)take(128 * 128 * 2);
    unsigned short* Wf2t = (unsigned short*)take(32 * 128 * 2);
    float* util_sum = (float*)take((size_t)G * 4);
    int*   cnt      = (int*)  take((size_t)G * 4);
    (void)ws_size;

    hipMemsetAsync(deg, 0, (size_t)N * 4, stream);
    hipMemsetAsync(cursor, 0, (size_t)N * 4, stream);
    hipMemsetAsync(util_sum, 0, (size_t)G * 4, stream);
    hipMemsetAsync(cnt, 0, (size_t)G * 4, stream);

    const int nb = (N + 1023) / 1024;

    // ---- CSR build + weight prep ----
    k_deg<<<(E + 255) / 256, 256, 0, stream>>>(dst, deg, E);
    k_dinv<<<(N + 255) / 256, 256, 0, stream>>>(deg, dinv, N);
    k_scan1<<<nb, 256, 0, stream>>>(deg, rowptr + 1, bsum, N);
    k_scan2<<<1, 256, 0, stream>>>(bsum, nb);
    k_scan3<<<(N + 255) / 256, 256, 0, stream>>>(rowptr, bsum, N);
    k_scatter<<<(E + 255) / 256, 256, 0, stream>>>(src, dst, dinv, rowptr, cursor,
                                                   csr_src, csr_w, E);
    k_counts<<<(N + 255) / 256, 256, 0, stream>>>(batch, cnt, N);
    k_prep_w<<<208, 256, 0, stream>>>(W1, W2, Wf1, Wf2, W1t, W2t, Wf1t, Wf2t);

    const int aggGrid  = (N + 3) / 4;
    const int gemmGrid = (N + 63) / 64;

    // ---- GCN layer 1: aggregate x (9-wide), then GEMM+bias+tanh -> bf16 ----
    k_aggx<<<(N + 15) / 16, 256, 0, stream>>>(x, rowptr, csr_src, csr_w, dinv, xa, N);
    k_gemm_in9<<<((size_t)N * U + 255) / 256, 256, 0, stream>>>(xa, W_in, b_in, bufA, N);

    // ---- GCN layer 2 ----
    k_gemm_mfma<<<gemmGrid, 256, 0, stream>>>(bufA, W1t, Tb, N);
    k_aggb<<<aggGrid, 256, 0, stream>>>(Tb, rowptr, csr_src, csr_w, dinv, b1, bufA, N);
    // ---- GCN layer 3 ----
    k_gemm_mfma<<<gemmGrid, 256, 0, stream>>>(bufA, W2t, Tb, N);
    k_aggb<<<aggGrid, 256, 0, stream>>>(Tb, rowptr, csr_src, csr_w, dinv, b2, bufA, N);

    // ---- MLP head + pooled sums ----
    k_mlp<<<gemmGrid, 256, 0, stream>>>(bufA, Wf1t, bf1, Wf2t, bf2, Wf3, bf3,
                                        batch, util_sum, N);

    // ---- util + pairs ----
    k_util<<<(G + 255) / 256, 256, 0, stream>>>(util_sum, cnt, out + P, G);
    k_pairs<<<(P + 255) / 256, 256, 0, stream>>>(out + P, idx_a, idx_b, out, P);
}

// Round 4
// 694.521 us; speedup vs baseline: 1.5092x; 1.0851x over previous
//
#include <hip/hip_runtime.h>
#include <hip/hip_bf16.h>
#include <math.h>

// ---------------------------------------------------------------------------
// RankGNN R4: csr_w eliminated via dinv pre-scaling (Ts = dinv*h folded into
// GEMM epilogue; agg = dinv[dst]*(sum+self)). Scatter writes only csr_src.
// aggb unrolled 4x for gather latency hiding.
// ---------------------------------------------------------------------------

#define U 128
#define LDA 136  // LDS row stride in bf16 elems (128 + 8 pad)

typedef __attribute__((ext_vector_type(8))) short bf16x8;
typedef __attribute__((ext_vector_type(4))) float f32x4;

__device__ __forceinline__ unsigned short f2bf(float f) {
    unsigned u = __float_as_uint(f);
    unsigned r = (u + 0x7fffu + ((u >> 16) & 1u)) >> 16;  // RNE
    return (unsigned short)r;
}
__device__ __forceinline__ float bf_lo(unsigned u) { return __uint_as_float(u << 16); }
__device__ __forceinline__ float bf_hi(unsigned u) { return __uint_as_float(u & 0xffff0000u); }

// ---------------- degree histogram ----------------
__global__ void k_deg(const int* __restrict__ dst, int* __restrict__ deg, int E) {
    int e = blockIdx.x * 256 + threadIdx.x;
    if (e < E) atomicAdd(&deg[dst[e]], 1);
}

__global__ void k_dinv(const int* __restrict__ deg, float* __restrict__ dinv, int N) {
    int i = blockIdx.x * 256 + threadIdx.x;
    if (i < N) dinv[i] = rsqrtf((float)deg[i] + 1.0f);
}

// xs = dinv[n] * x[n]  (N x 9)
__global__ void k_scale_x(const float* __restrict__ x, const float* __restrict__ dinv,
                          float* __restrict__ xs, int NE) {
    int t = blockIdx.x * 256 + threadIdx.x;
    if (t < NE) xs[t] = x[t] * dinv[t / 9];
}

// ---------------- exclusive scan (rowptr) ----------------
__global__ __launch_bounds__(256) void k_scan1(const int* __restrict__ deg,
                                               int* __restrict__ rowptr1,
                                               int* __restrict__ bsum, int N) {
    __shared__ int sc[256];
    int t = threadIdx.x, b = blockIdx.x;
    int base = b * 1024 + t * 4;
    int v[4];
    int s = 0;
    #pragma unroll
    for (int j = 0; j < 4; ++j) {
        int idx = base + j;
        int d = (idx < N) ? deg[idx] : 0;
        s += d;
        v[j] = s;
    }
    sc[t] = s;
    __syncthreads();
    for (int off = 1; off < 256; off <<= 1) {
        int x = (t >= off) ? sc[t - off] : 0;
        __syncthreads();
        sc[t] += x;
        __syncthreads();
    }
    int excl = sc[t] - s;
    #pragma unroll
    for (int j = 0; j < 4; ++j) {
        int idx = base + j;
        if (idx < N) rowptr1[idx] = v[j] + excl;
    }
    if (t == 255) bsum[b] = sc[255];
}

__global__ __launch_bounds__(256) void k_scan2(int* __restrict__ bsum, int nb) {
    __shared__ int sc[256];
    int t = threadIdx.x;
    int v = (t < nb) ? bsum[t] : 0;
    sc[t] = v;
    __syncthreads();
    for (int off = 1; off < 256; off <<= 1) {
        int x = (t >= off) ? sc[t - off] : 0;
        __syncthreads();
        sc[t] += x;
        __syncthreads();
    }
    if (t < nb) bsum[t] = sc[t] - v;  // exclusive
}

__global__ void k_scan3(int* __restrict__ rowptr, const int* __restrict__ boff, int N) {
    int i = blockIdx.x * 256 + threadIdx.x;
    if (i < N) rowptr[1 + i] += boff[i >> 10];
    if (i == 0) rowptr[0] = 0;
}

// ---------------- CSR scatter (index only) ----------------
__global__ void k_scatter(const int* __restrict__ src, const int* __restrict__ dst,
                          const int* __restrict__ rowptr, int* __restrict__ cursor,
                          int* __restrict__ csr_src, int E) {
    int e = blockIdx.x * 256 + threadIdx.x;
    if (e < E) {
        int d = dst[e];
        int pos = atomicAdd(&cursor[d], 1);
        csr_src[rowptr[d] + pos] = src[e];
    }
}

// ---------------- per-graph node counts ----------------
__global__ void k_counts(const int* __restrict__ batch, int* __restrict__ cnt, int N) {
    int i = blockIdx.x * 256 + threadIdx.x;
    if (i < N) atomicAdd(&cnt[batch[i]], 1);
}

// ---------------- weight prep: transpose + bf16 ----------------
__global__ void k_prep_w(const float* __restrict__ W1, const float* __restrict__ W2,
                         const float* __restrict__ Wf1, const float* __restrict__ Wf2,
                         unsigned short* __restrict__ W1t, unsigned short* __restrict__ W2t,
                         unsigned short* __restrict__ Wf1t, unsigned short* __restrict__ Wf2t) {
    int t = blockIdx.x * 256 + threadIdx.x;
    if (t < 16384) {
        int n = t >> 7, k = t & 127;
        W1t[n * 128 + k] = f2bf(W1[k * 128 + n]);
    } else if (t < 32768) {
        int i = t - 16384, n = i >> 7, k = i & 127;
        W2t[n * 128 + k] = f2bf(W2[k * 128 + n]);
    } else if (t < 49152) {
        int i = t - 32768, n = i >> 7, k = i & 127;
        Wf1t[n * 128 + k] = f2bf(Wf1[k * 128 + n]);
    } else if (t < 53248) {
        int i = t - 49152, n = i >> 7, k = i & 127;
        Wf2t[n * 128 + k] = f2bf(Wf2[k * 32 + n]);
    }
}

// ---------------- layer-1: aggregate xs (N x 9), output dinv-scaled ---------
// xa[n] = dinv[n] * (sum_src xs[src] + xs[n])
__global__ __launch_bounds__(256) void k_aggx(const float* __restrict__ xs,
                                              const int* __restrict__ rowptr,
                                              const int* __restrict__ csr_src,
                                              const float* __restrict__ dinv,
                                              float* __restrict__ xa, int N) {
    int node = blockIdx.x * 16 + (threadIdx.x >> 4);
    if (node >= N) return;
    int lane = threadIdx.x & 15;
    bool act = lane < 9;
    int s = rowptr[node], e = rowptr[node + 1];
    float a0 = 0.0f, a1 = 0.0f;
    int i = s;
    for (; i + 2 <= e; i += 2) {
        int s0 = csr_src[i], s1 = csr_src[i + 1];
        if (act) {
            a0 += xs[s0 * 9 + lane];
            a1 += xs[s1 * 9 + lane];
        }
    }
    if (i < e) {
        int s0 = csr_src[i];
        if (act) a0 += xs[s0 * 9 + lane];
    }
    if (act) {
        float dv = dinv[node];
        xa[node * 9 + lane] = dv * (a0 + a1 + xs[node * 9 + lane]);
    }
}

// ---------------- layer-1 GEMM: bf16(tanh(xa @ W_in + b)) ----------------
__global__ void k_gemm_in9(const float* __restrict__ xa, const float* __restrict__ Wi,
                           const float* __restrict__ bi, unsigned short* __restrict__ T,
                           int N) {
    int t = blockIdx.x * 256 + threadIdx.x;
    if (t < N * U) {
        int n = t >> 7, c = t & 127;
        const float* xr = xa + n * 9;
        float acc = bi[c];
        #pragma unroll
        for (int k = 0; k < 9; ++k) acc += xr[k] * Wi[k * U + c];
        T[t] = f2bf(tanhf(acc));
    }
}

// ---------------- MFMA GEMM: Ts(bf16) = dinv * (A(bf16) @ Wt^T) -------------
__global__ __launch_bounds__(256) void k_gemm_mfma(const unsigned short* __restrict__ A,
                                                   const unsigned short* __restrict__ Wt,
                                                   const float* __restrict__ dinv,
                                                   unsigned short* __restrict__ Out, int N) {
    __shared__ unsigned short As[64 * LDA];
    const int tid = threadIdx.x;
    const int row0 = blockIdx.x * 64;
    const unsigned* A32 = (const unsigned*)A;
    #pragma unroll
    for (int j = 0; j < 16; ++j) {
        int idx = tid + j * 256;
        int r = idx >> 6, kd = idx & 63;
        unsigned v = (row0 + r < N) ? A32[(size_t)(row0 + r) * 64 + kd] : 0u;
        *(unsigned*)&As[r * LDA + kd * 2] = v;
    }
    __syncthreads();
    const int wave = tid >> 6, lane = tid & 63;
    const int m16 = lane & 15, q = lane >> 4;
    f32x4 acc[8];
    #pragma unroll
    for (int t = 0; t < 8; ++t) acc[t] = (f32x4){0.f, 0.f, 0.f, 0.f};
    const unsigned short* arow = &As[(wave * 16 + m16) * LDA + q * 8];
    #pragma unroll
    for (int kc = 0; kc < 4; ++kc) {
        bf16x8 af = *(const bf16x8*)(arow + kc * 32);
        #pragma unroll
        for (int t = 0; t < 8; ++t) {
            bf16x8 bfr = *(const bf16x8*)(Wt + ((t * 16 + m16) * 128 + kc * 32 + q * 8));
            acc[t] = __builtin_amdgcn_mfma_f32_16x16x32_bf16(af, bfr, acc[t], 0, 0, 0);
        }
    }
    float dv[4];
    #pragma unroll
    for (int r = 0; r < 4; ++r) {
        int gr = row0 + wave * 16 + q * 4 + r;
        dv[r] = (gr < N) ? dinv[gr] : 0.0f;
    }
    #pragma unroll
    for (int t = 0; t < 8; ++t) {
        #pragma unroll
        for (int r = 0; r < 4; ++r) {
            int gr = row0 + wave * 16 + q * 4 + r;
            if (gr < N) Out[(size_t)gr * U + t * 16 + m16] = f2bf(acc[t][r] * dv[r]);
        }
    }
}

// ---------------- aggregation: h = tanh(dinv[d]*(sum Ts + Ts[d]) + b) -------
__global__ __launch_bounds__(256) void k_aggb(const unsigned short* __restrict__ Tb,
                                              const int* __restrict__ rowptr,
                                              const int* __restrict__ csr_src,
                                              const float* __restrict__ dinv,
                                              const float* __restrict__ bias,
                                              unsigned short* __restrict__ Out, int N) {
    int node = blockIdx.x * 4 + (threadIdx.x >> 6);
    if (node >= N) return;
    int lane = threadIdx.x & 63;
    const unsigned* T32 = (const unsigned*)Tb;
    float ax = 0.0f, ay = 0.0f, bx = 0.0f, by = 0.0f;
    int s = rowptr[node], e = rowptr[node + 1];
    int i = s;
    for (; i + 4 <= e; i += 4) {
        int s0 = csr_src[i], s1 = csr_src[i + 1];
        int s2 = csr_src[i + 2], s3 = csr_src[i + 3];
        unsigned u0 = T32[s0 * 64 + lane];
        unsigned u1 = T32[s1 * 64 + lane];
        unsigned u2 = T32[s2 * 64 + lane];
        unsigned u3 = T32[s3 * 64 + lane];
        ax += bf_lo(u0) + bf_lo(u1);
        ay += bf_hi(u0) + bf_hi(u1);
        bx += bf_lo(u2) + bf_lo(u3);
        by += bf_hi(u2) + bf_hi(u3);
    }
    for (; i < e; ++i) {
        int s0 = csr_src[i];
        unsigned u0 = T32[s0 * 64 + lane];
        ax += bf_lo(u0);
        ay += bf_hi(u0);
    }
    float dv = dinv[node];
    unsigned su = T32[node * 64 + lane];
    float2 bb = *(const float2*)&bias[lane * 2];
    float ox = tanhf(dv * (ax + bx + bf_lo(su)) + bb.x);
    float oy = tanhf(dv * (ay + by + bf_hi(su)) + bb.y);
    unsigned o = (unsigned)f2bf(ox) | ((unsigned)f2bf(oy) << 16);
    ((unsigned*)Out)[node * 64 + lane] = o;
}

// ---------------- fused MFMA MLP head + pooled sum ----------------
__global__ __launch_bounds__(256) void k_mlp(const unsigned short* __restrict__ H,
                                             const unsigned short* __restrict__ Wf1t,
                                             const float* __restrict__ bf1,
                                             const unsigned short* __restrict__ Wf2t,
                                             const float* __restrict__ bf2,
                                             const float* __restrict__ Wf3,
                                             const float* __restrict__ bf3,
                                             const int* __restrict__ batch,
                                             float* __restrict__ util_sum, int N) {
    __shared__ unsigned short As[64 * LDA];
    __shared__ unsigned short H2[64 * LDA];
    __shared__ float H3[64][36];
    const int tid = threadIdx.x;
    const int row0 = blockIdx.x * 64;
    const unsigned* H32 = (const unsigned*)H;
    #pragma unroll
    for (int j = 0; j < 16; ++j) {
        int idx = tid + j * 256;
        int r = idx >> 6, kd = idx & 63;
        unsigned v = (row0 + r < N) ? H32[(size_t)(row0 + r) * 64 + kd] : 0u;
        *(unsigned*)&As[r * LDA + kd * 2] = v;
    }
    __syncthreads();
    const int wave = tid >> 6, lane = tid & 63;
    const int m16 = lane & 15, q = lane >> 4;
    // ---- layer 1: 128 -> 128 ----
    {
        f32x4 acc[8];
        #pragma unroll
        for (int t = 0; t < 8; ++t) acc[t] = (f32x4){0.f, 0.f, 0.f, 0.f};
        const unsigned short* arow = &As[(wave * 16 + m16) * LDA + q * 8];
        #pragma unroll
        for (int kc = 0; kc < 4; ++kc) {
            bf16x8 af = *(const bf16x8*)(arow + kc * 32);
            #pragma unroll
            for (int t = 0; t < 8; ++t) {
                bf16x8 bfr = *(const bf16x8*)(Wf1t + ((t * 16 + m16) * 128 + kc * 32 + q * 8));
                acc[t] = __builtin_amdgcn_mfma_f32_16x16x32_bf16(af, bfr, acc[t], 0, 0, 0);
            }
        }
        #pragma unroll
        for (int t = 0; t < 8; ++t) {
            float b = bf1[t * 16 + m16];
            #pragma unroll
            for (int r = 0; r < 4; ++r) {
                int lr = wave * 16 + q * 4 + r;
                H2[lr * LDA + t * 16 + m16] = f2bf(tanhf(acc[t][r] + b));
            }
        }
    }
    __syncthreads();
    // ---- layer 2: 128 -> 32 ----
    {
        f32x4 acc2[2];
        acc2[0] = (f32x4){0.f, 0.f, 0.f, 0.f};
        acc2[1] = (f32x4){0.f, 0.f, 0.f, 0.f};
        const unsigned short* arow = &H2[(wave * 16 + m16) * LDA + q * 8];
        #pragma unroll
        for (int kc = 0; kc < 4; ++kc) {
            bf16x8 af = *(const bf16x8*)(arow + kc * 32);
            #pragma unroll
            for (int t = 0; t < 2; ++t) {
                bf16x8 bfr = *(const bf16x8*)(Wf2t + ((t * 16 + m16) * 128 + kc * 32 + q * 8));
                acc2[t] = __builtin_amdgcn_mfma_f32_16x16x32_bf16(af, bfr, acc2[t], 0, 0, 0);
            }
        }
        #pragma unroll
        for (int t = 0; t < 2; ++t) {
            float b = bf2[t * 16 + m16];
            #pragma unroll
            for (int r = 0; r < 4; ++r) {
                int lr = wave * 16 + q * 4 + r;
                H3[lr][t * 16 + m16] = tanhf(acc2[t][r] + b);
            }
        }
    }
    __syncthreads();
    // ---- layer 3 + pooled atomic ----
    if (tid < 64) {
        int n = row0 + tid;
        if (n < N) {
            float s = bf3[0];
            #pragma unroll
            for (int k = 0; k < 32; ++k) s += H3[tid][k] * Wf3[k];
            atomicAdd(&util_sum[batch[n]], s);
        }
    }
}

// ---------------- util = sum / max(cnt,1) ----------------
__global__ void k_util(const float* __restrict__ util_sum, const int* __restrict__ cnt,
                       float* __restrict__ out_util, int G) {
    int g = blockIdx.x * 256 + threadIdx.x;
    if (g < G) {
        float c = (float)cnt[g];
        out_util[g] = util_sum[g] / fmaxf(c, 1.0f);
    }
}

// ---------------- pair sigmoid ----------------
__global__ void k_pairs(const float* __restrict__ u, const int* __restrict__ ia,
                        const int* __restrict__ ib, float* __restrict__ out, int P) {
    int p = blockIdx.x * 256 + threadIdx.x;
    if (p < P) {
        float d = u[ib[p]] - u[ia[p]];
        out[p] = 1.0f / (1.0f + expf(-d));
    }
}

extern "C" void kernel_launch(void* const* d_in, const int* in_sizes, int n_in,
                              void* d_out, int out_size, void* d_ws, size_t ws_size,
                              hipStream_t stream) {
    const float* x     = (const float*)d_in[0];
    const int*   eidx  = (const int*)d_in[1];
    const int*   batch = (const int*)d_in[2];
    const int*   idx_a = (const int*)d_in[3];
    const int*   idx_b = (const int*)d_in[4];
    const float* W_in  = (const float*)d_in[5];
    const float* b_in  = (const float*)d_in[6];
    const float* W1    = (const float*)d_in[7];
    const float* b1    = (const float*)d_in[8];
    const float* W2    = (const float*)d_in[9];
    const float* b2    = (const float*)d_in[10];
    const float* Wf1   = (const float*)d_in[11];
    const float* bf1   = (const float*)d_in[12];
    const float* Wf2   = (const float*)d_in[13];
    const float* bf2   = (const float*)d_in[14];
    const float* Wf3   = (const float*)d_in[15];
    const float* bf3   = (const float*)d_in[16];
    float* out = (float*)d_out;

    const int N = in_sizes[0] / 9;
    const int E = in_sizes[1] / 2;
    const int P = in_sizes[3];
    const int G = out_size - P;

    const int* src = eidx;
    const int* dst = eidx + E;

    // ---- workspace carve-out ----
    char* ws = (char*)d_ws;
    size_t off = 0;
    auto take = [&](size_t bytes) -> void* {
        void* p = ws + off;
        off = (off + bytes + 255) & ~(size_t)255;
        return p;
    };
    int*   deg      = (int*)  take((size_t)N * 4);
    float* dinv     = (float*)take((size_t)N * 4);
    int*   rowptr   = (int*)  take((size_t)(N + 1) * 4);
    int*   bsum     = (int*)  take(256 * 4);
    int*   cursor   = (int*)  take((size_t)N * 4);
    int*   csr_src  = (int*)  take((size_t)E * 4);
    float* xs       = (float*)take((size_t)N * 9 * 4);
    float* xa       = (float*)take((size_t)N * 9 * 4);
    unsigned short* bufA = (unsigned short*)take((size_t)N * U * 2);  // bf16 acts
    unsigned short* Tb   = (unsigned short*)take((size_t)N * U * 2);  // bf16 table
    unsigned short* W1t  = (unsigned short*)take(128 * 128 * 2);
    unsigned short* W2t  = (unsigned short*)take(128 * 128 * 2);
    unsigned short* Wf1t = (unsigned short*)take(128 * 128 * 2);
    unsigned short* Wf2t = (unsigned short*)take(32 * 128 * 2);
    float* util_sum = (float*)take((size_t)G * 4);
    int*   cnt      = (int*)  take((size_t)G * 4);
    (void)ws_size;

    hipMemsetAsync(deg, 0, (size_t)N * 4, stream);
    hipMemsetAsync(cursor, 0, (size_t)N * 4, stream);
    hipMemsetAsync(util_sum, 0, (size_t)G * 4, stream);
    hipMemsetAsync(cnt, 0, (size_t)G * 4, stream);

    const int nb = (N + 1023) / 1024;

    // ---- CSR build + weight prep ----
    k_deg<<<(E + 255) / 256, 256, 0, stream>>>(dst, deg, E);
    k_dinv<<<(N + 255) / 256, 256, 0, stream>>>(deg, dinv, N);
    k_scale_x<<<((size_t)N * 9 + 255) / 256, 256, 0, stream>>>(x, dinv, xs, N * 9);
    k_scan1<<<nb, 256, 0, stream>>>(deg, rowptr + 1, bsum, N);
    k_scan2<<<1, 256, 0, stream>>>(bsum, nb);
    k_scan3<<<(N + 255) / 256, 256, 0, stream>>>(rowptr, bsum, N);
    k_scatter<<<(E + 255) / 256, 256, 0, stream>>>(src, dst, rowptr, cursor, csr_src, E);
    k_counts<<<(N + 255) / 256, 256, 0, stream>>>(batch, cnt, N);
    k_prep_w<<<208, 256, 0, stream>>>(W1, W2, Wf1, Wf2, W1t, W2t, Wf1t, Wf2t);

    const int aggGrid  = (N + 3) / 4;
    const int gemmGrid = (N + 63) / 64;

    // ---- GCN layer 1: aggregate xs (9-wide), then GEMM+bias+tanh -> bf16 ----
    k_aggx<<<(N + 15) / 16, 256, 0, stream>>>(xs, rowptr, csr_src, dinv, xa, N);
    k_gemm_in9<<<((size_t)N * U + 255) / 256, 256, 0, stream>>>(xa, W_in, b_in, bufA, N);

    // ---- GCN layer 2 ----
    k_gemm_mfma<<<gemmGrid, 256, 0, stream>>>(bufA, W1t, dinv, Tb, N);
    k_aggb<<<aggGrid, 256, 0, stream>>>(Tb, rowptr, csr_src, dinv, b1, bufA, N);
    // ---- GCN layer 3 ----
    k_gemm_mfma<<<gemmGrid, 256, 0, stream>>>(bufA, W2t, dinv, Tb, N);
    k_aggb<<<aggGrid, 256, 0, stream>>>(Tb, rowptr, csr_src, dinv, b2, bufA, N);

    // ---- MLP head + pooled sums ----
    k_mlp<<<gemmGrid, 256, 0, stream>>>(bufA, Wf1t, bf1, Wf2t, bf2, Wf3, bf3,
                                        batch, util_sum, N);

    // ---- util + pairs ----
    k_util<<<(G + 255) / 256, 256, 0, stream>>>(util_sum, cnt, out + P, G);
    k_pairs<<<(P + 255) / 256, 256, 0, stream>>>(out + P, idx_a, idx_b, out, P);
}

// Round 5
// 646.739 us; speedup vs baseline: 1.6207x; 1.0739x over previous
//
#include <hip/hip_runtime.h>
#include <hip/hip_bf16.h>
#include <math.h>

// ---------------------------------------------------------------------------
// RankGNN R5: multi-pass dst-windowed scatter (L2-resident write window);
// barrier-free LDS-free MFMA GEMM; barrier-free MLP head with wave-local
// LDS transpose + shuffle-reduce layer 3.
// ---------------------------------------------------------------------------

#define U 128
#define LDA 136  // LDS row stride in bf16 elems (128 + 8 pad)

typedef __attribute__((ext_vector_type(8))) short bf16x8;
typedef __attribute__((ext_vector_type(4))) float f32x4;

__device__ __forceinline__ unsigned short f2bf(float f) {
    unsigned u = __float_as_uint(f);
    unsigned r = (u + 0x7fffu + ((u >> 16) & 1u)) >> 16;  // RNE
    return (unsigned short)r;
}
__device__ __forceinline__ float bf_lo(unsigned u) { return __uint_as_float(u << 16); }
__device__ __forceinline__ float bf_hi(unsigned u) { return __uint_as_float(u & 0xffff0000u); }

// ---------------- degree histogram ----------------
__global__ void k_deg(const int* __restrict__ dst, int* __restrict__ deg, int E) {
    int e = blockIdx.x * 256 + threadIdx.x;
    if (e < E) atomicAdd(&deg[dst[e]], 1);
}

__global__ void k_dinv(const int* __restrict__ deg, float* __restrict__ dinv, int N) {
    int i = blockIdx.x * 256 + threadIdx.x;
    if (i < N) dinv[i] = rsqrtf((float)deg[i] + 1.0f);
}

// xs = dinv[n] * x[n]  (N x 9)
__global__ void k_scale_x(const float* __restrict__ x, const float* __restrict__ dinv,
                          float* __restrict__ xs, int NE) {
    int t = blockIdx.x * 256 + threadIdx.x;
    if (t < NE) xs[t] = x[t] * dinv[t / 9];
}

// ---------------- exclusive scan (rowptr) ----------------
__global__ __launch_bounds__(256) void k_scan1(const int* __restrict__ deg,
                                               int* __restrict__ rowptr1,
                                               int* __restrict__ bsum, int N) {
    __shared__ int sc[256];
    int t = threadIdx.x, b = blockIdx.x;
    int base = b * 1024 + t * 4;
    int v[4];
    int s = 0;
    #pragma unroll
    for (int j = 0; j < 4; ++j) {
        int idx = base + j;
        int d = (idx < N) ? deg[idx] : 0;
        s += d;
        v[j] = s;
    }
    sc[t] = s;
    __syncthreads();
    for (int off = 1; off < 256; off <<= 1) {
        int x = (t >= off) ? sc[t - off] : 0;
        __syncthreads();
        sc[t] += x;
        __syncthreads();
    }
    int excl = sc[t] - s;
    #pragma unroll
    for (int j = 0; j < 4; ++j) {
        int idx = base + j;
        if (idx < N) rowptr1[idx] = v[j] + excl;
    }
    if (t == 255) bsum[b] = sc[255];
}

__global__ __launch_bounds__(256) void k_scan2(int* __restrict__ bsum, int nb) {
    __shared__ int sc[256];
    int t = threadIdx.x;
    int v = (t < nb) ? bsum[t] : 0;
    sc[t] = v;
    __syncthreads();
    for (int off = 1; off < 256; off <<= 1) {
        int x = (t >= off) ? sc[t - off] : 0;
        __syncthreads();
        sc[t] += x;
        __syncthreads();
    }
    if (t < nb) bsum[t] = sc[t] - v;  // exclusive
}

__global__ void k_scan3(int* __restrict__ rowptr, const int* __restrict__ boff, int N) {
    int i = blockIdx.x * 256 + threadIdx.x;
    if (i < N) rowptr[1 + i] += boff[i >> 10];
    if (i == 0) rowptr[0] = 0;
}

// ---------------- CSR scatter: dst-windowed multi-pass ----------------
// pass = blockIdx.y handles dst in [pass<<13, (pass+1)<<13): csr write window
// ~512 KB -> L2-resident, line evictions amortized over the ~16 writes/row.
__global__ void k_scatter(const int* __restrict__ src, const int* __restrict__ dst,
                          const int* __restrict__ rowptr, int* __restrict__ cursor,
                          int* __restrict__ csr_src, int E) {
    int e = blockIdx.x * 256 + threadIdx.x;
    int pass = blockIdx.y;
    if (e < E) {
        int d = dst[e];
        if ((d >> 13) == pass) {
            int pos = atomicAdd(&cursor[d], 1);
            csr_src[rowptr[d] + pos] = src[e];
        }
    }
}

// ---------------- per-graph node counts ----------------
__global__ void k_counts(const int* __restrict__ batch, int* __restrict__ cnt, int N) {
    int i = blockIdx.x * 256 + threadIdx.x;
    if (i < N) atomicAdd(&cnt[batch[i]], 1);
}

// ---------------- weight prep: transpose + bf16 ----------------
__global__ void k_prep_w(const float* __restrict__ W1, const float* __restrict__ W2,
                         const float* __restrict__ Wf1, const float* __restrict__ Wf2,
                         unsigned short* __restrict__ W1t, unsigned short* __restrict__ W2t,
                         unsigned short* __restrict__ Wf1t, unsigned short* __restrict__ Wf2t) {
    int t = blockIdx.x * 256 + threadIdx.x;
    if (t < 16384) {
        int n = t >> 7, k = t & 127;
        W1t[n * 128 + k] = f2bf(W1[k * 128 + n]);
    } else if (t < 32768) {
        int i = t - 16384, n = i >> 7, k = i & 127;
        W2t[n * 128 + k] = f2bf(W2[k * 128 + n]);
    } else if (t < 49152) {
        int i = t - 32768, n = i >> 7, k = i & 127;
        Wf1t[n * 128 + k] = f2bf(Wf1[k * 128 + n]);
    } else if (t < 53248) {
        int i = t - 49152, n = i >> 7, k = i & 127;
        Wf2t[n * 128 + k] = f2bf(Wf2[k * 32 + n]);
    }
}

// ---------------- layer-1: aggregate xs (N x 9), output dinv-scaled ---------
__global__ __launch_bounds__(256) void k_aggx(const float* __restrict__ xs,
                                              const int* __restrict__ rowptr,
                                              const int* __restrict__ csr_src,
                                              const float* __restrict__ dinv,
                                              float* __restrict__ xa, int N) {
    int node = blockIdx.x * 16 + (threadIdx.x >> 4);
    if (node >= N) return;
    int lane = threadIdx.x & 15;
    bool act = lane < 9;
    int s = rowptr[node], e = rowptr[node + 1];
    float a0 = 0.0f, a1 = 0.0f;
    int i = s;
    for (; i + 2 <= e; i += 2) {
        int s0 = csr_src[i], s1 = csr_src[i + 1];
        if (act) {
            a0 += xs[s0 * 9 + lane];
            a1 += xs[s1 * 9 + lane];
        }
    }
    if (i < e) {
        int s0 = csr_src[i];
        if (act) a0 += xs[s0 * 9 + lane];
    }
    if (act) {
        float dv = dinv[node];
        xa[node * 9 + lane] = dv * (a0 + a1 + xs[node * 9 + lane]);
    }
}

// ---------------- layer-1 GEMM: bf16(tanh(xa @ W_in + b)) ----------------
__global__ void k_gemm_in9(const float* __restrict__ xa, const float* __restrict__ Wi,
                           const float* __restrict__ bi, unsigned short* __restrict__ T,
                           int N) {
    int t = blockIdx.x * 256 + threadIdx.x;
    if (t < N * U) {
        int n = t >> 7, c = t & 127;
        const float* xr = xa + n * 9;
        float acc = bi[c];
        #pragma unroll
        for (int k = 0; k < 9; ++k) acc += xr[k] * Wi[k * U + c];
        T[t] = f2bf(tanhf(acc));
    }
}

// ---------------- MFMA GEMM (LDS-free, barrier-free) ----------------
// Ts(bf16) = dinv * (A(bf16) @ Wt^T). A-frags loaded directly from global
// (same 64B segments staging would read). One wave = 16 rows x 128 cols.
__global__ __launch_bounds__(256) void k_gemm_mfma(const unsigned short* __restrict__ A,
                                                   const unsigned short* __restrict__ Wt,
                                                   const float* __restrict__ dinv,
                                                   unsigned short* __restrict__ Out, int N) {
    const int tid = threadIdx.x;
    const int wave = tid >> 6, lane = tid & 63;
    const int m16 = lane & 15, q = lane >> 4;
    const int row0 = blockIdx.x * 64 + wave * 16;
    int arow_idx = row0 + m16;
    if (arow_idx >= N) arow_idx = N - 1;  // clamp; OOB outputs are guarded
    const bf16x8* arow = (const bf16x8*)(A + (size_t)arow_idx * U + q * 8);
    f32x4 acc[8];
    #pragma unroll
    for (int t = 0; t < 8; ++t) acc[t] = (f32x4){0.f, 0.f, 0.f, 0.f};
    #pragma unroll
    for (int kc = 0; kc < 4; ++kc) {
        bf16x8 af = arow[kc * 4];  // + kc*32 elems
        #pragma unroll
        for (int t = 0; t < 8; ++t) {
            bf16x8 bfr = *(const bf16x8*)(Wt + ((t * 16 + m16) * 128 + kc * 32 + q * 8));
            acc[t] = __builtin_amdgcn_mfma_f32_16x16x32_bf16(af, bfr, acc[t], 0, 0, 0);
        }
    }
    float dv[4];
    #pragma unroll
    for (int r = 0; r < 4; ++r) {
        int gr = row0 + q * 4 + r;
        dv[r] = (gr < N) ? dinv[gr] : 0.0f;
    }
    #pragma unroll
    for (int t = 0; t < 8; ++t) {
        #pragma unroll
        for (int r = 0; r < 4; ++r) {
            int gr = row0 + q * 4 + r;
            if (gr < N) Out[(size_t)gr * U + t * 16 + m16] = f2bf(acc[t][r] * dv[r]);
        }
    }
}

// ---------------- aggregation: h = tanh(dinv[d]*(sum Ts + Ts[d]) + b) -------
__global__ __launch_bounds__(256) void k_aggb(const unsigned short* __restrict__ Tb,
                                              const int* __restrict__ rowptr,
                                              const int* __restrict__ csr_src,
                                              const float* __restrict__ dinv,
                                              const float* __restrict__ bias,
                                              unsigned short* __restrict__ Out, int N) {
    int node = blockIdx.x * 4 + (threadIdx.x >> 6);
    if (node >= N) return;
    int lane = threadIdx.x & 63;
    const unsigned* T32 = (const unsigned*)Tb;
    float ax = 0.0f, ay = 0.0f, bx = 0.0f, by = 0.0f;
    int s = rowptr[node], e = rowptr[node + 1];
    int i = s;
    for (; i + 4 <= e; i += 4) {
        int s0 = csr_src[i], s1 = csr_src[i + 1];
        int s2 = csr_src[i + 2], s3 = csr_src[i + 3];
        unsigned u0 = T32[s0 * 64 + lane];
        unsigned u1 = T32[s1 * 64 + lane];
        unsigned u2 = T32[s2 * 64 + lane];
        unsigned u3 = T32[s3 * 64 + lane];
        ax += bf_lo(u0) + bf_lo(u1);
        ay += bf_hi(u0) + bf_hi(u1);
        bx += bf_lo(u2) + bf_lo(u3);
        by += bf_hi(u2) + bf_hi(u3);
    }
    for (; i < e; ++i) {
        int s0 = csr_src[i];
        unsigned u0 = T32[s0 * 64 + lane];
        ax += bf_lo(u0);
        ay += bf_hi(u0);
    }
    float dv = dinv[node];
    unsigned su = T32[node * 64 + lane];
    float2 bb = *(const float2*)&bias[lane * 2];
    float ox = tanhf(dv * (ax + bx + bf_lo(su)) + bb.x);
    float oy = tanhf(dv * (ay + by + bf_hi(su)) + bb.y);
    unsigned o = (unsigned)f2bf(ox) | ((unsigned)f2bf(oy) << 16);
    ((unsigned*)Out)[node * 64 + lane] = o;
}

// ---------------- fused MFMA MLP head (barrier-free) ----------------
// Per wave: 16 nodes. L1 128->128 (A-frags direct from global, C->A transpose
// via wave-local LDS slice), L2 128->32, L3 via shuffle-reduce + atomics.
__global__ __launch_bounds__(256) void k_mlp(const unsigned short* __restrict__ H,
                                             const unsigned short* __restrict__ Wf1t,
                                             const float* __restrict__ bf1,
                                             const unsigned short* __restrict__ Wf2t,
                                             const float* __restrict__ bf2,
                                             const float* __restrict__ Wf3,
                                             const float* __restrict__ bf3,
                                             const int* __restrict__ batch,
                                             float* __restrict__ util_sum, int N) {
    __shared__ unsigned short H2[64 * LDA];  // wave-local 16-row slices
    const int tid = threadIdx.x;
    const int wave = tid >> 6, lane = tid & 63;
    const int m16 = lane & 15, q = lane >> 4;
    const int row0 = blockIdx.x * 64 + wave * 16;
    int arow_idx = row0 + m16;
    if (arow_idx >= N) arow_idx = N - 1;
    const bf16x8* arow = (const bf16x8*)(H + (size_t)arow_idx * U + q * 8);
    // ---- layer 1: 128 -> 128 ----
    f32x4 acc[8];
    #pragma unroll
    for (int t = 0; t < 8; ++t) acc[t] = (f32x4){0.f, 0.f, 0.f, 0.f};
    #pragma unroll
    for (int kc = 0; kc < 4; ++kc) {
        bf16x8 af = arow[kc * 4];
        #pragma unroll
        for (int t = 0; t < 8; ++t) {
            bf16x8 bfr = *(const bf16x8*)(Wf1t + ((t * 16 + m16) * 128 + kc * 32 + q * 8));
            acc[t] = __builtin_amdgcn_mfma_f32_16x16x32_bf16(af, bfr, acc[t], 0, 0, 0);
        }
    }
    // epilogue: tanh -> wave-local LDS slice (C-layout -> memory row layout)
    #pragma unroll
    for (int t = 0; t < 8; ++t) {
        float b = bf1[t * 16 + m16];
        #pragma unroll
        for (int r = 0; r < 4; ++r) {
            int lr = wave * 16 + q * 4 + r;
            H2[lr * LDA + t * 16 + m16] = f2bf(tanhf(acc[t][r] + b));
        }
    }
    // ---- layer 2: 128 -> 32 (A-frags from own LDS slice; in-order DS => no barrier)
    f32x4 acc2[2];
    acc2[0] = (f32x4){0.f, 0.f, 0.f, 0.f};
    acc2[1] = (f32x4){0.f, 0.f, 0.f, 0.f};
    const unsigned short* h2row = &H2[(wave * 16 + m16) * LDA + q * 8];
    #pragma unroll
    for (int kc = 0; kc < 4; ++kc) {
        bf16x8 af = *(const bf16x8*)(h2row + kc * 32);
        #pragma unroll
        for (int t = 0; t < 2; ++t) {
            bf16x8 bfr = *(const bf16x8*)(Wf2t + ((t * 16 + m16) * 128 + kc * 32 + q * 8));
            acc2[t] = __builtin_amdgcn_mfma_f32_16x16x32_bf16(af, bfr, acc2[t], 0, 0, 0);
        }
    }
    // ---- layer 3: tanh, dot with Wf3, reduce over the 16 m-lanes ----
    float b2lo = bf2[m16], b2hi = bf2[m16 + 16];
    float w3lo = Wf3[m16], w3hi = Wf3[m16 + 16];
    float bf3v = bf3[0];
    #pragma unroll
    for (int r = 0; r < 4; ++r) {
        float t0 = tanhf(acc2[0][r] + b2lo);
        float t1 = tanhf(acc2[1][r] + b2hi);
        float v = t0 * w3lo + t1 * w3hi;
        v += __shfl_xor(v, 1);
        v += __shfl_xor(v, 2);
        v += __shfl_xor(v, 4);
        v += __shfl_xor(v, 8);
        if (m16 == 0) {
            int n = row0 + q * 4 + r;
            if (n < N) atomicAdd(&util_sum[batch[n]], v + bf3v);
        }
    }
}

// ---------------- util = sum / max(cnt,1) ----------------
__global__ void k_util(const float* __restrict__ util_sum, const int* __restrict__ cnt,
                       float* __restrict__ out_util, int G) {
    int g = blockIdx.x * 256 + threadIdx.x;
    if (g < G) {
        float c = (float)cnt[g];
        out_util[g] = util_sum[g] / fmaxf(c, 1.0f);
    }
}

// ---------------- pair sigmoid ----------------
__global__ void k_pairs(const float* __restrict__ u, const int* __restrict__ ia,
                        const int* __restrict__ ib, float* __restrict__ out, int P) {
    int p = blockIdx.x * 256 + threadIdx.x;
    if (p < P) {
        float d = u[ib[p]] - u[ia[p]];
        out[p] = 1.0f / (1.0f + expf(-d));
    }
}

extern "C" void kernel_launch(void* const* d_in, const int* in_sizes, int n_in,
                              void* d_out, int out_size, void* d_ws, size_t ws_size,
                              hipStream_t stream) {
    const float* x     = (const float*)d_in[0];
    const int*   eidx  = (const int*)d_in[1];
    const int*   batch = (const int*)d_in[2];
    const int*   idx_a = (const int*)d_in[3];
    const int*   idx_b = (const int*)d_in[4];
    const float* W_in  = (const float*)d_in[5];
    const float* b_in  = (const float*)d_in[6];
    const float* W1    = (const float*)d_in[7];
    const float* b1    = (const float*)d_in[8];
    const float* W2    = (const float*)d_in[9];
    const float* b2    = (const float*)d_in[10];
    const float* Wf1   = (const float*)d_in[11];
    const float* bf1   = (const float*)d_in[12];
    const float* Wf2   = (const float*)d_in[13];
    const float* bf2   = (const float*)d_in[14];
    const float* Wf3   = (const float*)d_in[15];
    const float* bf3   = (const float*)d_in[16];
    float* out = (float*)d_out;

    const int N = in_sizes[0] / 9;
    const int E = in_sizes[1] / 2;
    const int P = in_sizes[3];
    const int G = out_size - P;

    const int* src = eidx;
    const int* dst = eidx + E;

    // ---- workspace carve-out ----
    char* ws = (char*)d_ws;
    size_t off = 0;
    auto take = [&](size_t bytes) -> void* {
        void* p = ws + off;
        off = (off + bytes + 255) & ~(size_t)255;
        return p;
    };
    int*   deg      = (int*)  take((size_t)N * 4);
    float* dinv     = (float*)take((size_t)N * 4);
    int*   rowptr   = (int*)  take((size_t)(N + 1) * 4);
    int*   bsum     = (int*)  take(256 * 4);
    int*   cursor   = (int*)  take((size_t)N * 4);
    int*   csr_src  = (int*)  take((size_t)E * 4);
    float* xs       = (float*)take((size_t)N * 9 * 4);
    float* xa       = (float*)take((size_t)N * 9 * 4);
    unsigned short* bufA = (unsigned short*)take((size_t)N * U * 2);  // bf16 acts
    unsigned short* Tb   = (unsigned short*)take((size_t)N * U * 2);  // bf16 table
    unsigned short* W1t  = (unsigned short*)take(128 * 128 * 2);
    unsigned short* W2t  = (unsigned short*)take(128 * 128 * 2);
    unsigned short* Wf1t = (unsigned short*)take(128 * 128 * 2);
    unsigned short* Wf2t = (unsigned short*)take(32 * 128 * 2);
    float* util_sum = (float*)take((size_t)G * 4);
    int*   cnt      = (int*)  take((size_t)G * 4);
    (void)ws_size;

    hipMemsetAsync(deg, 0, (size_t)N * 4, stream);
    hipMemsetAsync(cursor, 0, (size_t)N * 4, stream);
    hipMemsetAsync(util_sum, 0, (size_t)G * 4, stream);
    hipMemsetAsync(cnt, 0, (size_t)G * 4, stream);

    const int nb = (N + 1023) / 1024;

    // ---- CSR build + weight prep ----
    k_deg<<<(E + 255) / 256, 256, 0, stream>>>(dst, deg, E);
    k_dinv<<<(N + 255) / 256, 256, 0, stream>>>(deg, dinv, N);
    k_scale_x<<<((size_t)N * 9 + 255) / 256, 256, 0, stream>>>(x, dinv, xs, N * 9);
    k_scan1<<<nb, 256, 0, stream>>>(deg, rowptr + 1, bsum, N);
    k_scan2<<<1, 256, 0, stream>>>(bsum, nb);
    k_scan3<<<(N + 255) / 256, 256, 0, stream>>>(rowptr, bsum, N);
    {
        dim3 g((E + 255) / 256, (N >> 13) + 1, 1);
        k_scatter<<<g, 256, 0, stream>>>(src, dst, rowptr, cursor, csr_src, E);
    }
    k_counts<<<(N + 255) / 256, 256, 0, stream>>>(batch, cnt, N);
    k_prep_w<<<208, 256, 0, stream>>>(W1, W2, Wf1, Wf2, W1t, W2t, Wf1t, Wf2t);

    const int aggGrid  = (N + 3) / 4;
    const int gemmGrid = (N + 63) / 64;

    // ---- GCN layer 1: aggregate xs (9-wide), then GEMM+bias+tanh -> bf16 ----
    k_aggx<<<(N + 15) / 16, 256, 0, stream>>>(xs, rowptr, csr_src, dinv, xa, N);
    k_gemm_in9<<<((size_t)N * U + 255) / 256, 256, 0, stream>>>(xa, W_in, b_in, bufA, N);

    // ---- GCN layer 2 ----
    k_gemm_mfma<<<gemmGrid, 256, 0, stream>>>(bufA, W1t, dinv, Tb, N);
    k_aggb<<<aggGrid, 256, 0, stream>>>(Tb, rowptr, csr_src, dinv, b1, bufA, N);
    // ---- GCN layer 3 ----
    k_gemm_mfma<<<gemmGrid, 256, 0, stream>>>(bufA, W2t, dinv, Tb, N);
    k_aggb<<<aggGrid, 256, 0, stream>>>(Tb, rowptr, csr_src, dinv, b2, bufA, N);

    // ---- MLP head + pooled sums ----
    k_mlp<<<gemmGrid, 256, 0, stream>>>(bufA, Wf1t, bf1, Wf2t, bf2, Wf3, bf3,
                                        batch, util_sum, N);

    // ---- util + pairs ----
    k_util<<<(G + 255) / 256, 256, 0, stream>>>(util_sum, cnt, out + P, G);
    k_pairs<<<(P + 255) / 256, 256, 0, stream>>>(out + P, idx_a, idx_b, out, P);
}

// Round 6
// 615.263 us; speedup vs baseline: 1.7036x; 1.0512x over previous
//
#include <hip/hip_runtime.h>
#include <hip/hip_bf16.h>
#include <math.h>

// ---------------------------------------------------------------------------
// RankGNN R6: XCD-affine windowed CSR build (window w owned by XCD w%8 via
// blockIdx%8 -> single-L2 write locality); aggb unroll 8; aggx unroll 4.
// ---------------------------------------------------------------------------

#define U 128
#define LDA 136    // LDS row stride in bf16 elems (128 + 8 pad)
#define SWB 13     // log2(scatter window) = 8192 nodes
#define SW  8192
#define NJ  256    // edge-chunk blocks per XCD-slot (grid = 8*NJ)

typedef __attribute__((ext_vector_type(8))) short bf16x8;
typedef __attribute__((ext_vector_type(4))) float f32x4;

__device__ __forceinline__ unsigned short f2bf(float f) {
    unsigned u = __float_as_uint(f);
    unsigned r = (u + 0x7fffu + ((u >> 16) & 1u)) >> 16;  // RNE
    return (unsigned short)r;
}
__device__ __forceinline__ float bf_lo(unsigned u) { return __uint_as_float(u << 16); }
__device__ __forceinline__ float bf_hi(unsigned u) { return __uint_as_float(u & 0xffff0000u); }

// ---------------- degree histogram (XCD-affine windowed) ----------------
__global__ __launch_bounds__(256) void k_deg(const int* __restrict__ dst,
                                             int* __restrict__ deg, int E, int nw) {
    int xcd = blockIdx.x & 7, j = blockIdx.x >> 3;
    int chunk = (E + NJ - 1) / NJ;
    int e0 = j * chunk, e1 = min(e0 + chunk, E);
    for (int w = xcd; w < nw; w += 8) {
        int lo = w << SWB, hi = lo + SW;
        for (int e = e0 + threadIdx.x; e < e1; e += 256) {
            int d = dst[e];
            if (d >= lo && d < hi) atomicAdd(&deg[d], 1);
        }
    }
}

__global__ void k_dinv(const int* __restrict__ deg, float* __restrict__ dinv, int N) {
    int i = blockIdx.x * 256 + threadIdx.x;
    if (i < N) dinv[i] = rsqrtf((float)deg[i] + 1.0f);
}

// xs = dinv[n] * x[n]  (N x 9)
__global__ void k_scale_x(const float* __restrict__ x, const float* __restrict__ dinv,
                          float* __restrict__ xs, int NE) {
    int t = blockIdx.x * 256 + threadIdx.x;
    if (t < NE) xs[t] = x[t] * dinv[t / 9];
}

// ---------------- exclusive scan (rowptr) ----------------
__global__ __launch_bounds__(256) void k_scan1(const int* __restrict__ deg,
                                               int* __restrict__ rowptr1,
                                               int* __restrict__ bsum, int N) {
    __shared__ int sc[256];
    int t = threadIdx.x, b = blockIdx.x;
    int base = b * 1024 + t * 4;
    int v[4];
    int s = 0;
    #pragma unroll
    for (int j = 0; j < 4; ++j) {
        int idx = base + j;
        int d = (idx < N) ? deg[idx] : 0;
        s += d;
        v[j] = s;
    }
    sc[t] = s;
    __syncthreads();
    for (int off = 1; off < 256; off <<= 1) {
        int x = (t >= off) ? sc[t - off] : 0;
        __syncthreads();
        sc[t] += x;
        __syncthreads();
    }
    int excl = sc[t] - s;
    #pragma unroll
    for (int j = 0; j < 4; ++j) {
        int idx = base + j;
        if (idx < N) rowptr1[idx] = v[j] + excl;
    }
    if (t == 255) bsum[b] = sc[255];
}

__global__ __launch_bounds__(256) void k_scan2(int* __restrict__ bsum, int nb) {
    __shared__ int sc[256];
    int t = threadIdx.x;
    int v = (t < nb) ? bsum[t] : 0;
    sc[t] = v;
    __syncthreads();
    for (int off = 1; off < 256; off <<= 1) {
        int x = (t >= off) ? sc[t - off] : 0;
        __syncthreads();
        sc[t] += x;
        __syncthreads();
    }
    if (t < nb) bsum[t] = sc[t] - v;  // exclusive
}

__global__ void k_scan3(int* __restrict__ rowptr, const int* __restrict__ boff, int N) {
    int i = blockIdx.x * 256 + threadIdx.x;
    if (i < N) rowptr[1 + i] += boff[i >> 10];
    if (i == 0) rowptr[0] = 0;
}

// ---------------- CSR scatter (XCD-affine windowed) ----------------
// Window w handled only by blocks with blockIdx%8 == w%8: all writes to its
// ~512 KB CSR slice come from one XCD's L2 -> one eviction per line. The
// block's dst chunk (~25 KB) stays L1-resident across its window visits.
__global__ __launch_bounds__(256) void k_scatter(const int* __restrict__ src,
                                                 const int* __restrict__ dst,
                                                 const int* __restrict__ rowptr,
                                                 int* __restrict__ cursor,
                                                 int* __restrict__ csr_src, int E, int nw) {
    int xcd = blockIdx.x & 7, j = blockIdx.x >> 3;
    int chunk = (E + NJ - 1) / NJ;
    int e0 = j * chunk, e1 = min(e0 + chunk, E);
    for (int w = xcd; w < nw; w += 8) {
        int lo = w << SWB, hi = lo + SW;
        for (int e = e0 + threadIdx.x; e < e1; e += 256) {
            int d = dst[e];
            if (d >= lo && d < hi) {
                int pos = atomicAdd(&cursor[d], 1);
                csr_src[rowptr[d] + pos] = src[e];
            }
        }
    }
}

// ---------------- per-graph node counts ----------------
__global__ void k_counts(const int* __restrict__ batch, int* __restrict__ cnt, int N) {
    int i = blockIdx.x * 256 + threadIdx.x;
    if (i < N) atomicAdd(&cnt[batch[i]], 1);
}

// ---------------- weight prep: transpose + bf16 ----------------
__global__ void k_prep_w(const float* __restrict__ W1, const float* __restrict__ W2,
                         const float* __restrict__ Wf1, const float* __restrict__ Wf2,
                         unsigned short* __restrict__ W1t, unsigned short* __restrict__ W2t,
                         unsigned short* __restrict__ Wf1t, unsigned short* __restrict__ Wf2t) {
    int t = blockIdx.x * 256 + threadIdx.x;
    if (t < 16384) {
        int n = t >> 7, k = t & 127;
        W1t[n * 128 + k] = f2bf(W1[k * 128 + n]);
    } else if (t < 32768) {
        int i = t - 16384, n = i >> 7, k = i & 127;
        W2t[n * 128 + k] = f2bf(W2[k * 128 + n]);
    } else if (t < 49152) {
        int i = t - 32768, n = i >> 7, k = i & 127;
        Wf1t[n * 128 + k] = f2bf(Wf1[k * 128 + n]);
    } else if (t < 53248) {
        int i = t - 49152, n = i >> 7, k = i & 127;
        Wf2t[n * 128 + k] = f2bf(Wf2[k * 32 + n]);
    }
}

// ---------------- layer-1: aggregate xs (N x 9), output dinv-scaled ---------
__global__ __launch_bounds__(256) void k_aggx(const float* __restrict__ xs,
                                              const int* __restrict__ rowptr,
                                              const int* __restrict__ csr_src,
                                              const float* __restrict__ dinv,
                                              float* __restrict__ xa, int N) {
    int node = blockIdx.x * 16 + (threadIdx.x >> 4);
    if (node >= N) return;
    int lane = threadIdx.x & 15;
    bool act = lane < 9;
    int s = rowptr[node], e = rowptr[node + 1];
    float a0 = 0.0f, a1 = 0.0f, a2 = 0.0f, a3 = 0.0f;
    int i = s;
    for (; i + 4 <= e; i += 4) {
        int s0 = csr_src[i], s1 = csr_src[i + 1];
        int s2 = csr_src[i + 2], s3 = csr_src[i + 3];
        if (act) {
            a0 += xs[s0 * 9 + lane];
            a1 += xs[s1 * 9 + lane];
            a2 += xs[s2 * 9 + lane];
            a3 += xs[s3 * 9 + lane];
        }
    }
    for (; i < e; ++i) {
        int s0 = csr_src[i];
        if (act) a0 += xs[s0 * 9 + lane];
    }
    if (act) {
        float dv = dinv[node];
        xa[node * 9 + lane] = dv * (a0 + a1 + a2 + a3 + xs[node * 9 + lane]);
    }
}

// ---------------- layer-1 GEMM: bf16(tanh(xa @ W_in + b)) ----------------
__global__ void k_gemm_in9(const float* __restrict__ xa, const float* __restrict__ Wi,
                           const float* __restrict__ bi, unsigned short* __restrict__ T,
                           int N) {
    int t = blockIdx.x * 256 + threadIdx.x;
    if (t < N * U) {
        int n = t >> 7, c = t & 127;
        const float* xr = xa + n * 9;
        float acc = bi[c];
        #pragma unroll
        for (int k = 0; k < 9; ++k) acc += xr[k] * Wi[k * U + c];
        T[t] = f2bf(tanhf(acc));
    }
}

// ---------------- MFMA GEMM (LDS-free, barrier-free) ----------------
__global__ __launch_bounds__(256) void k_gemm_mfma(const unsigned short* __restrict__ A,
                                                   const unsigned short* __restrict__ Wt,
                                                   const float* __restrict__ dinv,
                                                   unsigned short* __restrict__ Out, int N) {
    const int tid = threadIdx.x;
    const int wave = tid >> 6, lane = tid & 63;
    const int m16 = lane & 15, q = lane >> 4;
    const int row0 = blockIdx.x * 64 + wave * 16;
    int arow_idx = row0 + m16;
    if (arow_idx >= N) arow_idx = N - 1;  // clamp; OOB outputs are guarded
    const bf16x8* arow = (const bf16x8*)(A + (size_t)arow_idx * U + q * 8);
    f32x4 acc[8];
    #pragma unroll
    for (int t = 0; t < 8; ++t) acc[t] = (f32x4){0.f, 0.f, 0.f, 0.f};
    #pragma unroll
    for (int kc = 0; kc < 4; ++kc) {
        bf16x8 af = arow[kc * 4];
        #pragma unroll
        for (int t = 0; t < 8; ++t) {
            bf16x8 bfr = *(const bf16x8*)(Wt + ((t * 16 + m16) * 128 + kc * 32 + q * 8));
            acc[t] = __builtin_amdgcn_mfma_f32_16x16x32_bf16(af, bfr, acc[t], 0, 0, 0);
        }
    }
    float dv[4];
    #pragma unroll
    for (int r = 0; r < 4; ++r) {
        int gr = row0 + q * 4 + r;
        dv[r] = (gr < N) ? dinv[gr] : 0.0f;
    }
    #pragma unroll
    for (int t = 0; t < 8; ++t) {
        #pragma unroll
        for (int r = 0; r < 4; ++r) {
            int gr = row0 + q * 4 + r;
            if (gr < N) Out[(size_t)gr * U + t * 16 + m16] = f2bf(acc[t][r] * dv[r]);
        }
    }
}

// ---------------- aggregation: h = tanh(dinv[d]*(sum Ts + Ts[d]) + b) -------
// unroll 8: 8 outstanding 256B row-gathers per wave (latency-bound kernel)
__global__ __launch_bounds__(256) void k_aggb(const unsigned short* __restrict__ Tb,
                                              const int* __restrict__ rowptr,
                                              const int* __restrict__ csr_src,
                                              const float* __restrict__ dinv,
                                              const float* __restrict__ bias,
                                              unsigned short* __restrict__ Out, int N) {
    int node = blockIdx.x * 4 + (threadIdx.x >> 6);
    if (node >= N) return;
    int lane = threadIdx.x & 63;
    const unsigned* T32 = (const unsigned*)Tb;
    float ax = 0.0f, ay = 0.0f, bx = 0.0f, by = 0.0f;
    int s = rowptr[node], e = rowptr[node + 1];
    int i = s;
    for (; i + 8 <= e; i += 8) {
        int idx[8];
        #pragma unroll
        for (int u = 0; u < 8; ++u) idx[u] = csr_src[i + u];
        unsigned uv[8];
        #pragma unroll
        for (int u = 0; u < 8; ++u) uv[u] = T32[idx[u] * 64 + lane];
        #pragma unroll
        for (int u = 0; u < 8; u += 2) {
            ax += bf_lo(uv[u]) + bf_lo(uv[u + 1]);
            ay += bf_hi(uv[u]) + bf_hi(uv[u + 1]);
        }
    }
    for (; i + 4 <= e; i += 4) {
        int s0 = csr_src[i], s1 = csr_src[i + 1];
        int s2 = csr_src[i + 2], s3 = csr_src[i + 3];
        unsigned u0 = T32[s0 * 64 + lane];
        unsigned u1 = T32[s1 * 64 + lane];
        unsigned u2 = T32[s2 * 64 + lane];
        unsigned u3 = T32[s3 * 64 + lane];
        ax += bf_lo(u0) + bf_lo(u1);
        ay += bf_hi(u0) + bf_hi(u1);
        bx += bf_lo(u2) + bf_lo(u3);
        by += bf_hi(u2) + bf_hi(u3);
    }
    for (; i < e; ++i) {
        int s0 = csr_src[i];
        unsigned u0 = T32[s0 * 64 + lane];
        ax += bf_lo(u0);
        ay += bf_hi(u0);
    }
    float dv = dinv[node];
    unsigned su = T32[node * 64 + lane];
    float2 bb = *(const float2*)&bias[lane * 2];
    float ox = tanhf(dv * (ax + bx + bf_lo(su)) + bb.x);
    float oy = tanhf(dv * (ay + by + bf_hi(su)) + bb.y);
    unsigned o = (unsigned)f2bf(ox) | ((unsigned)f2bf(oy) << 16);
    ((unsigned*)Out)[node * 64 + lane] = o;
}

// ---------------- fused MFMA MLP head (barrier-free) ----------------
__global__ __launch_bounds__(256) void k_mlp(const unsigned short* __restrict__ H,
                                             const unsigned short* __restrict__ Wf1t,
                                             const float* __restrict__ bf1,
                                             const unsigned short* __restrict__ Wf2t,
                                             const float* __restrict__ bf2,
                                             const float* __restrict__ Wf3,
                                             const float* __restrict__ bf3,
                                             const int* __restrict__ batch,
                                             float* __restrict__ util_sum, int N) {
    __shared__ unsigned short H2[64 * LDA];  // wave-local 16-row slices
    const int tid = threadIdx.x;
    const int wave = tid >> 6, lane = tid & 63;
    const int m16 = lane & 15, q = lane >> 4;
    const int row0 = blockIdx.x * 64 + wave * 16;
    int arow_idx = row0 + m16;
    if (arow_idx >= N) arow_idx = N - 1;
    const bf16x8* arow = (const bf16x8*)(H + (size_t)arow_idx * U + q * 8);
    f32x4 acc[8];
    #pragma unroll
    for (int t = 0; t < 8; ++t) acc[t] = (f32x4){0.f, 0.f, 0.f, 0.f};
    #pragma unroll
    for (int kc = 0; kc < 4; ++kc) {
        bf16x8 af = arow[kc * 4];
        #pragma unroll
        for (int t = 0; t < 8; ++t) {
            bf16x8 bfr = *(const bf16x8*)(Wf1t + ((t * 16 + m16) * 128 + kc * 32 + q * 8));
            acc[t] = __builtin_amdgcn_mfma_f32_16x16x32_bf16(af, bfr, acc[t], 0, 0, 0);
        }
    }
    #pragma unroll
    for (int t = 0; t < 8; ++t) {
        float b = bf1[t * 16 + m16];
        #pragma unroll
        for (int r = 0; r < 4; ++r) {
            int lr = wave * 16 + q * 4 + r;
            H2[lr * LDA + t * 16 + m16] = f2bf(tanhf(acc[t][r] + b));
        }
    }
    f32x4 acc2[2];
    acc2[0] = (f32x4){0.f, 0.f, 0.f, 0.f};
    acc2[1] = (f32x4){0.f, 0.f, 0.f, 0.f};
    const unsigned short* h2row = &H2[(wave * 16 + m16) * LDA + q * 8];
    #pragma unroll
    for (int kc = 0; kc < 4; ++kc) {
        bf16x8 af = *(const bf16x8*)(h2row + kc * 32);
        #pragma unroll
        for (int t = 0; t < 2; ++t) {
            bf16x8 bfr = *(const bf16x8*)(Wf2t + ((t * 16 + m16) * 128 + kc * 32 + q * 8));
            acc2[t] = __builtin_amdgcn_mfma_f32_16x16x32_bf16(af, bfr, acc2[t], 0, 0, 0);
        }
    }
    float b2lo = bf2[m16], b2hi = bf2[m16 + 16];
    float w3lo = Wf3[m16], w3hi = Wf3[m16 + 16];
    float bf3v = bf3[0];
    #pragma unroll
    for (int r = 0; r < 4; ++r) {
        float t0 = tanhf(acc2[0][r] + b2lo);
        float t1 = tanhf(acc2[1][r] + b2hi);
        float v = t0 * w3lo + t1 * w3hi;
        v += __shfl_xor(v, 1);
        v += __shfl_xor(v, 2);
        v += __shfl_xor(v, 4);
        v += __shfl_xor(v, 8);
        if (m16 == 0) {
            int n = row0 + q * 4 + r;
            if (n < N) atomicAdd(&util_sum[batch[n]], v + bf3v);
        }
    }
}

// ---------------- util = sum / max(cnt,1) ----------------
__global__ void k_util(const float* __restrict__ util_sum, const int* __restrict__ cnt,
                       float* __restrict__ out_util, int G) {
    int g = blockIdx.x * 256 + threadIdx.x;
    if (g < G) {
        float c = (float)cnt[g];
        out_util[g] = util_sum[g] / fmaxf(c, 1.0f);
    }
}

// ---------------- pair sigmoid ----------------
__global__ void k_pairs(const float* __restrict__ u, const int* __restrict__ ia,
                        const int* __restrict__ ib, float* __restrict__ out, int P) {
    int p = blockIdx.x * 256 + threadIdx.x;
    if (p < P) {
        float d = u[ib[p]] - u[ia[p]];
        out[p] = 1.0f / (1.0f + expf(-d));
    }
}

extern "C" void kernel_launch(void* const* d_in, const int* in_sizes, int n_in,
                              void* d_out, int out_size, void* d_ws, size_t ws_size,
                              hipStream_t stream) {
    const float* x     = (const float*)d_in[0];
    const int*   eidx  = (const int*)d_in[1];
    const int*   batch = (const int*)d_in[2];
    const int*   idx_a = (const int*)d_in[3];
    const int*   idx_b = (const int*)d_in[4];
    const float* W_in  = (const float*)d_in[5];
    const float* b_in  = (const float*)d_in[6];
    const float* W1    = (const float*)d_in[7];
    const float* b1    = (const float*)d_in[8];
    const float* W2    = (const float*)d_in[9];
    const float* b2    = (const float*)d_in[10];
    const float* Wf1   = (const float*)d_in[11];
    const float* bf1   = (const float*)d_in[12];
    const float* Wf2   = (const float*)d_in[13];
    const float* bf2   = (const float*)d_in[14];
    const float* Wf3   = (const float*)d_in[15];
    const float* bf3   = (const float*)d_in[16];
    float* out = (float*)d_out;

    const int N = in_sizes[0] / 9;
    const int E = in_sizes[1] / 2;
    const int P = in_sizes[3];
    const int G = out_size - P;

    const int* src = eidx;
    const int* dst = eidx + E;

    // ---- workspace carve-out ----
    char* ws = (char*)d_ws;
    size_t off = 0;
    auto take = [&](size_t bytes) -> void* {
        void* p = ws + off;
        off = (off + bytes + 255) & ~(size_t)255;
        return p;
    };
    int*   deg      = (int*)  take((size_t)N * 4);
    float* dinv     = (float*)take((size_t)N * 4);
    int*   rowptr   = (int*)  take((size_t)(N + 1) * 4);
    int*   bsum     = (int*)  take(256 * 4);
    int*   cursor   = (int*)  take((size_t)N * 4);
    int*   csr_src  = (int*)  take((size_t)E * 4);
    float* xs       = (float*)take((size_t)N * 9 * 4);
    float* xa       = (float*)take((size_t)N * 9 * 4);
    unsigned short* bufA = (unsigned short*)take((size_t)N * U * 2);  // bf16 acts
    unsigned short* Tb   = (unsigned short*)take((size_t)N * U * 2);  // bf16 table
    unsigned short* W1t  = (unsigned short*)take(128 * 128 * 2);
    unsigned short* W2t  = (unsigned short*)take(128 * 128 * 2);
    unsigned short* Wf1t = (unsigned short*)take(128 * 128 * 2);
    unsigned short* Wf2t = (unsigned short*)take(32 * 128 * 2);
    float* util_sum = (float*)take((size_t)G * 4);
    int*   cnt      = (int*)  take((size_t)G * 4);
    (void)ws_size;

    hipMemsetAsync(deg, 0, (size_t)N * 4, stream);
    hipMemsetAsync(cursor, 0, (size_t)N * 4, stream);
    hipMemsetAsync(util_sum, 0, (size_t)G * 4, stream);
    hipMemsetAsync(cnt, 0, (size_t)G * 4, stream);

    const int nb = (N + 1023) / 1024;
    const int nw = (N + SW - 1) / SW;

    // ---- CSR build + weight prep ----
    k_deg<<<8 * NJ, 256, 0, stream>>>(dst, deg, E, nw);
    k_dinv<<<(N + 255) / 256, 256, 0, stream>>>(deg, dinv, N);
    k_scale_x<<<((size_t)N * 9 + 255) / 256, 256, 0, stream>>>(x, dinv, xs, N * 9);
    k_scan1<<<nb, 256, 0, stream>>>(deg, rowptr + 1, bsum, N);
    k_scan2<<<1, 256, 0, stream>>>(bsum, nb);
    k_scan3<<<(N + 255) / 256, 256, 0, stream>>>(rowptr, bsum, N);
    k_scatter<<<8 * NJ, 256, 0, stream>>>(src, dst, rowptr, cursor, csr_src, E, nw);
    k_counts<<<(N + 255) / 256, 256, 0, stream>>>(batch, cnt, N);
    k_prep_w<<<208, 256, 0, stream>>>(W1, W2, Wf1, Wf2, W1t, W2t, Wf1t, Wf2t);

    const int aggGrid  = (N + 3) / 4;
    const int gemmGrid = (N + 63) / 64;

    // ---- GCN layer 1: aggregate xs (9-wide), then GEMM+bias+tanh -> bf16 ----
    k_aggx<<<(N + 15) / 16, 256, 0, stream>>>(xs, rowptr, csr_src, dinv, xa, N);
    k_gemm_in9<<<((size_t)N * U + 255) / 256, 256, 0, stream>>>(xa, W_in, b_in, bufA, N);

    // ---- GCN layer 2 ----
    k_gemm_mfma<<<gemmGrid, 256, 0, stream>>>(bufA, W1t, dinv, Tb, N);
    k_aggb<<<aggGrid, 256, 0, stream>>>(Tb, rowptr, csr_src, dinv, b1, bufA, N);
    // ---- GCN layer 3 ----
    k_gemm_mfma<<<gemmGrid, 256, 0, stream>>>(bufA, W2t, dinv, Tb, N);
    k_aggb<<<aggGrid, 256, 0, stream>>>(Tb, rowptr, csr_src, dinv, b2, bufA, N);

    // ---- MLP head + pooled sums ----
    k_mlp<<<gemmGrid, 256, 0, stream>>>(bufA, Wf1t, bf1, Wf2t, bf2, Wf3, bf3,
                                        batch, util_sum, N);

    // ---- util + pairs ----
    k_util<<<(G + 255) / 256, 256, 0, stream>>>(util_sum, cnt, out + P, G);
    k_pairs<<<(P + 255) / 256, 256, 0, stream>>>(out + P, idx_a, idx_b, out, P);
}

// Round 7
// 593.135 us; speedup vs baseline: 1.7672x; 1.0373x over previous
//
#include <hip/hip_runtime.h>
#include <hip/hip_bf16.h>
#include <math.h>

// ---------------------------------------------------------------------------
// RankGNN R7: CSR build rebuilt as two-level counting sort (atomic-light,
// single-writer csr windows -> no write amplification); kernel fusion
// (prep, scan23, out); single memset.
// ---------------------------------------------------------------------------

#define U 128
#define LDA 136    // LDS row stride in bf16 elems (128 + 8 pad)
#define WB 9       // log2(window) = 512 nodes per level-2 window
#define WSZ 512
#define NJ1 256    // level-1 blocks (edge chunks)

typedef __attribute__((ext_vector_type(8))) short bf16x8;
typedef __attribute__((ext_vector_type(4))) float f32x4;

__device__ __forceinline__ unsigned short f2bf(float f) {
    unsigned u = __float_as_uint(f);
    unsigned r = (u + 0x7fffu + ((u >> 16) & 1u)) >> 16;  // RNE
    return (unsigned short)r;
}
__device__ __forceinline__ float bf_lo(unsigned u) { return __uint_as_float(u << 16); }
__device__ __forceinline__ float bf_hi(unsigned u) { return __uint_as_float(u & 0xffff0000u); }

// ---------------- level-1: per-chunk window histogram ----------------
__global__ __launch_bounds__(256) void k_hist1(const int* __restrict__ dst,
                                               int* __restrict__ hist_g, int E, int nw) {
    __shared__ int h[256];  // nw <= 256
    int b = blockIdx.x;
    for (int i = threadIdx.x; i < nw; i += 256) h[i] = 0;
    __syncthreads();
    int ch = (E + NJ1 - 1) / NJ1;
    int e0 = b * ch, e1 = min(e0 + ch, E);
    for (int e = e0 + threadIdx.x; e < e1; e += 256)
        atomicAdd(&h[dst[e] >> WB], 1);
    __syncthreads();
    for (int w = threadIdx.x; w < nw; w += 256) hist_g[w * NJ1 + b] = h[w];
}

// ---------------- exclusive scan of hist_g (nw*256 values, 1 block) ---------
__global__ __launch_bounds__(256) void k_scanh(int* __restrict__ hist_g, int nw) {
    __shared__ int ps[256];
    int t = threadIdx.x;
    int n = nw;  // per-thread chunk (flat layout is [w][b], chunk = t*nw..)
    int base = t * n;
    int s = 0;
    for (int i = 0; i < n; ++i) s += hist_g[base + i];
    ps[t] = s;
    __syncthreads();
    for (int off = 1; off < 256; off <<= 1) {
        int v = (t >= off) ? ps[t - off] : 0;
        __syncthreads();
        ps[t] += v;
        __syncthreads();
    }
    int ex = ps[t] - s;
    for (int i = 0; i < n; ++i) {
        int v = hist_g[base + i];
        hist_g[base + i] = ex;
        ex += v;
    }
}

// ---------------- level-1: bucket edges window-major ----------------
__global__ __launch_bounds__(256) void k_bucket(const int* __restrict__ src,
                                                const int* __restrict__ dst,
                                                const int* __restrict__ hist_g,
                                                int2* __restrict__ eb, int E, int nw) {
    __shared__ int lcur[256];
    int b = blockIdx.x;
    for (int w = threadIdx.x; w < nw; w += 256) lcur[w] = hist_g[w * NJ1 + b];
    __syncthreads();
    int ch = (E + NJ1 - 1) / NJ1;
    int e0 = b * ch, e1 = min(e0 + ch, E);
    for (int e = e0 + threadIdx.x; e < e1; e += 256) {
        int d = dst[e];
        int pos = atomicAdd(&lcur[d >> WB], 1);
        eb[pos] = make_int2(src[e], d);
    }
}

// ---------------- level-2: per-window degree histogram -> deg ---------------
__global__ __launch_bounds__(256) void k_deg2(const int2* __restrict__ eb,
                                              const int* __restrict__ hist_g,
                                              int* __restrict__ deg, int E, int nw, int N) {
    __shared__ int h[WSZ];
    int w = blockIdx.x;
    h[threadIdx.x] = 0;
    h[threadIdx.x + 256] = 0;
    __syncthreads();
    int s0 = hist_g[w * NJ1];
    int s1 = (w + 1 < nw) ? hist_g[(w + 1) * NJ1] : E;
    for (int i = s0 + threadIdx.x; i < s1; i += 256)
        atomicAdd(&h[eb[i].y & (WSZ - 1)], 1);
    __syncthreads();
    int base = w << WB;
    if (base + threadIdx.x < N) deg[base + threadIdx.x] = h[threadIdx.x];
    if (base + 256 + threadIdx.x < N) deg[base + 256 + threadIdx.x] = h[256 + threadIdx.x];
}

// ---------------- rowptr scan ----------------
__global__ __launch_bounds__(256) void k_scan1(const int* __restrict__ deg,
                                               int* __restrict__ rowptr1,
                                               int* __restrict__ bsum, int N) {
    __shared__ int sc[256];
    int t = threadIdx.x, b = blockIdx.x;
    int base = b * 1024 + t * 4;
    int v[4];
    int s = 0;
    #pragma unroll
    for (int j = 0; j < 4; ++j) {
        int idx = base + j;
        int d = (idx < N) ? deg[idx] : 0;
        s += d;
        v[j] = s;
    }
    sc[t] = s;
    __syncthreads();
    for (int off = 1; off < 256; off <<= 1) {
        int x = (t >= off) ? sc[t - off] : 0;
        __syncthreads();
        sc[t] += x;
        __syncthreads();
    }
    int excl = sc[t] - s;
    #pragma unroll
    for (int j = 0; j < 4; ++j) {
        int idx = base + j;
        if (idx < N) rowptr1[idx] = v[j] + excl;
    }
    if (t == 255) bsum[b] = sc[255];
}

// scan2+scan3 fused: every block redundantly scans bsum (nb<=256), then adds.
__global__ __launch_bounds__(256) void k_scan23(int* __restrict__ rowptr,
                                                const int* __restrict__ bsum,
                                                int nb, int N) {
    __shared__ int sc[256];
    __shared__ int bo[256];
    int t = threadIdx.x;
    int v = (t < nb) ? bsum[t] : 0;
    sc[t] = v;
    __syncthreads();
    for (int off = 1; off < 256; off <<= 1) {
        int u = (t >= off) ? sc[t - off] : 0;
        __syncthreads();
        sc[t] += u;
        __syncthreads();
    }
    bo[t] = sc[t] - v;  // exclusive
    __syncthreads();
    int i = blockIdx.x * 256 + t;
    if (i < N) rowptr[1 + i] += bo[i >> 10];
    if (i == 0) rowptr[0] = 0;
}

// ---------------- level-2: single-writer CSR scatter ----------------
__global__ __launch_bounds__(256) void k_scatter2(const int2* __restrict__ eb,
                                                  const int* __restrict__ hist_g,
                                                  const int* __restrict__ rowptr,
                                                  int* __restrict__ csr_src,
                                                  int E, int nw, int N) {
    __shared__ int cur[WSZ];
    int w = blockIdx.x;
    int base = w << WB;
    int i0 = base + threadIdx.x, i1 = base + 256 + threadIdx.x;
    cur[threadIdx.x] = (i0 < N) ? rowptr[i0] : 0;
    cur[threadIdx.x + 256] = (i1 < N) ? rowptr[i1] : 0;
    __syncthreads();
    int s0 = hist_g[w * NJ1];
    int s1 = (w + 1 < nw) ? hist_g[(w + 1) * NJ1] : E;
    for (int i = s0 + threadIdx.x; i < s1; i += 256) {
        int2 e = eb[i];
        int pos = atomicAdd(&cur[e.y & (WSZ - 1)], 1);
        csr_src[pos] = e.x;
    }
}

// ---------------- fused prep: dinv, xs, counts, weight transpose ------------
__global__ __launch_bounds__(256) void k_prep(const int* __restrict__ deg,
                                              const float* __restrict__ x,
                                              const int* __restrict__ batch,
                                              const float* __restrict__ W1,
                                              const float* __restrict__ W2,
                                              const float* __restrict__ Wf1,
                                              const float* __restrict__ Wf2,
                                              float* __restrict__ dinv,
                                              float* __restrict__ xs,
                                              int* __restrict__ cnt,
                                              unsigned short* __restrict__ W1t,
                                              unsigned short* __restrict__ W2t,
                                              unsigned short* __restrict__ Wf1t,
                                              unsigned short* __restrict__ Wf2t, int N) {
    int t = blockIdx.x * 256 + threadIdx.x;
    if (t < N) {
        float dv = rsqrtf((float)deg[t] + 1.0f);
        dinv[t] = dv;
        #pragma unroll
        for (int k = 0; k < 9; ++k) xs[t * 9 + k] = x[t * 9 + k] * dv;
        atomicAdd(&cnt[batch[t]], 1);
    }
    if (t < 16384) {
        int n = t >> 7, k = t & 127;
        W1t[n * 128 + k] = f2bf(W1[k * 128 + n]);
        Wf1t[n * 128 + k] = f2bf(Wf1[k * 128 + n]);
    } else if (t < 32768) {
        int i = t - 16384, n = i >> 7, k = i & 127;
        W2t[n * 128 + k] = f2bf(W2[k * 128 + n]);
    } else if (t < 36864) {
        int i = t - 32768, n = i >> 7, k = i & 127;
        Wf2t[n * 128 + k] = f2bf(Wf2[k * 32 + n]);
    }
}

// ---------------- layer-1: aggregate xs (N x 9), output dinv-scaled ---------
__global__ __launch_bounds__(256) void k_aggx(const float* __restrict__ xs,
                                              const int* __restrict__ rowptr,
                                              const int* __restrict__ csr_src,
                                              const float* __restrict__ dinv,
                                              float* __restrict__ xa, int N) {
    int node = blockIdx.x * 16 + (threadIdx.x >> 4);
    if (node >= N) return;
    int lane = threadIdx.x & 15;
    bool act = lane < 9;
    int s = rowptr[node], e = rowptr[node + 1];
    float a0 = 0.0f, a1 = 0.0f, a2 = 0.0f, a3 = 0.0f;
    int i = s;
    for (; i + 4 <= e; i += 4) {
        int s0 = csr_src[i], s1 = csr_src[i + 1];
        int s2 = csr_src[i + 2], s3 = csr_src[i + 3];
        if (act) {
            a0 += xs[s0 * 9 + lane];
            a1 += xs[s1 * 9 + lane];
            a2 += xs[s2 * 9 + lane];
            a3 += xs[s3 * 9 + lane];
        }
    }
    for (; i < e; ++i) {
        int s0 = csr_src[i];
        if (act) a0 += xs[s0 * 9 + lane];
    }
    if (act) {
        float dv = dinv[node];
        xa[node * 9 + lane] = dv * (a0 + a1 + a2 + a3 + xs[node * 9 + lane]);
    }
}

// ---------------- layer-1 GEMM: bf16(tanh(xa @ W_in + b)) ----------------
__global__ void k_gemm_in9(const float* __restrict__ xa, const float* __restrict__ Wi,
                           const float* __restrict__ bi, unsigned short* __restrict__ T,
                           int N) {
    int t = blockIdx.x * 256 + threadIdx.x;
    if (t < N * U) {
        int n = t >> 7, c = t & 127;
        const float* xr = xa + n * 9;
        float acc = bi[c];
        #pragma unroll
        for (int k = 0; k < 9; ++k) acc += xr[k] * Wi[k * U + c];
        T[t] = f2bf(tanhf(acc));
    }
}

// ---------------- MFMA GEMM (LDS-free, barrier-free) ----------------
__global__ __launch_bounds__(256) void k_gemm_mfma(const unsigned short* __restrict__ A,
                                                   const unsigned short* __restrict__ Wt,
                                                   const float* __restrict__ dinv,
                                                   unsigned short* __restrict__ Out, int N) {
    const int tid = threadIdx.x;
    const int wave = tid >> 6, lane = tid & 63;
    const int m16 = lane & 15, q = lane >> 4;
    const int row0 = blockIdx.x * 64 + wave * 16;
    int arow_idx = row0 + m16;
    if (arow_idx >= N) arow_idx = N - 1;  // clamp; OOB outputs are guarded
    const bf16x8* arow = (const bf16x8*)(A + (size_t)arow_idx * U + q * 8);
    f32x4 acc[8];
    #pragma unroll
    for (int t = 0; t < 8; ++t) acc[t] = (f32x4){0.f, 0.f, 0.f, 0.f};
    #pragma unroll
    for (int kc = 0; kc < 4; ++kc) {
        bf16x8 af = arow[kc * 4];
        #pragma unroll
        for (int t = 0; t < 8; ++t) {
            bf16x8 bfr = *(const bf16x8*)(Wt + ((t * 16 + m16) * 128 + kc * 32 + q * 8));
            acc[t] = __builtin_amdgcn_mfma_f32_16x16x32_bf16(af, bfr, acc[t], 0, 0, 0);
        }
    }
    float dv[4];
    #pragma unroll
    for (int r = 0; r < 4; ++r) {
        int gr = row0 + q * 4 + r;
        dv[r] = (gr < N) ? dinv[gr] : 0.0f;
    }
    #pragma unroll
    for (int t = 0; t < 8; ++t) {
        #pragma unroll
        for (int r = 0; r < 4; ++r) {
            int gr = row0 + q * 4 + r;
            if (gr < N) Out[(size_t)gr * U + t * 16 + m16] = f2bf(acc[t][r] * dv[r]);
        }
    }
}

// ---------------- aggregation: h = tanh(dinv[d]*(sum Ts + Ts[d]) + b) -------
__global__ __launch_bounds__(256) void k_aggb(const unsigned short* __restrict__ Tb,
                                              const int* __restrict__ rowptr,
                                              const int* __restrict__ csr_src,
                                              const float* __restrict__ dinv,
                                              const float* __restrict__ bias,
                                              unsigned short* __restrict__ Out, int N) {
    int node = blockIdx.x * 4 + (threadIdx.x >> 6);
    if (node >= N) return;
    int lane = threadIdx.x & 63;
    const unsigned* T32 = (const unsigned*)Tb;
    float ax = 0.0f, ay = 0.0f, bx = 0.0f, by = 0.0f;
    int s = rowptr[node], e = rowptr[node + 1];
    int i = s;
    for (; i + 8 <= e; i += 8) {
        int idx[8];
        #pragma unroll
        for (int u = 0; u < 8; ++u) idx[u] = csr_src[i + u];
        unsigned uv[8];
        #pragma unroll
        for (int u = 0; u < 8; ++u) uv[u] = T32[idx[u] * 64 + lane];
        #pragma unroll
        for (int u = 0; u < 8; u += 2) {
            ax += bf_lo(uv[u]) + bf_lo(uv[u + 1]);
            ay += bf_hi(uv[u]) + bf_hi(uv[u + 1]);
        }
    }
    for (; i + 4 <= e; i += 4) {
        int s0 = csr_src[i], s1 = csr_src[i + 1];
        int s2 = csr_src[i + 2], s3 = csr_src[i + 3];
        unsigned u0 = T32[s0 * 64 + lane];
        unsigned u1 = T32[s1 * 64 + lane];
        unsigned u2 = T32[s2 * 64 + lane];
        unsigned u3 = T32[s3 * 64 + lane];
        ax += bf_lo(u0) + bf_lo(u1);
        ay += bf_hi(u0) + bf_hi(u1);
        bx += bf_lo(u2) + bf_lo(u3);
        by += bf_hi(u2) + bf_hi(u3);
    }
    for (; i < e; ++i) {
        int s0 = csr_src[i];
        unsigned u0 = T32[s0 * 64 + lane];
        ax += bf_lo(u0);
        ay += bf_hi(u0);
    }
    float dv = dinv[node];
    unsigned su = T32[node * 64 + lane];
    float2 bb = *(const float2*)&bias[lane * 2];
    float ox = tanhf(dv * (ax + bx + bf_lo(su)) + bb.x);
    float oy = tanhf(dv * (ay + by + bf_hi(su)) + bb.y);
    unsigned o = (unsigned)f2bf(ox) | ((unsigned)f2bf(oy) << 16);
    ((unsigned*)Out)[node * 64 + lane] = o;
}

// ---------------- fused MFMA MLP head (barrier-free) ----------------
__global__ __launch_bounds__(256) void k_mlp(const unsigned short* __restrict__ H,
                                             const unsigned short* __restrict__ Wf1t,
                                             const float* __restrict__ bf1,
                                             const unsigned short* __restrict__ Wf2t,
                                             const float* __restrict__ bf2,
                                             const float* __restrict__ Wf3,
                                             const float* __restrict__ bf3,
                                             const int* __restrict__ batch,
                                             float* __restrict__ util_sum, int N) {
    __shared__ unsigned short H2[64 * LDA];  // wave-local 16-row slices
    const int tid = threadIdx.x;
    const int wave = tid >> 6, lane = tid & 63;
    const int m16 = lane & 15, q = lane >> 4;
    const int row0 = blockIdx.x * 64 + wave * 16;
    int arow_idx = row0 + m16;
    if (arow_idx >= N) arow_idx = N - 1;
    const bf16x8* arow = (const bf16x8*)(H + (size_t)arow_idx * U + q * 8);
    f32x4 acc[8];
    #pragma unroll
    for (int t = 0; t < 8; ++t) acc[t] = (f32x4){0.f, 0.f, 0.f, 0.f};
    #pragma unroll
    for (int kc = 0; kc < 4; ++kc) {
        bf16x8 af = arow[kc * 4];
        #pragma unroll
        for (int t = 0; t < 8; ++t) {
            bf16x8 bfr = *(const bf16x8*)(Wf1t + ((t * 16 + m16) * 128 + kc * 32 + q * 8));
            acc[t] = __builtin_amdgcn_mfma_f32_16x16x32_bf16(af, bfr, acc[t], 0, 0, 0);
        }
    }
    #pragma unroll
    for (int t = 0; t < 8; ++t) {
        float b = bf1[t * 16 + m16];
        #pragma unroll
        for (int r = 0; r < 4; ++r) {
            int lr = wave * 16 + q * 4 + r;
            H2[lr * LDA + t * 16 + m16] = f2bf(tanhf(acc[t][r] + b));
        }
    }
    f32x4 acc2[2];
    acc2[0] = (f32x4){0.f, 0.f, 0.f, 0.f};
    acc2[1] = (f32x4){0.f, 0.f, 0.f, 0.f};
    const unsigned short* h2row = &H2[(wave * 16 + m16) * LDA + q * 8];
    #pragma unroll
    for (int kc = 0; kc < 4; ++kc) {
        bf16x8 af = *(const bf16x8*)(h2row + kc * 32);
        #pragma unroll
        for (int t = 0; t < 2; ++t) {
            bf16x8 bfr = *(const bf16x8*)(Wf2t + ((t * 16 + m16) * 128 + kc * 32 + q * 8));
            acc2[t] = __builtin_amdgcn_mfma_f32_16x16x32_bf16(af, bfr, acc2[t], 0, 0, 0);
        }
    }
    float b2lo = bf2[m16], b2hi = bf2[m16 + 16];
    float w3lo = Wf3[m16], w3hi = Wf3[m16 + 16];
    float bf3v = bf3[0];
    #pragma unroll
    for (int r = 0; r < 4; ++r) {
        float t0 = tanhf(acc2[0][r] + b2lo);
        float t1 = tanhf(acc2[1][r] + b2hi);
        float v = t0 * w3lo + t1 * w3hi;
        v += __shfl_xor(v, 1);
        v += __shfl_xor(v, 2);
        v += __shfl_xor(v, 4);
        v += __shfl_xor(v, 8);
        if (m16 == 0) {
            int n = row0 + q * 4 + r;
            if (n < N) atomicAdd(&util_sum[batch[n]], v + bf3v);
        }
    }
}

// ---------------- fused output: util + pair sigmoid ----------------
__global__ void k_out(const float* __restrict__ us, const int* __restrict__ cnt,
                      const int* __restrict__ ia, const int* __restrict__ ib,
                      float* __restrict__ out, int P, int G) {
    int t = blockIdx.x * 256 + threadIdx.x;
    if (t < G) out[P + t] = us[t] / fmaxf((float)cnt[t], 1.0f);
    if (t < P) {
        int a = ia[t], b = ib[t];
        float ua = us[a] / fmaxf((float)cnt[a], 1.0f);
        float ub = us[b] / fmaxf((float)cnt[b], 1.0f);
        out[t] = 1.0f / (1.0f + expf(-(ub - ua)));
    }
}

extern "C" void kernel_launch(void* const* d_in, const int* in_sizes, int n_in,
                              void* d_out, int out_size, void* d_ws, size_t ws_size,
                              hipStream_t stream) {
    const float* x     = (const float*)d_in[0];
    const int*   eidx  = (const int*)d_in[1];
    const int*   batch = (const int*)d_in[2];
    const int*   idx_a = (const int*)d_in[3];
    const int*   idx_b = (const int*)d_in[4];
    const float* W_in  = (const float*)d_in[5];
    const float* b_in  = (const float*)d_in[6];
    const float* W1    = (const float*)d_in[7];
    const float* b1    = (const float*)d_in[8];
    const float* W2    = (const float*)d_in[9];
    const float* b2    = (const float*)d_in[10];
    const float* Wf1   = (const float*)d_in[11];
    const float* bf1   = (const float*)d_in[12];
    const float* Wf2   = (const float*)d_in[13];
    const float* bf2   = (const float*)d_in[14];
    const float* Wf3   = (const float*)d_in[15];
    const float* bf3   = (const float*)d_in[16];
    float* out = (float*)d_out;

    const int N = in_sizes[0] / 9;
    const int E = in_sizes[1] / 2;
    const int P = in_sizes[3];
    const int G = out_size - P;

    const int* src = eidx;
    const int* dst = eidx + E;

    const int nw = (N + WSZ - 1) >> WB;  // level-2 windows (196 for N=100k)
    const int nb = (N + 1023) / 1024;

    // ---- workspace carve-out ----
    char* ws = (char*)d_ws;
    size_t off = 0;
    auto take = [&](size_t bytes) -> void* {
        void* p = ws + off;
        off = (off + bytes + 255) & ~(size_t)255;
        return p;
    };
    int*   deg      = (int*)  take((size_t)N * 4);
    float* dinv     = (float*)take((size_t)N * 4);
    int*   rowptr   = (int*)  take((size_t)(N + 1) * 4);
    int*   bsum     = (int*)  take(256 * 4);
    int*   hist_g   = (int*)  take((size_t)nw * NJ1 * 4);
    int2*  eb       = (int2*) take((size_t)E * 8);
    int*   csr_src  = (int*)  take((size_t)E * 4);
    float* xs       = (float*)take((size_t)N * 9 * 4);
    float* xa       = (float*)take((size_t)N * 9 * 4);
    unsigned short* bufA = (unsigned short*)take((size_t)N * U * 2);  // bf16 acts
    unsigned short* Tb   = (unsigned short*)take((size_t)N * U * 2);  // bf16 table
    unsigned short* W1t  = (unsigned short*)take(128 * 128 * 2);
    unsigned short* W2t  = (unsigned short*)take(128 * 128 * 2);
    unsigned short* Wf1t = (unsigned short*)take(128 * 128 * 2);
    unsigned short* Wf2t = (unsigned short*)take(32 * 128 * 2);
    // zero-region: util_sum + cnt contiguous, single memset
    float* util_sum = (float*)take((size_t)G * 4 + (size_t)G * 4);
    int*   cnt      = (int*)(util_sum + G);
    (void)ws_size;

    hipMemsetAsync(util_sum, 0, (size_t)G * 8, stream);

    // ---- CSR build: two-level counting sort ----
    k_hist1<<<NJ1, 256, 0, stream>>>(dst, hist_g, E, nw);
    k_scanh<<<1, 256, 0, stream>>>(hist_g, nw);
    k_bucket<<<NJ1, 256, 0, stream>>>(src, dst, hist_g, eb, E, nw);
    k_deg2<<<nw, 256, 0, stream>>>(eb, hist_g, deg, E, nw, N);
    k_prep<<<(N + 255) / 256, 256, 0, stream>>>(deg, x, batch, W1, W2, Wf1, Wf2,
                                                dinv, xs, cnt, W1t, W2t, Wf1t, Wf2t, N);
    k_scan1<<<nb, 256, 0, stream>>>(deg, rowptr + 1, bsum, N);
    k_scan23<<<(N + 255) / 256, 256, 0, stream>>>(rowptr, bsum, nb, N);
    k_scatter2<<<nw, 256, 0, stream>>>(eb, hist_g, rowptr, csr_src, E, nw, N);

    const int aggGrid  = (N + 3) / 4;
    const int gemmGrid = (N + 63) / 64;

    // ---- GCN layer 1: aggregate xs (9-wide), then GEMM+bias+tanh -> bf16 ----
    k_aggx<<<(N + 15) / 16, 256, 0, stream>>>(xs, rowptr, csr_src, dinv, xa, N);
    k_gemm_in9<<<((size_t)N * U + 255) / 256, 256, 0, stream>>>(xa, W_in, b_in, bufA, N);

    // ---- GCN layer 2 ----
    k_gemm_mfma<<<gemmGrid, 256, 0, stream>>>(bufA, W1t, dinv, Tb, N);
    k_aggb<<<aggGrid, 256, 0, stream>>>(Tb, rowptr, csr_src, dinv, b1, bufA, N);
    // ---- GCN layer 3 ----
    k_gemm_mfma<<<gemmGrid, 256, 0, stream>>>(bufA, W2t, dinv, Tb, N);
    k_aggb<<<aggGrid, 256, 0, stream>>>(Tb, rowptr, csr_src, dinv, b2, bufA, N);

    // ---- MLP head + pooled sums ----
    k_mlp<<<gemmGrid, 256, 0, stream>>>(bufA, Wf1t, bf1, Wf2t, bf2, Wf3, bf3,
                                        batch, util_sum, N);

    // ---- fused util + pairs ----
    int mx = (P > G ? P : G);
    k_out<<<(mx + 255) / 256, 256, 0, stream>>>(util_sum, cnt, idx_a, idx_b, out, P, G);
}

// Round 8
// 519.894 us; speedup vs baseline: 2.0161x; 1.1409x over previous
//
#include <hip/hip_runtime.h>
#include <hip/hip_bf16.h>
#include <math.h>

// ---------------------------------------------------------------------------
// RankGNN R8: replace single-block k_scanh (85us, uncoalesced) with standard
// two-kernel parallel exclusive scan over hist_g. Everything else as R7.
// ---------------------------------------------------------------------------

#define U 128
#define LDA 136    // LDS row stride in bf16 elems (128 + 8 pad)
#define WB 9       // log2(window) = 512 nodes per level-2 window
#define WSZ 512
#define NJ1 256    // level-1 blocks (edge chunks)

typedef __attribute__((ext_vector_type(8))) short bf16x8;
typedef __attribute__((ext_vector_type(4))) float f32x4;

__device__ __forceinline__ unsigned short f2bf(float f) {
    unsigned u = __float_as_uint(f);
    unsigned r = (u + 0x7fffu + ((u >> 16) & 1u)) >> 16;  // RNE
    return (unsigned short)r;
}
__device__ __forceinline__ float bf_lo(unsigned u) { return __uint_as_float(u << 16); }
__device__ __forceinline__ float bf_hi(unsigned u) { return __uint_as_float(u & 0xffff0000u); }

// ---------------- level-1: per-chunk window histogram ----------------
__global__ __launch_bounds__(256) void k_hist1(const int* __restrict__ dst,
                                               int* __restrict__ hist_g, int E, int nw) {
    __shared__ int h[256];  // nw <= 256
    int b = blockIdx.x;
    for (int i = threadIdx.x; i < nw; i += 256) h[i] = 0;
    __syncthreads();
    int ch = (E + NJ1 - 1) / NJ1;
    int e0 = b * ch, e1 = min(e0 + ch, E);
    for (int e = e0 + threadIdx.x; e < e1; e += 256)
        atomicAdd(&h[dst[e] >> WB], 1);
    __syncthreads();
    for (int w = threadIdx.x; w < nw; w += 256) hist_g[w * NJ1 + b] = h[w];
}

// ---------------- generic parallel exclusive scan (in place) ----------------
// escan1: per-block 1024-elem exclusive scan + block sums
__global__ __launch_bounds__(256) void k_escan1(int* __restrict__ a,
                                                int* __restrict__ bsum, int n) {
    __shared__ int sc[256];
    int t = threadIdx.x, b = blockIdx.x;
    int base = b * 1024 + t * 4;
    int v[4];
    int s = 0;
    #pragma unroll
    for (int j = 0; j < 4; ++j) {
        int idx = base + j;
        int d = (idx < n) ? a[idx] : 0;
        v[j] = s;  // exclusive within thread
        s += d;
    }
    sc[t] = s;
    __syncthreads();
    for (int off = 1; off < 256; off <<= 1) {
        int x = (t >= off) ? sc[t - off] : 0;
        __syncthreads();
        sc[t] += x;
        __syncthreads();
    }
    int excl = sc[t] - s;
    #pragma unroll
    for (int j = 0; j < 4; ++j) {
        int idx = base + j;
        if (idx < n) a[idx] = v[j] + excl;
    }
    if (t == 255) bsum[b] = sc[255];
}

// escan2: each block redundantly scans bsum (nb<=256), adds its offset
__global__ __launch_bounds__(256) void k_escan2(int* __restrict__ a,
                                                const int* __restrict__ bsum,
                                                int nb, int n) {
    __shared__ int sc[256];
    int t = threadIdx.x;
    int v = (t < nb) ? bsum[t] : 0;
    sc[t] = v;
    __syncthreads();
    for (int off = 1; off < 256; off <<= 1) {
        int u = (t >= off) ? sc[t - off] : 0;
        __syncthreads();
        sc[t] += u;
        __syncthreads();
    }
    int myoff = (blockIdx.x > 0) ? (sc[blockIdx.x] - bsum[blockIdx.x]) : 0;
    // note: sc is inclusive; exclusive offset for block b = sc[b] - bsum_orig[b]
    int base = blockIdx.x * 1024;
    #pragma unroll
    for (int j = 0; j < 4; ++j) {
        int idx = base + t + j * 256;
        if (idx < n) a[idx] += myoff;
    }
}

// ---------------- level-1: bucket edges window-major ----------------
__global__ __launch_bounds__(256) void k_bucket(const int* __restrict__ src,
                                                const int* __restrict__ dst,
                                                const int* __restrict__ hist_g,
                                                int2* __restrict__ eb, int E, int nw) {
    __shared__ int lcur[256];
    int b = blockIdx.x;
    for (int w = threadIdx.x; w < nw; w += 256) lcur[w] = hist_g[w * NJ1 + b];
    __syncthreads();
    int ch = (E + NJ1 - 1) / NJ1;
    int e0 = b * ch, e1 = min(e0 + ch, E);
    for (int e = e0 + threadIdx.x; e < e1; e += 256) {
        int d = dst[e];
        int pos = atomicAdd(&lcur[d >> WB], 1);
        eb[pos] = make_int2(src[e], d);
    }
}

// ---------------- level-2: per-window degree histogram -> deg ---------------
__global__ __launch_bounds__(256) void k_deg2(const int2* __restrict__ eb,
                                              const int* __restrict__ hist_g,
                                              int* __restrict__ deg, int E, int nw, int N) {
    __shared__ int h[WSZ];
    int w = blockIdx.x;
    h[threadIdx.x] = 0;
    h[threadIdx.x + 256] = 0;
    __syncthreads();
    int s0 = hist_g[w * NJ1];
    int s1 = (w + 1 < nw) ? hist_g[(w + 1) * NJ1] : E;
    for (int i = s0 + threadIdx.x; i < s1; i += 256)
        atomicAdd(&h[eb[i].y & (WSZ - 1)], 1);
    __syncthreads();
    int base = w << WB;
    if (base + threadIdx.x < N) deg[base + threadIdx.x] = h[threadIdx.x];
    if (base + 256 + threadIdx.x < N) deg[base + 256 + threadIdx.x] = h[256 + threadIdx.x];
}

// ---------------- rowptr scan ----------------
__global__ __launch_bounds__(256) void k_scan1(const int* __restrict__ deg,
                                               int* __restrict__ rowptr1,
                                               int* __restrict__ bsum, int N) {
    __shared__ int sc[256];
    int t = threadIdx.x, b = blockIdx.x;
    int base = b * 1024 + t * 4;
    int v[4];
    int s = 0;
    #pragma unroll
    for (int j = 0; j < 4; ++j) {
        int idx = base + j;
        int d = (idx < N) ? deg[idx] : 0;
        s += d;
        v[j] = s;
    }
    sc[t] = s;
    __syncthreads();
    for (int off = 1; off < 256; off <<= 1) {
        int x = (t >= off) ? sc[t - off] : 0;
        __syncthreads();
        sc[t] += x;
        __syncthreads();
    }
    int excl = sc[t] - s;
    #pragma unroll
    for (int j = 0; j < 4; ++j) {
        int idx = base + j;
        if (idx < N) rowptr1[idx] = v[j] + excl;
    }
    if (t == 255) bsum[b] = sc[255];
}

// scan2+scan3 fused: every block redundantly scans bsum (nb<=256), then adds.
__global__ __launch_bounds__(256) void k_scan23(int* __restrict__ rowptr,
                                                const int* __restrict__ bsum,
                                                int nb, int N) {
    __shared__ int sc[256];
    __shared__ int bo[256];
    int t = threadIdx.x;
    int v = (t < nb) ? bsum[t] : 0;
    sc[t] = v;
    __syncthreads();
    for (int off = 1; off < 256; off <<= 1) {
        int u = (t >= off) ? sc[t - off] : 0;
        __syncthreads();
        sc[t] += u;
        __syncthreads();
    }
    bo[t] = sc[t] - v;  // exclusive
    __syncthreads();
    int i = blockIdx.x * 256 + t;
    if (i < N) rowptr[1 + i] += bo[i >> 10];
    if (i == 0) rowptr[0] = 0;
}

// ---------------- level-2: single-writer CSR scatter ----------------
__global__ __launch_bounds__(256) void k_scatter2(const int2* __restrict__ eb,
                                                  const int* __restrict__ hist_g,
                                                  const int* __restrict__ rowptr,
                                                  int* __restrict__ csr_src,
                                                  int E, int nw, int N) {
    __shared__ int cur[WSZ];
    int w = blockIdx.x;
    int base = w << WB;
    int i0 = base + threadIdx.x, i1 = base + 256 + threadIdx.x;
    cur[threadIdx.x] = (i0 < N) ? rowptr[i0] : 0;
    cur[threadIdx.x + 256] = (i1 < N) ? rowptr[i1] : 0;
    __syncthreads();
    int s0 = hist_g[w * NJ1];
    int s1 = (w + 1 < nw) ? hist_g[(w + 1) * NJ1] : E;
    for (int i = s0 + threadIdx.x; i < s1; i += 256) {
        int2 e = eb[i];
        int pos = atomicAdd(&cur[e.y & (WSZ - 1)], 1);
        csr_src[pos] = e.x;
    }
}

// ---------------- fused prep: dinv, xs, counts, weight transpose ------------
__global__ __launch_bounds__(256) void k_prep(const int* __restrict__ deg,
                                              const float* __restrict__ x,
                                              const int* __restrict__ batch,
                                              const float* __restrict__ W1,
                                              const float* __restrict__ W2,
                                              const float* __restrict__ Wf1,
                                              const float* __restrict__ Wf2,
                                              float* __restrict__ dinv,
                                              float* __restrict__ xs,
                                              int* __restrict__ cnt,
                                              unsigned short* __restrict__ W1t,
                                              unsigned short* __restrict__ W2t,
                                              unsigned short* __restrict__ Wf1t,
                                              unsigned short* __restrict__ Wf2t, int N) {
    int t = blockIdx.x * 256 + threadIdx.x;
    if (t < N) {
        float dv = rsqrtf((float)deg[t] + 1.0f);
        dinv[t] = dv;
        #pragma unroll
        for (int k = 0; k < 9; ++k) xs[t * 9 + k] = x[t * 9 + k] * dv;
        atomicAdd(&cnt[batch[t]], 1);
    }
    if (t < 16384) {
        int n = t >> 7, k = t & 127;
        W1t[n * 128 + k] = f2bf(W1[k * 128 + n]);
        Wf1t[n * 128 + k] = f2bf(Wf1[k * 128 + n]);
    } else if (t < 32768) {
        int i = t - 16384, n = i >> 7, k = i & 127;
        W2t[n * 128 + k] = f2bf(W2[k * 128 + n]);
    } else if (t < 36864) {
        int i = t - 32768, n = i >> 7, k = i & 127;
        Wf2t[n * 128 + k] = f2bf(Wf2[k * 32 + n]);
    }
}

// ---------------- layer-1: aggregate xs (N x 9), output dinv-scaled ---------
__global__ __launch_bounds__(256) void k_aggx(const float* __restrict__ xs,
                                              const int* __restrict__ rowptr,
                                              const int* __restrict__ csr_src,
                                              const float* __restrict__ dinv,
                                              float* __restrict__ xa, int N) {
    int node = blockIdx.x * 16 + (threadIdx.x >> 4);
    if (node >= N) return;
    int lane = threadIdx.x & 15;
    bool act = lane < 9;
    int s = rowptr[node], e = rowptr[node + 1];
    float a0 = 0.0f, a1 = 0.0f, a2 = 0.0f, a3 = 0.0f;
    int i = s;
    for (; i + 4 <= e; i += 4) {
        int s0 = csr_src[i], s1 = csr_src[i + 1];
        int s2 = csr_src[i + 2], s3 = csr_src[i + 3];
        if (act) {
            a0 += xs[s0 * 9 + lane];
            a1 += xs[s1 * 9 + lane];
            a2 += xs[s2 * 9 + lane];
            a3 += xs[s3 * 9 + lane];
        }
    }
    for (; i < e; ++i) {
        int s0 = csr_src[i];
        if (act) a0 += xs[s0 * 9 + lane];
    }
    if (act) {
        float dv = dinv[node];
        xa[node * 9 + lane] = dv * (a0 + a1 + a2 + a3 + xs[node * 9 + lane]);
    }
}

// ---------------- layer-1 GEMM: bf16(tanh(xa @ W_in + b)) ----------------
__global__ void k_gemm_in9(const float* __restrict__ xa, const float* __restrict__ Wi,
                           const float* __restrict__ bi, unsigned short* __restrict__ T,
                           int N) {
    int t = blockIdx.x * 256 + threadIdx.x;
    if (t < N * U) {
        int n = t >> 7, c = t & 127;
        const float* xr = xa + n * 9;
        float acc = bi[c];
        #pragma unroll
        for (int k = 0; k < 9; ++k) acc += xr[k] * Wi[k * U + c];
        T[t] = f2bf(tanhf(acc));
    }
}

// ---------------- MFMA GEMM (LDS-free, barrier-free) ----------------
__global__ __launch_bounds__(256) void k_gemm_mfma(const unsigned short* __restrict__ A,
                                                   const unsigned short* __restrict__ Wt,
                                                   const float* __restrict__ dinv,
                                                   unsigned short* __restrict__ Out, int N) {
    const int tid = threadIdx.x;
    const int wave = tid >> 6, lane = tid & 63;
    const int m16 = lane & 15, q = lane >> 4;
    const int row0 = blockIdx.x * 64 + wave * 16;
    int arow_idx = row0 + m16;
    if (arow_idx >= N) arow_idx = N - 1;  // clamp; OOB outputs are guarded
    const bf16x8* arow = (const bf16x8*)(A + (size_t)arow_idx * U + q * 8);
    f32x4 acc[8];
    #pragma unroll
    for (int t = 0; t < 8; ++t) acc[t] = (f32x4){0.f, 0.f, 0.f, 0.f};
    #pragma unroll
    for (int kc = 0; kc < 4; ++kc) {
        bf16x8 af = arow[kc * 4];
        #pragma unroll
        for (int t = 0; t < 8; ++t) {
            bf16x8 bfr = *(const bf16x8*)(Wt + ((t * 16 + m16) * 128 + kc * 32 + q * 8));
            acc[t] = __builtin_amdgcn_mfma_f32_16x16x32_bf16(af, bfr, acc[t], 0, 0, 0);
        }
    }
    float dv[4];
    #pragma unroll
    for (int r = 0; r < 4; ++r) {
        int gr = row0 + q * 4 + r;
        dv[r] = (gr < N) ? dinv[gr] : 0.0f;
    }
    #pragma unroll
    for (int t = 0; t < 8; ++t) {
        #pragma unroll
        for (int r = 0; r < 4; ++r) {
            int gr = row0 + q * 4 + r;
            if (gr < N) Out[(size_t)gr * U + t * 16 + m16] = f2bf(acc[t][r] * dv[r]);
        }
    }
}

// ---------------- aggregation: h = tanh(dinv[d]*(sum Ts + Ts[d]) + b) -------
__global__ __launch_bounds__(256) void k_aggb(const unsigned short* __restrict__ Tb,
                                              const int* __restrict__ rowptr,
                                              const int* __restrict__ csr_src,
                                              const float* __restrict__ dinv,
                                              const float* __restrict__ bias,
                                              unsigned short* __restrict__ Out, int N) {
    int node = blockIdx.x * 4 + (threadIdx.x >> 6);
    if (node >= N) return;
    int lane = threadIdx.x & 63;
    const unsigned* T32 = (const unsigned*)Tb;
    float ax = 0.0f, ay = 0.0f, bx = 0.0f, by = 0.0f;
    int s = rowptr[node], e = rowptr[node + 1];
    int i = s;
    for (; i + 8 <= e; i += 8) {
        int idx[8];
        #pragma unroll
        for (int u = 0; u < 8; ++u) idx[u] = csr_src[i + u];
        unsigned uv[8];
        #pragma unroll
        for (int u = 0; u < 8; ++u) uv[u] = T32[idx[u] * 64 + lane];
        #pragma unroll
        for (int u = 0; u < 8; u += 2) {
            ax += bf_lo(uv[u]) + bf_lo(uv[u + 1]);
            ay += bf_hi(uv[u]) + bf_hi(uv[u + 1]);
        }
    }
    for (; i + 4 <= e; i += 4) {
        int s0 = csr_src[i], s1 = csr_src[i + 1];
        int s2 = csr_src[i + 2], s3 = csr_src[i + 3];
        unsigned u0 = T32[s0 * 64 + lane];
        unsigned u1 = T32[s1 * 64 + lane];
        unsigned u2 = T32[s2 * 64 + lane];
        unsigned u3 = T32[s3 * 64 + lane];
        ax += bf_lo(u0) + bf_lo(u1);
        ay += bf_hi(u0) + bf_hi(u1);
        bx += bf_lo(u2) + bf_lo(u3);
        by += bf_hi(u2) + bf_hi(u3);
    }
    for (; i < e; ++i) {
        int s0 = csr_src[i];
        unsigned u0 = T32[s0 * 64 + lane];
        ax += bf_lo(u0);
        ay += bf_hi(u0);
    }
    float dv = dinv[node];
    unsigned su = T32[node * 64 + lane];
    float2 bb = *(const float2*)&bias[lane * 2];
    float ox = tanhf(dv * (ax + bx + bf_lo(su)) + bb.x);
    float oy = tanhf(dv * (ay + by + bf_hi(su)) + bb.y);
    unsigned o = (unsigned)f2bf(ox) | ((unsigned)f2bf(oy) << 16);
    ((unsigned*)Out)[node * 64 + lane] = o;
}

// ---------------- fused MFMA MLP head (barrier-free) ----------------
__global__ __launch_bounds__(256) void k_mlp(const unsigned short* __restrict__ H,
                                             const unsigned short* __restrict__ Wf1t,
                                             const float* __restrict__ bf1,
                                             const unsigned short* __restrict__ Wf2t,
                                             const float* __restrict__ bf2,
                                             const float* __restrict__ Wf3,
                                             const float* __restrict__ bf3,
                                             const int* __restrict__ batch,
                                             float* __restrict__ util_sum, int N) {
    __shared__ unsigned short H2[64 * LDA];  // wave-local 16-row slices
    const int tid = threadIdx.x;
    const int wave = tid >> 6, lane = tid & 63;
    const int m16 = lane & 15, q = lane >> 4;
    const int row0 = blockIdx.x * 64 + wave * 16;
    int arow_idx = row0 + m16;
    if (arow_idx >= N) arow_idx = N - 1;
    const bf16x8* arow = (const bf16x8*)(H + (size_t)arow_idx * U + q * 8);
    f32x4 acc[8];
    #pragma unroll
    for (int t = 0; t < 8; ++t) acc[t] = (f32x4){0.f, 0.f, 0.f, 0.f};
    #pragma unroll
    for (int kc = 0; kc < 4; ++kc) {
        bf16x8 af = arow[kc * 4];
        #pragma unroll
        for (int t = 0; t < 8; ++t) {
            bf16x8 bfr = *(const bf16x8*)(Wf1t + ((t * 16 + m16) * 128 + kc * 32 + q * 8));
            acc[t] = __builtin_amdgcn_mfma_f32_16x16x32_bf16(af, bfr, acc[t], 0, 0, 0);
        }
    }
    #pragma unroll
    for (int t = 0; t < 8; ++t) {
        float b = bf1[t * 16 + m16];
        #pragma unroll
        for (int r = 0; r < 4; ++r) {
            int lr = wave * 16 + q * 4 + r;
            H2[lr * LDA + t * 16 + m16] = f2bf(tanhf(acc[t][r] + b));
        }
    }
    f32x4 acc2[2];
    acc2[0] = (f32x4){0.f, 0.f, 0.f, 0.f};
    acc2[1] = (f32x4){0.f, 0.f, 0.f, 0.f};
    const unsigned short* h2row = &H2[(wave * 16 + m16) * LDA + q * 8];
    #pragma unroll
    for (int kc = 0; kc < 4; ++kc) {
        bf16x8 af = *(const bf16x8*)(h2row + kc * 32);
        #pragma unroll
        for (int t = 0; t < 2; ++t) {
            bf16x8 bfr = *(const bf16x8*)(Wf2t + ((t * 16 + m16) * 128 + kc * 32 + q * 8));
            acc2[t] = __builtin_amdgcn_mfma_f32_16x16x32_bf16(af, bfr, acc2[t], 0, 0, 0);
        }
    }
    float b2lo = bf2[m16], b2hi = bf2[m16 + 16];
    float w3lo = Wf3[m16], w3hi = Wf3[m16 + 16];
    float bf3v = bf3[0];
    #pragma unroll
    for (int r = 0; r < 4; ++r) {
        float t0 = tanhf(acc2[0][r] + b2lo);
        float t1 = tanhf(acc2[1][r] + b2hi);
        float v = t0 * w3lo + t1 * w3hi;
        v += __shfl_xor(v, 1);
        v += __shfl_xor(v, 2);
        v += __shfl_xor(v, 4);
        v += __shfl_xor(v, 8);
        if (m16 == 0) {
            int n = row0 + q * 4 + r;
            if (n < N) atomicAdd(&util_sum[batch[n]], v + bf3v);
        }
    }
}

// ---------------- fused output: util + pair sigmoid ----------------
__global__ void k_out(const float* __restrict__ us, const int* __restrict__ cnt,
                      const int* __restrict__ ia, const int* __restrict__ ib,
                      float* __restrict__ out, int P, int G) {
    int t = blockIdx.x * 256 + threadIdx.x;
    if (t < G) out[P + t] = us[t] / fmaxf((float)cnt[t], 1.0f);
    if (t < P) {
        int a = ia[t], b = ib[t];
        float ua = us[a] / fmaxf((float)cnt[a], 1.0f);
        float ub = us[b] / fmaxf((float)cnt[b], 1.0f);
        out[t] = 1.0f / (1.0f + expf(-(ub - ua)));
    }
}

extern "C" void kernel_launch(void* const* d_in, const int* in_sizes, int n_in,
                              void* d_out, int out_size, void* d_ws, size_t ws_size,
                              hipStream_t stream) {
    const float* x     = (const float*)d_in[0];
    const int*   eidx  = (const int*)d_in[1];
    const int*   batch = (const int*)d_in[2];
    const int*   idx_a = (const int*)d_in[3];
    const int*   idx_b = (const int*)d_in[4];
    const float* W_in  = (const float*)d_in[5];
    const float* b_in  = (const float*)d_in[6];
    const float* W1    = (const float*)d_in[7];
    const float* b1    = (const float*)d_in[8];
    const float* W2    = (const float*)d_in[9];
    const float* b2    = (const float*)d_in[10];
    const float* Wf1   = (const float*)d_in[11];
    const float* bf1   = (const float*)d_in[12];
    const float* Wf2   = (const float*)d_in[13];
    const float* bf2   = (const float*)d_in[14];
    const float* Wf3   = (const float*)d_in[15];
    const float* bf3   = (const float*)d_in[16];
    float* out = (float*)d_out;

    const int N = in_sizes[0] / 9;
    const int E = in_sizes[1] / 2;
    const int P = in_sizes[3];
    const int G = out_size - P;

    const int* src = eidx;
    const int* dst = eidx + E;

    const int nw = (N + WSZ - 1) >> WB;  // level-2 windows (196 for N=100k)
    const int nb = (N + 1023) / 1024;
    const int nh = nw * NJ1;             // hist_g size
    const int nbh = (nh + 1023) / 1024;  // scan blocks for hist_g

    // ---- workspace carve-out ----
    char* ws = (char*)d_ws;
    size_t off = 0;
    auto take = [&](size_t bytes) -> void* {
        void* p = ws + off;
        off = (off + bytes + 255) & ~(size_t)255;
        return p;
    };
    int*   deg      = (int*)  take((size_t)N * 4);
    float* dinv     = (float*)take((size_t)N * 4);
    int*   rowptr   = (int*)  take((size_t)(N + 1) * 4);
    int*   bsum     = (int*)  take(256 * 4);
    int*   bsum2    = (int*)  take(256 * 4);
    int*   hist_g   = (int*)  take((size_t)nh * 4);
    int2*  eb       = (int2*) take((size_t)E * 8);
    int*   csr_src  = (int*)  take((size_t)E * 4);
    float* xs       = (float*)take((size_t)N * 9 * 4);
    float* xa       = (float*)take((size_t)N * 9 * 4);
    unsigned short* bufA = (unsigned short*)take((size_t)N * U * 2);  // bf16 acts
    unsigned short* Tb   = (unsigned short*)take((size_t)N * U * 2);  // bf16 table
    unsigned short* W1t  = (unsigned short*)take(128 * 128 * 2);
    unsigned short* W2t  = (unsigned short*)take(128 * 128 * 2);
    unsigned short* Wf1t = (unsigned short*)take(128 * 128 * 2);
    unsigned short* Wf2t = (unsigned short*)take(32 * 128 * 2);
    // zero-region: util_sum + cnt contiguous, single memset
    float* util_sum = (float*)take((size_t)G * 4 + (size_t)G * 4);
    int*   cnt      = (int*)(util_sum + G);
    (void)ws_size;

    hipMemsetAsync(util_sum, 0, (size_t)G * 8, stream);

    // ---- CSR build: two-level counting sort ----
    k_hist1<<<NJ1, 256, 0, stream>>>(dst, hist_g, E, nw);
    k_escan1<<<nbh, 256, 0, stream>>>(hist_g, bsum2, nh);
    k_escan2<<<nbh, 256, 0, stream>>>(hist_g, bsum2, nbh, nh);
    k_bucket<<<NJ1, 256, 0, stream>>>(src, dst, hist_g, eb, E, nw);
    k_deg2<<<nw, 256, 0, stream>>>(eb, hist_g, deg, E, nw, N);
    k_prep<<<(N + 255) / 256, 256, 0, stream>>>(deg, x, batch, W1, W2, Wf1, Wf2,
                                                dinv, xs, cnt, W1t, W2t, Wf1t, Wf2t, N);
    k_scan1<<<nb, 256, 0, stream>>>(deg, rowptr + 1, bsum, N);
    k_scan23<<<(N + 255) / 256, 256, 0, stream>>>(rowptr, bsum, nb, N);
    k_scatter2<<<nw, 256, 0, stream>>>(eb, hist_g, rowptr, csr_src, E, nw, N);

    const int aggGrid  = (N + 3) / 4;
    const int gemmGrid = (N + 63) / 64;

    // ---- GCN layer 1: aggregate xs (9-wide), then GEMM+bias+tanh -> bf16 ----
    k_aggx<<<(N + 15) / 16, 256, 0, stream>>>(xs, rowptr, csr_src, dinv, xa, N);
    k_gemm_in9<<<((size_t)N * U + 255) / 256, 256, 0, stream>>>(xa, W_in, b_in, bufA, N);

    // ---- GCN layer 2 ----
    k_gemm_mfma<<<gemmGrid, 256, 0, stream>>>(bufA, W1t, dinv, Tb, N);
    k_aggb<<<aggGrid, 256, 0, stream>>>(Tb, rowptr, csr_src, dinv, b1, bufA, N);
    // ---- GCN layer 3 ----
    k_gemm_mfma<<<gemmGrid, 256, 0, stream>>>(bufA, W2t, dinv, Tb, N);
    k_aggb<<<aggGrid, 256, 0, stream>>>(Tb, rowptr, csr_src, dinv, b2, bufA, N);

    // ---- MLP head + pooled sums ----
    k_mlp<<<gemmGrid, 256, 0, stream>>>(bufA, Wf1t, bf1, Wf2t, bf2, Wf3, bf3,
                                        batch, util_sum, N);

    // ---- fused util + pairs ----
    int mx = (P > G ? P : G);
    k_out<<<(mx + 255) / 256, 256, 0, stream>>>(util_sum, cnt, idx_a, idx_b, out, P, G);
}

// Round 9
// 476.822 us; speedup vs baseline: 2.1983x; 1.0903x over previous
//
#include <hip/hip_runtime.h>
#include <hip/hip_bf16.h>
#include <math.h>

// ---------------------------------------------------------------------------
// RankGNN R9: k_mlp rewritten — register-resident weight fragments (loaded
// once per wave), 4 node-tiles streamed per wave with A-prefetch, LDS-pooled
// graph atomics. CSR build + GCN layers as R8.
// ---------------------------------------------------------------------------

#define U 128
#define LDA 136    // LDS row stride in bf16 elems (128 + 8 pad)
#define WB 9       // log2(window) = 512 nodes per level-2 window
#define WSZ 512
#define NJ1 256    // level-1 blocks (edge chunks)

typedef __attribute__((ext_vector_type(8))) short bf16x8;
typedef __attribute__((ext_vector_type(4))) float f32x4;

__device__ __forceinline__ unsigned short f2bf(float f) {
    unsigned u = __float_as_uint(f);
    unsigned r = (u + 0x7fffu + ((u >> 16) & 1u)) >> 16;  // RNE
    return (unsigned short)r;
}
__device__ __forceinline__ float bf_lo(unsigned u) { return __uint_as_float(u << 16); }
__device__ __forceinline__ float bf_hi(unsigned u) { return __uint_as_float(u & 0xffff0000u); }

// ---------------- level-1: per-chunk window histogram ----------------
__global__ __launch_bounds__(256) void k_hist1(const int* __restrict__ dst,
                                               int* __restrict__ hist_g, int E, int nw) {
    __shared__ int h[256];  // nw <= 256
    int b = blockIdx.x;
    for (int i = threadIdx.x; i < nw; i += 256) h[i] = 0;
    __syncthreads();
    int ch = (E + NJ1 - 1) / NJ1;
    int e0 = b * ch, e1 = min(e0 + ch, E);
    for (int e = e0 + threadIdx.x; e < e1; e += 256)
        atomicAdd(&h[dst[e] >> WB], 1);
    __syncthreads();
    for (int w = threadIdx.x; w < nw; w += 256) hist_g[w * NJ1 + b] = h[w];
}

// ---------------- generic parallel exclusive scan (in place) ----------------
__global__ __launch_bounds__(256) void k_escan1(int* __restrict__ a,
                                                int* __restrict__ bsum, int n) {
    __shared__ int sc[256];
    int t = threadIdx.x, b = blockIdx.x;
    int base = b * 1024 + t * 4;
    int v[4];
    int s = 0;
    #pragma unroll
    for (int j = 0; j < 4; ++j) {
        int idx = base + j;
        int d = (idx < n) ? a[idx] : 0;
        v[j] = s;  // exclusive within thread
        s += d;
    }
    sc[t] = s;
    __syncthreads();
    for (int off = 1; off < 256; off <<= 1) {
        int x = (t >= off) ? sc[t - off] : 0;
        __syncthreads();
        sc[t] += x;
        __syncthreads();
    }
    int excl = sc[t] - s;
    #pragma unroll
    for (int j = 0; j < 4; ++j) {
        int idx = base + j;
        if (idx < n) a[idx] = v[j] + excl;
    }
    if (t == 255) bsum[b] = sc[255];
}

__global__ __launch_bounds__(256) void k_escan2(int* __restrict__ a,
                                                const int* __restrict__ bsum,
                                                int nb, int n) {
    __shared__ int sc[256];
    int t = threadIdx.x;
    int v = (t < nb) ? bsum[t] : 0;
    sc[t] = v;
    __syncthreads();
    for (int off = 1; off < 256; off <<= 1) {
        int u = (t >= off) ? sc[t - off] : 0;
        __syncthreads();
        sc[t] += u;
        __syncthreads();
    }
    int myoff = (blockIdx.x > 0) ? (sc[blockIdx.x] - bsum[blockIdx.x]) : 0;
    int base = blockIdx.x * 1024;
    #pragma unroll
    for (int j = 0; j < 4; ++j) {
        int idx = base + t + j * 256;
        if (idx < n) a[idx] += myoff;
    }
}

// ---------------- level-1: bucket edges window-major ----------------
__global__ __launch_bounds__(256) void k_bucket(const int* __restrict__ src,
                                                const int* __restrict__ dst,
                                                const int* __restrict__ hist_g,
                                                int2* __restrict__ eb, int E, int nw) {
    __shared__ int lcur[256];
    int b = blockIdx.x;
    for (int w = threadIdx.x; w < nw; w += 256) lcur[w] = hist_g[w * NJ1 + b];
    __syncthreads();
    int ch = (E + NJ1 - 1) / NJ1;
    int e0 = b * ch, e1 = min(e0 + ch, E);
    for (int e = e0 + threadIdx.x; e < e1; e += 256) {
        int d = dst[e];
        int pos = atomicAdd(&lcur[d >> WB], 1);
        eb[pos] = make_int2(src[e], d);
    }
}

// ---------------- level-2: per-window degree histogram -> deg ---------------
__global__ __launch_bounds__(256) void k_deg2(const int2* __restrict__ eb,
                                              const int* __restrict__ hist_g,
                                              int* __restrict__ deg, int E, int nw, int N) {
    __shared__ int h[WSZ];
    int w = blockIdx.x;
    h[threadIdx.x] = 0;
    h[threadIdx.x + 256] = 0;
    __syncthreads();
    int s0 = hist_g[w * NJ1];
    int s1 = (w + 1 < nw) ? hist_g[(w + 1) * NJ1] : E;
    for (int i = s0 + threadIdx.x; i < s1; i += 256)
        atomicAdd(&h[eb[i].y & (WSZ - 1)], 1);
    __syncthreads();
    int base = w << WB;
    if (base + threadIdx.x < N) deg[base + threadIdx.x] = h[threadIdx.x];
    if (base + 256 + threadIdx.x < N) deg[base + 256 + threadIdx.x] = h[256 + threadIdx.x];
}

// ---------------- rowptr scan ----------------
__global__ __launch_bounds__(256) void k_scan1(const int* __restrict__ deg,
                                               int* __restrict__ rowptr1,
                                               int* __restrict__ bsum, int N) {
    __shared__ int sc[256];
    int t = threadIdx.x, b = blockIdx.x;
    int base = b * 1024 + t * 4;
    int v[4];
    int s = 0;
    #pragma unroll
    for (int j = 0; j < 4; ++j) {
        int idx = base + j;
        int d = (idx < N) ? deg[idx] : 0;
        s += d;
        v[j] = s;
    }
    sc[t] = s;
    __syncthreads();
    for (int off = 1; off < 256; off <<= 1) {
        int x = (t >= off) ? sc[t - off] : 0;
        __syncthreads();
        sc[t] += x;
        __syncthreads();
    }
    int excl = sc[t] - s;
    #pragma unroll
    for (int j = 0; j < 4; ++j) {
        int idx = base + j;
        if (idx < N) rowptr1[idx] = v[j] + excl;
    }
    if (t == 255) bsum[b] = sc[255];
}

__global__ __launch_bounds__(256) void k_scan23(int* __restrict__ rowptr,
                                                const int* __restrict__ bsum,
                                                int nb, int N) {
    __shared__ int sc[256];
    __shared__ int bo[256];
    int t = threadIdx.x;
    int v = (t < nb) ? bsum[t] : 0;
    sc[t] = v;
    __syncthreads();
    for (int off = 1; off < 256; off <<= 1) {
        int u = (t >= off) ? sc[t - off] : 0;
        __syncthreads();
        sc[t] += u;
        __syncthreads();
    }
    bo[t] = sc[t] - v;  // exclusive
    __syncthreads();
    int i = blockIdx.x * 256 + t;
    if (i < N) rowptr[1 + i] += bo[i >> 10];
    if (i == 0) rowptr[0] = 0;
}

// ---------------- level-2: single-writer CSR scatter ----------------
__global__ __launch_bounds__(256) void k_scatter2(const int2* __restrict__ eb,
                                                  const int* __restrict__ hist_g,
                                                  const int* __restrict__ rowptr,
                                                  int* __restrict__ csr_src,
                                                  int E, int nw, int N) {
    __shared__ int cur[WSZ];
    int w = blockIdx.x;
    int base = w << WB;
    int i0 = base + threadIdx.x, i1 = base + 256 + threadIdx.x;
    cur[threadIdx.x] = (i0 < N) ? rowptr[i0] : 0;
    cur[threadIdx.x + 256] = (i1 < N) ? rowptr[i1] : 0;
    __syncthreads();
    int s0 = hist_g[w * NJ1];
    int s1 = (w + 1 < nw) ? hist_g[(w + 1) * NJ1] : E;
    for (int i = s0 + threadIdx.x; i < s1; i += 256) {
        int2 e = eb[i];
        int pos = atomicAdd(&cur[e.y & (WSZ - 1)], 1);
        csr_src[pos] = e.x;
    }
}

// ---------------- fused prep: dinv, xs, counts, weight transpose ------------
__global__ __launch_bounds__(256) void k_prep(const int* __restrict__ deg,
                                              const float* __restrict__ x,
                                              const int* __restrict__ batch,
                                              const float* __restrict__ W1,
                                              const float* __restrict__ W2,
                                              const float* __restrict__ Wf1,
                                              const float* __restrict__ Wf2,
                                              float* __restrict__ dinv,
                                              float* __restrict__ xs,
                                              int* __restrict__ cnt,
                                              unsigned short* __restrict__ W1t,
                                              unsigned short* __restrict__ W2t,
                                              unsigned short* __restrict__ Wf1t,
                                              unsigned short* __restrict__ Wf2t, int N) {
    int t = blockIdx.x * 256 + threadIdx.x;
    if (t < N) {
        float dv = rsqrtf((float)deg[t] + 1.0f);
        dinv[t] = dv;
        #pragma unroll
        for (int k = 0; k < 9; ++k) xs[t * 9 + k] = x[t * 9 + k] * dv;
        atomicAdd(&cnt[batch[t]], 1);
    }
    if (t < 16384) {
        int n = t >> 7, k = t & 127;
        W1t[n * 128 + k] = f2bf(W1[k * 128 + n]);
        Wf1t[n * 128 + k] = f2bf(Wf1[k * 128 + n]);
    } else if (t < 32768) {
        int i = t - 16384, n = i >> 7, k = i & 127;
        W2t[n * 128 + k] = f2bf(W2[k * 128 + n]);
    } else if (t < 36864) {
        int i = t - 32768, n = i >> 7, k = i & 127;
        Wf2t[n * 128 + k] = f2bf(Wf2[k * 32 + n]);
    }
}

// ---------------- layer-1: aggregate xs (N x 9), output dinv-scaled ---------
__global__ __launch_bounds__(256) void k_aggx(const float* __restrict__ xs,
                                              const int* __restrict__ rowptr,
                                              const int* __restrict__ csr_src,
                                              const float* __restrict__ dinv,
                                              float* __restrict__ xa, int N) {
    int node = blockIdx.x * 16 + (threadIdx.x >> 4);
    if (node >= N) return;
    int lane = threadIdx.x & 15;
    bool act = lane < 9;
    int s = rowptr[node], e = rowptr[node + 1];
    float a0 = 0.0f, a1 = 0.0f, a2 = 0.0f, a3 = 0.0f;
    int i = s;
    for (; i + 4 <= e; i += 4) {
        int s0 = csr_src[i], s1 = csr_src[i + 1];
        int s2 = csr_src[i + 2], s3 = csr_src[i + 3];
        if (act) {
            a0 += xs[s0 * 9 + lane];
            a1 += xs[s1 * 9 + lane];
            a2 += xs[s2 * 9 + lane];
            a3 += xs[s3 * 9 + lane];
        }
    }
    for (; i < e; ++i) {
        int s0 = csr_src[i];
        if (act) a0 += xs[s0 * 9 + lane];
    }
    if (act) {
        float dv = dinv[node];
        xa[node * 9 + lane] = dv * (a0 + a1 + a2 + a3 + xs[node * 9 + lane]);
    }
}

// ---------------- layer-1 GEMM: bf16(tanh(xa @ W_in + b)) ----------------
__global__ void k_gemm_in9(const float* __restrict__ xa, const float* __restrict__ Wi,
                           const float* __restrict__ bi, unsigned short* __restrict__ T,
                           int N) {
    int t = blockIdx.x * 256 + threadIdx.x;
    if (t < N * U) {
        int n = t >> 7, c = t & 127;
        const float* xr = xa + n * 9;
        float acc = bi[c];
        #pragma unroll
        for (int k = 0; k < 9; ++k) acc += xr[k] * Wi[k * U + c];
        T[t] = f2bf(tanhf(acc));
    }
}

// ---------------- MFMA GEMM (LDS-free, barrier-free) ----------------
__global__ __launch_bounds__(256) void k_gemm_mfma(const unsigned short* __restrict__ A,
                                                   const unsigned short* __restrict__ Wt,
                                                   const float* __restrict__ dinv,
                                                   unsigned short* __restrict__ Out, int N) {
    const int tid = threadIdx.x;
    const int wave = tid >> 6, lane = tid & 63;
    const int m16 = lane & 15, q = lane >> 4;
    const int row0 = blockIdx.x * 64 + wave * 16;
    int arow_idx = row0 + m16;
    if (arow_idx >= N) arow_idx = N - 1;  // clamp; OOB outputs are guarded
    const bf16x8* arow = (const bf16x8*)(A + (size_t)arow_idx * U + q * 8);
    f32x4 acc[8];
    #pragma unroll
    for (int t = 0; t < 8; ++t) acc[t] = (f32x4){0.f, 0.f, 0.f, 0.f};
    #pragma unroll
    for (int kc = 0; kc < 4; ++kc) {
        bf16x8 af = arow[kc * 4];
        #pragma unroll
        for (int t = 0; t < 8; ++t) {
            bf16x8 bfr = *(const bf16x8*)(Wt + ((t * 16 + m16) * 128 + kc * 32 + q * 8));
            acc[t] = __builtin_amdgcn_mfma_f32_16x16x32_bf16(af, bfr, acc[t], 0, 0, 0);
        }
    }
    float dv[4];
    #pragma unroll
    for (int r = 0; r < 4; ++r) {
        int gr = row0 + q * 4 + r;
        dv[r] = (gr < N) ? dinv[gr] : 0.0f;
    }
    #pragma unroll
    for (int t = 0; t < 8; ++t) {
        #pragma unroll
        for (int r = 0; r < 4; ++r) {
            int gr = row0 + q * 4 + r;
            if (gr < N) Out[(size_t)gr * U + t * 16 + m16] = f2bf(acc[t][r] * dv[r]);
        }
    }
}

// ---------------- aggregation: h = tanh(dinv[d]*(sum Ts + Ts[d]) + b) -------
__global__ __launch_bounds__(256) void k_aggb(const unsigned short* __restrict__ Tb,
                                              const int* __restrict__ rowptr,
                                              const int* __restrict__ csr_src,
                                              const float* __restrict__ dinv,
                                              const float* __restrict__ bias,
                                              unsigned short* __restrict__ Out, int N) {
    int node = blockIdx.x * 4 + (threadIdx.x >> 6);
    if (node >= N) return;
    int lane = threadIdx.x & 63;
    const unsigned* T32 = (const unsigned*)Tb;
    float ax = 0.0f, ay = 0.0f, bx = 0.0f, by = 0.0f;
    int s = rowptr[node], e = rowptr[node + 1];
    int i = s;
    for (; i + 8 <= e; i += 8) {
        int idx[8];
        #pragma unroll
        for (int u = 0; u < 8; ++u) idx[u] = csr_src[i + u];
        unsigned uv[8];
        #pragma unroll
        for (int u = 0; u < 8; ++u) uv[u] = T32[idx[u] * 64 + lane];
        #pragma unroll
        for (int u = 0; u < 8; u += 2) {
            ax += bf_lo(uv[u]) + bf_lo(uv[u + 1]);
            ay += bf_hi(uv[u]) + bf_hi(uv[u + 1]);
        }
    }
    for (; i + 4 <= e; i += 4) {
        int s0 = csr_src[i], s1 = csr_src[i + 1];
        int s2 = csr_src[i + 2], s3 = csr_src[i + 3];
        unsigned u0 = T32[s0 * 64 + lane];
        unsigned u1 = T32[s1 * 64 + lane];
        unsigned u2 = T32[s2 * 64 + lane];
        unsigned u3 = T32[s3 * 64 + lane];
        ax += bf_lo(u0) + bf_lo(u1);
        ay += bf_hi(u0) + bf_hi(u1);
        bx += bf_lo(u2) + bf_lo(u3);
        by += bf_hi(u2) + bf_hi(u3);
    }
    for (; i < e; ++i) {
        int s0 = csr_src[i];
        unsigned u0 = T32[s0 * 64 + lane];
        ax += bf_lo(u0);
        ay += bf_hi(u0);
    }
    float dv = dinv[node];
    unsigned su = T32[node * 64 + lane];
    float2 bb = *(const float2*)&bias[lane * 2];
    float ox = tanhf(dv * (ax + bx + bf_lo(su)) + bb.x);
    float oy = tanhf(dv * (ay + by + bf_hi(su)) + bb.y);
    unsigned o = (unsigned)f2bf(ox) | ((unsigned)f2bf(oy) << 16);
    ((unsigned*)Out)[node * 64 + lane] = o;
}

// ---------------- fused MFMA MLP head v2 ----------------
// Register-resident weight frags (loaded once/wave); 4 tiles of 16 nodes per
// wave with A-prefetch; LDS-pooled graph atomics (block spans <=7 graphs).
__global__ __launch_bounds__(256, 2) void k_mlp(const unsigned short* __restrict__ H,
                                                const unsigned short* __restrict__ Wf1t,
                                                const float* __restrict__ bf1,
                                                const unsigned short* __restrict__ Wf2t,
                                                const float* __restrict__ bf2,
                                                const float* __restrict__ Wf3,
                                                const float* __restrict__ bf3,
                                                const int* __restrict__ batch,
                                                float* __restrict__ util_sum,
                                                int N, int G) {
    __shared__ unsigned short H2[4][16 * LDA];  // per-wave transpose slice
    __shared__ float gsum[8];
    const int tid = threadIdx.x;
    if (tid < 8) gsum[tid] = 0.0f;
    const int wave = tid >> 6, lane = tid & 63;
    const int m16 = lane & 15, q = lane >> 4;
    const int blk0 = blockIdx.x * 256;
    const int g0 = batch[min(blk0, N - 1)];
    // ---- load weight fragments once per wave ----
    bf16x8 w1[4][8], w2[4][2];
    #pragma unroll
    for (int kc = 0; kc < 4; ++kc) {
        #pragma unroll
        for (int t = 0; t < 8; ++t)
            w1[kc][t] = *(const bf16x8*)(Wf1t + ((t * 16 + m16) * 128 + kc * 32 + q * 8));
        #pragma unroll
        for (int t = 0; t < 2; ++t)
            w2[kc][t] = *(const bf16x8*)(Wf2t + ((t * 16 + m16) * 128 + kc * 32 + q * 8));
    }
    float b1v[8];
    #pragma unroll
    for (int t = 0; t < 8; ++t) b1v[t] = bf1[t * 16 + m16];
    const float b2lo = bf2[m16], b2hi = bf2[m16 + 16];
    const float w3lo = Wf3[m16], w3hi = Wf3[m16 + 16];
    const float bf3v = bf3[0];
    __syncthreads();  // gsum init visible before tile atomics
    unsigned short* h2s = H2[wave];
    const int wbase = blk0 + wave * 64;
    // prefetch tile 0 A-frags
    bf16x8 a[4];
    {
        int ar = wbase + m16;
        if (ar >= N) ar = N - 1;
        const bf16x8* arow = (const bf16x8*)(H + (size_t)ar * U + q * 8);
        #pragma unroll
        for (int kc = 0; kc < 4; ++kc) a[kc] = arow[kc * 4];
    }
    for (int tile = 0; tile < 4; ++tile) {
        const int row0 = wbase + tile * 16;
        // prefetch next tile
        bf16x8 an[4];
        if (tile < 3) {
            int ar = row0 + 16 + m16;
            if (ar >= N) ar = N - 1;
            const bf16x8* arow = (const bf16x8*)(H + (size_t)ar * U + q * 8);
            #pragma unroll
            for (int kc = 0; kc < 4; ++kc) an[kc] = arow[kc * 4];
        }
        // ---- layer 1: 128 -> 128 ----
        f32x4 acc[8];
        #pragma unroll
        for (int t = 0; t < 8; ++t) acc[t] = (f32x4){0.f, 0.f, 0.f, 0.f};
        #pragma unroll
        for (int kc = 0; kc < 4; ++kc) {
            #pragma unroll
            for (int t = 0; t < 8; ++t)
                acc[t] = __builtin_amdgcn_mfma_f32_16x16x32_bf16(a[kc], w1[kc][t], acc[t], 0, 0, 0);
        }
        #pragma unroll
        for (int t = 0; t < 8; ++t) {
            #pragma unroll
            for (int r = 0; r < 4; ++r) {
                int lr = q * 4 + r;
                h2s[lr * LDA + t * 16 + m16] = f2bf(tanhf(acc[t][r] + b1v[t]));
            }
        }
        // ---- layer 2: 128 -> 32 (wave-local LDS, in-order DS) ----
        f32x4 acc2[2];
        acc2[0] = (f32x4){0.f, 0.f, 0.f, 0.f};
        acc2[1] = (f32x4){0.f, 0.f, 0.f, 0.f};
        const unsigned short* h2row = h2s + m16 * LDA + q * 8;
        #pragma unroll
        for (int kc = 0; kc < 4; ++kc) {
            bf16x8 af = *(const bf16x8*)(h2row + kc * 32);
            #pragma unroll
            for (int t = 0; t < 2; ++t)
                acc2[t] = __builtin_amdgcn_mfma_f32_16x16x32_bf16(af, w2[kc][t], acc2[t], 0, 0, 0);
        }
        // ---- layer 3 + pooled LDS atomic ----
        #pragma unroll
        for (int r = 0; r < 4; ++r) {
            float t0 = tanhf(acc2[0][r] + b2lo);
            float t1 = tanhf(acc2[1][r] + b2hi);
            float v = t0 * w3lo + t1 * w3hi;
            v += __shfl_xor(v, 1);
            v += __shfl_xor(v, 2);
            v += __shfl_xor(v, 4);
            v += __shfl_xor(v, 8);
            if (m16 == 0) {
                int n = row0 + q * 4 + r;
                if (n < N) atomicAdd(&gsum[batch[n] - g0], v + bf3v);
            }
        }
        #pragma unroll
        for (int kc = 0; kc < 4; ++kc) a[kc] = an[kc];
    }
    __syncthreads();
    if (tid < 8) {
        int g = g0 + tid;
        if (g < G) {
            float s = gsum[tid];
            if (s != 0.0f) atomicAdd(&util_sum[g], s);
        }
    }
}

// ---------------- fused output: util + pair sigmoid ----------------
__global__ void k_out(const float* __restrict__ us, const int* __restrict__ cnt,
                      const int* __restrict__ ia, const int* __restrict__ ib,
                      float* __restrict__ out, int P, int G) {
    int t = blockIdx.x * 256 + threadIdx.x;
    if (t < G) out[P + t] = us[t] / fmaxf((float)cnt[t], 1.0f);
    if (t < P) {
        int a = ia[t], b = ib[t];
        float ua = us[a] / fmaxf((float)cnt[a], 1.0f);
        float ub = us[b] / fmaxf((float)cnt[b], 1.0f);
        out[t] = 1.0f / (1.0f + expf(-(ub - ua)));
    }
}

extern "C" void kernel_launch(void* const* d_in, const int* in_sizes, int n_in,
                              void* d_out, int out_size, void* d_ws, size_t ws_size,
                              hipStream_t stream) {
    const float* x     = (const float*)d_in[0];
    const int*   eidx  = (const int*)d_in[1];
    const int*   batch = (const int*)d_in[2];
    const int*   idx_a = (const int*)d_in[3];
    const int*   idx_b = (const int*)d_in[4];
    const float* W_in  = (const float*)d_in[5];
    const float* b_in  = (const float*)d_in[6];
    const float* W1    = (const float*)d_in[7];
    const float* b1    = (const float*)d_in[8];
    const float* W2    = (const float*)d_in[9];
    const float* b2    = (const float*)d_in[10];
    const float* Wf1   = (const float*)d_in[11];
    const float* bf1   = (const float*)d_in[12];
    const float* Wf2   = (const float*)d_in[13];
    const float* bf2   = (const float*)d_in[14];
    const float* Wf3   = (const float*)d_in[15];
    const float* bf3   = (const float*)d_in[16];
    float* out = (float*)d_out;

    const int N = in_sizes[0] / 9;
    const int E = in_sizes[1] / 2;
    const int P = in_sizes[3];
    const int G = out_size - P;

    const int* src = eidx;
    const int* dst = eidx + E;

    const int nw = (N + WSZ - 1) >> WB;  // level-2 windows (196 for N=100k)
    const int nb = (N + 1023) / 1024;
    const int nh = nw * NJ1;             // hist_g size
    const int nbh = (nh + 1023) / 1024;  // scan blocks for hist_g

    // ---- workspace carve-out ----
    char* ws = (char*)d_ws;
    size_t off = 0;
    auto take = [&](size_t bytes) -> void* {
        void* p = ws + off;
        off = (off + bytes + 255) & ~(size_t)255;
        return p;
    };
    int*   deg      = (int*)  take((size_t)N * 4);
    float* dinv     = (float*)take((size_t)N * 4);
    int*   rowptr   = (int*)  take((size_t)(N + 1) * 4);
    int*   bsum     = (int*)  take(256 * 4);
    int*   bsum2    = (int*)  take(256 * 4);
    int*   hist_g   = (int*)  take((size_t)nh * 4);
    int2*  eb       = (int2*) take((size_t)E * 8);
    int*   csr_src  = (int*)  take((size_t)E * 4);
    float* xs       = (float*)take((size_t)N * 9 * 4);
    float* xa       = (float*)take((size_t)N * 9 * 4);
    unsigned short* bufA = (unsigned short*)take((size_t)N * U * 2);  // bf16 acts
    unsigned short* Tb   = (unsigned short*)take((size_t)N * U * 2);  // bf16 table
    unsigned short* W1t  = (unsigned short*)take(128 * 128 * 2);
    unsigned short* W2t  = (unsigned short*)take(128 * 128 * 2);
    unsigned short* Wf1t = (unsigned short*)take(128 * 128 * 2);
    unsigned short* Wf2t = (unsigned short*)take(32 * 128 * 2);
    // zero-region: util_sum + cnt contiguous, single memset
    float* util_sum = (float*)take((size_t)G * 4 + (size_t)G * 4);
    int*   cnt      = (int*)(util_sum + G);
    (void)ws_size;

    hipMemsetAsync(util_sum, 0, (size_t)G * 8, stream);

    // ---- CSR build: two-level counting sort ----
    k_hist1<<<NJ1, 256, 0, stream>>>(dst, hist_g, E, nw);
    k_escan1<<<nbh, 256, 0, stream>>>(hist_g, bsum2, nh);
    k_escan2<<<nbh, 256, 0, stream>>>(hist_g, bsum2, nbh, nh);
    k_bucket<<<NJ1, 256, 0, stream>>>(src, dst, hist_g, eb, E, nw);
    k_deg2<<<nw, 256, 0, stream>>>(eb, hist_g, deg, E, nw, N);
    k_prep<<<(N + 255) / 256, 256, 0, stream>>>(deg, x, batch, W1, W2, Wf1, Wf2,
                                                dinv, xs, cnt, W1t, W2t, Wf1t, Wf2t, N);
    k_scan1<<<nb, 256, 0, stream>>>(deg, rowptr + 1, bsum, N);
    k_scan23<<<(N + 255) / 256, 256, 0, stream>>>(rowptr, bsum, nb, N);
    k_scatter2<<<nw, 256, 0, stream>>>(eb, hist_g, rowptr, csr_src, E, nw, N);

    const int aggGrid  = (N + 3) / 4;
    const int gemmGrid = (N + 63) / 64;

    // ---- GCN layer 1: aggregate xs (9-wide), then GEMM+bias+tanh -> bf16 ----
    k_aggx<<<(N + 15) / 16, 256, 0, stream>>>(xs, rowptr, csr_src, dinv, xa, N);
    k_gemm_in9<<<((size_t)N * U + 255) / 256, 256, 0, stream>>>(xa, W_in, b_in, bufA, N);

    // ---- GCN layer 2 ----
    k_gemm_mfma<<<gemmGrid, 256, 0, stream>>>(bufA, W1t, dinv, Tb, N);
    k_aggb<<<aggGrid, 256, 0, stream>>>(Tb, rowptr, csr_src, dinv, b1, bufA, N);
    // ---- GCN layer 3 ----
    k_gemm_mfma<<<gemmGrid, 256, 0, stream>>>(bufA, W2t, dinv, Tb, N);
    k_aggb<<<aggGrid, 256, 0, stream>>>(Tb, rowptr, csr_src, dinv, b2, bufA, N);

    // ---- MLP head + pooled sums (256 nodes/block) ----
    k_mlp<<<(N + 255) / 256, 256, 0, stream>>>(bufA, Wf1t, bf1, Wf2t, bf2, Wf3, bf3,
                                               batch, util_sum, N, G);

    // ---- fused util + pairs ----
    int mx = (P > G ? P : G);
    k_out<<<(mx + 255) / 256, 256, 0, stream>>>(util_sum, cnt, idx_a, idx_b, out, P, G);
}

// Round 10
// 458.720 us; speedup vs baseline: 2.2850x; 1.0395x over previous
//
#include <hip/hip_runtime.h>
#include <hip/hip_bf16.h>
#include <math.h>

// ---------------------------------------------------------------------------
// RankGNN R10: fp8-e4m3 neighbor table (halves aggb gather bytes; HW
// cvt_pk_f32_fp8 unpack); xs padded to 64B rows (line-exact layer-1 gather).
// Revert plan: if absmax > 1e-2, restore bf16 table (R9 k_aggb/k_gemm_mfma).
// ---------------------------------------------------------------------------

#define U 128
#define LDA 136    // LDS row stride in bf16 elems (128 + 8 pad)
#define WB 9       // log2(window) = 512 nodes per level-2 window
#define WSZ 512
#define NJ1 256    // level-1 blocks (edge chunks)

typedef __attribute__((ext_vector_type(8))) short bf16x8;
typedef __attribute__((ext_vector_type(4))) float f32x4;
typedef __attribute__((ext_vector_type(2))) float f32x2;

__device__ __forceinline__ unsigned short f2bf(float f) {
    unsigned u = __float_as_uint(f);
    unsigned r = (u + 0x7fffu + ((u >> 16) & 1u)) >> 16;  // RNE
    return (unsigned short)r;
}
__device__ __forceinline__ unsigned char f2fp8(float v) {
    return (unsigned char)(__builtin_amdgcn_cvt_pk_fp8_f32(v, v, 0, false) & 0xff);
}

// ---------------- level-1: per-chunk window histogram ----------------
__global__ __launch_bounds__(256) void k_hist1(const int* __restrict__ dst,
                                               int* __restrict__ hist_g, int E, int nw) {
    __shared__ int h[256];  // nw <= 256
    int b = blockIdx.x;
    for (int i = threadIdx.x; i < nw; i += 256) h[i] = 0;
    __syncthreads();
    int ch = (E + NJ1 - 1) / NJ1;
    int e0 = b * ch, e1 = min(e0 + ch, E);
    for (int e = e0 + threadIdx.x; e < e1; e += 256)
        atomicAdd(&h[dst[e] >> WB], 1);
    __syncthreads();
    for (int w = threadIdx.x; w < nw; w += 256) hist_g[w * NJ1 + b] = h[w];
}

// ---------------- generic parallel exclusive scan (in place) ----------------
__global__ __launch_bounds__(256) void k_escan1(int* __restrict__ a,
                                                int* __restrict__ bsum, int n) {
    __shared__ int sc[256];
    int t = threadIdx.x, b = blockIdx.x;
    int base = b * 1024 + t * 4;
    int v[4];
    int s = 0;
    #pragma unroll
    for (int j = 0; j < 4; ++j) {
        int idx = base + j;
        int d = (idx < n) ? a[idx] : 0;
        v[j] = s;  // exclusive within thread
        s += d;
    }
    sc[t] = s;
    __syncthreads();
    for (int off = 1; off < 256; off <<= 1) {
        int x = (t >= off) ? sc[t - off] : 0;
        __syncthreads();
        sc[t] += x;
        __syncthreads();
    }
    int excl = sc[t] - s;
    #pragma unroll
    for (int j = 0; j < 4; ++j) {
        int idx = base + j;
        if (idx < n) a[idx] = v[j] + excl;
    }
    if (t == 255) bsum[b] = sc[255];
}

__global__ __launch_bounds__(256) void k_escan2(int* __restrict__ a,
                                                const int* __restrict__ bsum,
                                                int nb, int n) {
    __shared__ int sc[256];
    int t = threadIdx.x;
    int v = (t < nb) ? bsum[t] : 0;
    sc[t] = v;
    __syncthreads();
    for (int off = 1; off < 256; off <<= 1) {
        int u = (t >= off) ? sc[t - off] : 0;
        __syncthreads();
        sc[t] += u;
        __syncthreads();
    }
    int myoff = (blockIdx.x > 0) ? (sc[blockIdx.x] - bsum[blockIdx.x]) : 0;
    int base = blockIdx.x * 1024;
    #pragma unroll
    for (int j = 0; j < 4; ++j) {
        int idx = base + t + j * 256;
        if (idx < n) a[idx] += myoff;
    }
}

// ---------------- level-1: bucket edges window-major ----------------
__global__ __launch_bounds__(256) void k_bucket(const int* __restrict__ src,
                                                const int* __restrict__ dst,
                                                const int* __restrict__ hist_g,
                                                int2* __restrict__ eb, int E, int nw) {
    __shared__ int lcur[256];
    int b = blockIdx.x;
    for (int w = threadIdx.x; w < nw; w += 256) lcur[w] = hist_g[w * NJ1 + b];
    __syncthreads();
    int ch = (E + NJ1 - 1) / NJ1;
    int e0 = b * ch, e1 = min(e0 + ch, E);
    for (int e = e0 + threadIdx.x; e < e1; e += 256) {
        int d = dst[e];
        int pos = atomicAdd(&lcur[d >> WB], 1);
        eb[pos] = make_int2(src[e], d);
    }
}

// ---------------- level-2: per-window degree histogram -> deg ---------------
__global__ __launch_bounds__(256) void k_deg2(const int2* __restrict__ eb,
                                              const int* __restrict__ hist_g,
                                              int* __restrict__ deg, int E, int nw, int N) {
    __shared__ int h[WSZ];
    int w = blockIdx.x;
    h[threadIdx.x] = 0;
    h[threadIdx.x + 256] = 0;
    __syncthreads();
    int s0 = hist_g[w * NJ1];
    int s1 = (w + 1 < nw) ? hist_g[(w + 1) * NJ1] : E;
    for (int i = s0 + threadIdx.x; i < s1; i += 256)
        atomicAdd(&h[eb[i].y & (WSZ - 1)], 1);
    __syncthreads();
    int base = w << WB;
    if (base + threadIdx.x < N) deg[base + threadIdx.x] = h[threadIdx.x];
    if (base + 256 + threadIdx.x < N) deg[base + 256 + threadIdx.x] = h[256 + threadIdx.x];
}

// ---------------- rowptr scan ----------------
__global__ __launch_bounds__(256) void k_scan1(const int* __restrict__ deg,
                                               int* __restrict__ rowptr1,
                                               int* __restrict__ bsum, int N) {
    __shared__ int sc[256];
    int t = threadIdx.x, b = blockIdx.x;
    int base = b * 1024 + t * 4;
    int v[4];
    int s = 0;
    #pragma unroll
    for (int j = 0; j < 4; ++j) {
        int idx = base + j;
        int d = (idx < N) ? deg[idx] : 0;
        s += d;
        v[j] = s;
    }
    sc[t] = s;
    __syncthreads();
    for (int off = 1; off < 256; off <<= 1) {
        int x = (t >= off) ? sc[t - off] : 0;
        __syncthreads();
        sc[t] += x;
        __syncthreads();
    }
    int excl = sc[t] - s;
    #pragma unroll
    for (int j = 0; j < 4; ++j) {
        int idx = base + j;
        if (idx < N) rowptr1[idx] = v[j] + excl;
    }
    if (t == 255) bsum[b] = sc[255];
}

__global__ __launch_bounds__(256) void k_scan23(int* __restrict__ rowptr,
                                                const int* __restrict__ bsum,
                                                int nb, int N) {
    __shared__ int sc[256];
    __shared__ int bo[256];
    int t = threadIdx.x;
    int v = (t < nb) ? bsum[t] : 0;
    sc[t] = v;
    __syncthreads();
    for (int off = 1; off < 256; off <<= 1) {
        int u = (t >= off) ? sc[t - off] : 0;
        __syncthreads();
        sc[t] += u;
        __syncthreads();
    }
    bo[t] = sc[t] - v;  // exclusive
    __syncthreads();
    int i = blockIdx.x * 256 + t;
    if (i < N) rowptr[1 + i] += bo[i >> 10];
    if (i == 0) rowptr[0] = 0;
}

// ---------------- level-2: single-writer CSR scatter ----------------
__global__ __launch_bounds__(256) void k_scatter2(const int2* __restrict__ eb,
                                                  const int* __restrict__ hist_g,
                                                  const int* __restrict__ rowptr,
                                                  int* __restrict__ csr_src,
                                                  int E, int nw, int N) {
    __shared__ int cur[WSZ];
    int w = blockIdx.x;
    int base = w << WB;
    int i0 = base + threadIdx.x, i1 = base + 256 + threadIdx.x;
    cur[threadIdx.x] = (i0 < N) ? rowptr[i0] : 0;
    cur[threadIdx.x + 256] = (i1 < N) ? rowptr[i1] : 0;
    __syncthreads();
    int s0 = hist_g[w * NJ1];
    int s1 = (w + 1 < nw) ? hist_g[(w + 1) * NJ1] : E;
    for (int i = s0 + threadIdx.x; i < s1; i += 256) {
        int2 e = eb[i];
        int pos = atomicAdd(&cur[e.y & (WSZ - 1)], 1);
        csr_src[pos] = e.x;
    }
}

// ---------------- fused prep: dinv, xs (64B rows), counts, weights ----------
__global__ __launch_bounds__(256) void k_prep(const int* __restrict__ deg,
                                              const float* __restrict__ x,
                                              const int* __restrict__ batch,
                                              const float* __restrict__ W1,
                                              const float* __restrict__ W2,
                                              const float* __restrict__ Wf1,
                                              const float* __restrict__ Wf2,
                                              float* __restrict__ dinv,
                                              float* __restrict__ xs,
                                              int* __restrict__ cnt,
                                              unsigned short* __restrict__ W1t,
                                              unsigned short* __restrict__ W2t,
                                              unsigned short* __restrict__ Wf1t,
                                              unsigned short* __restrict__ Wf2t, int N) {
    int t = blockIdx.x * 256 + threadIdx.x;
    if (t < N) {
        float dv = rsqrtf((float)deg[t] + 1.0f);
        dinv[t] = dv;
        #pragma unroll
        for (int k = 0; k < 9; ++k) xs[t * 16 + k] = x[t * 9 + k] * dv;
        #pragma unroll
        for (int k = 9; k < 16; ++k) xs[t * 16 + k] = 0.0f;
        atomicAdd(&cnt[batch[t]], 1);
    }
    if (t < 16384) {
        int n = t >> 7, k = t & 127;
        W1t[n * 128 + k] = f2bf(W1[k * 128 + n]);
        Wf1t[n * 128 + k] = f2bf(Wf1[k * 128 + n]);
    } else if (t < 32768) {
        int i = t - 16384, n = i >> 7, k = i & 127;
        W2t[n * 128 + k] = f2bf(W2[k * 128 + n]);
    } else if (t < 36864) {
        int i = t - 32768, n = i >> 7, k = i & 127;
        Wf2t[n * 128 + k] = f2bf(Wf2[k * 32 + n]);
    }
}

// ---------------- layer-1: aggregate xs (64B rows), output dinv-scaled ------
__global__ __launch_bounds__(256) void k_aggx(const float* __restrict__ xs,
                                              const int* __restrict__ rowptr,
                                              const int* __restrict__ csr_src,
                                              const float* __restrict__ dinv,
                                              float* __restrict__ xa, int N) {
    int node = blockIdx.x * 16 + (threadIdx.x >> 4);
    if (node >= N) return;
    int lane = threadIdx.x & 15;
    int s = rowptr[node], e = rowptr[node + 1];
    float a0 = 0.0f, a1 = 0.0f, a2 = 0.0f, a3 = 0.0f;
    int i = s;
    for (; i + 4 <= e; i += 4) {
        int s0 = csr_src[i], s1 = csr_src[i + 1];
        int s2 = csr_src[i + 2], s3 = csr_src[i + 3];
        a0 += xs[s0 * 16 + lane];
        a1 += xs[s1 * 16 + lane];
        a2 += xs[s2 * 16 + lane];
        a3 += xs[s3 * 16 + lane];
    }
    for (; i < e; ++i) {
        int s0 = csr_src[i];
        a0 += xs[s0 * 16 + lane];
    }
    if (lane < 9) {
        float dv = dinv[node];
        xa[node * 9 + lane] = dv * (a0 + a1 + a2 + a3 + xs[node * 16 + lane]);
    }
}

// ---------------- layer-1 GEMM: bf16(tanh(xa @ W_in + b)) ----------------
__global__ void k_gemm_in9(const float* __restrict__ xa, const float* __restrict__ Wi,
                           const float* __restrict__ bi, unsigned short* __restrict__ T,
                           int N) {
    int t = blockIdx.x * 256 + threadIdx.x;
    if (t < N * U) {
        int n = t >> 7, c = t & 127;
        const float* xr = xa + n * 9;
        float acc = bi[c];
        #pragma unroll
        for (int k = 0; k < 9; ++k) acc += xr[k] * Wi[k * U + c];
        T[t] = f2bf(tanhf(acc));
    }
}

// ---------------- MFMA GEMM -> fp8 table: Ts = fp8(dinv * (A @ Wt^T)) -------
__global__ __launch_bounds__(256) void k_gemm_mfma(const unsigned short* __restrict__ A,
                                                   const unsigned short* __restrict__ Wt,
                                                   const float* __restrict__ dinv,
                                                   unsigned char* __restrict__ Out, int N) {
    const int tid = threadIdx.x;
    const int wave = tid >> 6, lane = tid & 63;
    const int m16 = lane & 15, q = lane >> 4;
    const int row0 = blockIdx.x * 64 + wave * 16;
    int arow_idx = row0 + m16;
    if (arow_idx >= N) arow_idx = N - 1;  // clamp; OOB outputs are guarded
    const bf16x8* arow = (const bf16x8*)(A + (size_t)arow_idx * U + q * 8);
    f32x4 acc[8];
    #pragma unroll
    for (int t = 0; t < 8; ++t) acc[t] = (f32x4){0.f, 0.f, 0.f, 0.f};
    #pragma unroll
    for (int kc = 0; kc < 4; ++kc) {
        bf16x8 af = arow[kc * 4];
        #pragma unroll
        for (int t = 0; t < 8; ++t) {
            bf16x8 bfr = *(const bf16x8*)(Wt + ((t * 16 + m16) * 128 + kc * 32 + q * 8));
            acc[t] = __builtin_amdgcn_mfma_f32_16x16x32_bf16(af, bfr, acc[t], 0, 0, 0);
        }
    }
    float dv[4];
    #pragma unroll
    for (int r = 0; r < 4; ++r) {
        int gr = row0 + q * 4 + r;
        dv[r] = (gr < N) ? dinv[gr] : 0.0f;
    }
    #pragma unroll
    for (int t = 0; t < 8; ++t) {
        #pragma unroll
        for (int r = 0; r < 4; ++r) {
            int gr = row0 + q * 4 + r;
            if (gr < N) Out[(size_t)gr * U + t * 16 + m16] = f2fp8(acc[t][r] * dv[r]);
        }
    }
}

// ---------------- aggregation (fp8 table): h = tanh(dinv*(sum+self)+b) ------
// 1 node/wave; lane loads ushort (2 fp8 feats), HW cvt_pk_f32_fp8 unpack.
__global__ __launch_bounds__(256) void k_aggb(const unsigned char* __restrict__ Tb,
                                              const int* __restrict__ rowptr,
                                              const int* __restrict__ csr_src,
                                              const float* __restrict__ dinv,
                                              const float* __restrict__ bias,
                                              unsigned short* __restrict__ Out, int N) {
    int node = blockIdx.x * 4 + (threadIdx.x >> 6);
    if (node >= N) return;
    int lane = threadIdx.x & 63;
    const unsigned short* T16 = (const unsigned short*)Tb;
    float ax = 0.0f, ay = 0.0f, bx = 0.0f, by = 0.0f;
    int s = rowptr[node], e = rowptr[node + 1];
    int i = s;
    for (; i + 8 <= e; i += 8) {
        int idx[8];
        #pragma unroll
        for (int u = 0; u < 8; ++u) idx[u] = csr_src[i + u];
        unsigned uv[8];
        #pragma unroll
        for (int u = 0; u < 8; ++u) uv[u] = T16[idx[u] * 64 + lane];
        #pragma unroll
        for (int u = 0; u < 8; u += 2) {
            f32x2 f0 = __builtin_amdgcn_cvt_pk_f32_fp8(uv[u], false);
            f32x2 f1 = __builtin_amdgcn_cvt_pk_f32_fp8(uv[u + 1], false);
            ax += f0[0] + f1[0];
            ay += f0[1] + f1[1];
        }
    }
    for (; i + 4 <= e; i += 4) {
        int s0 = csr_src[i], s1 = csr_src[i + 1];
        int s2 = csr_src[i + 2], s3 = csr_src[i + 3];
        f32x2 f0 = __builtin_amdgcn_cvt_pk_f32_fp8((unsigned)T16[s0 * 64 + lane], false);
        f32x2 f1 = __builtin_amdgcn_cvt_pk_f32_fp8((unsigned)T16[s1 * 64 + lane], false);
        f32x2 f2 = __builtin_amdgcn_cvt_pk_f32_fp8((unsigned)T16[s2 * 64 + lane], false);
        f32x2 f3 = __builtin_amdgcn_cvt_pk_f32_fp8((unsigned)T16[s3 * 64 + lane], false);
        ax += f0[0] + f1[0];
        ay += f0[1] + f1[1];
        bx += f2[0] + f3[0];
        by += f2[1] + f3[1];
    }
    for (; i < e; ++i) {
        int s0 = csr_src[i];
        f32x2 f0 = __builtin_amdgcn_cvt_pk_f32_fp8((unsigned)T16[s0 * 64 + lane], false);
        ax += f0[0];
        ay += f0[1];
    }
    float dv = dinv[node];
    f32x2 fs = __builtin_amdgcn_cvt_pk_f32_fp8((unsigned)T16[node * 64 + lane], false);
    float2 bb = *(const float2*)&bias[lane * 2];
    float ox = tanhf(dv * (ax + bx + fs[0]) + bb.x);
    float oy = tanhf(dv * (ay + by + fs[1]) + bb.y);
    unsigned o = (unsigned)f2bf(ox) | ((unsigned)f2bf(oy) << 16);
    ((unsigned*)Out)[node * 64 + lane] = o;
}

// ---------------- fused MFMA MLP head v2 (as R9) ----------------
__global__ __launch_bounds__(256, 2) void k_mlp(const unsigned short* __restrict__ H,
                                                const unsigned short* __restrict__ Wf1t,
                                                const float* __restrict__ bf1,
                                                const unsigned short* __restrict__ Wf2t,
                                                const float* __restrict__ bf2,
                                                const float* __restrict__ Wf3,
                                                const float* __restrict__ bf3,
                                                const int* __restrict__ batch,
                                                float* __restrict__ util_sum,
                                                int N, int G) {
    __shared__ unsigned short H2[4][16 * LDA];  // per-wave transpose slice
    __shared__ float gsum[8];
    const int tid = threadIdx.x;
    if (tid < 8) gsum[tid] = 0.0f;
    const int wave = tid >> 6, lane = tid & 63;
    const int m16 = lane & 15, q = lane >> 4;
    const int blk0 = blockIdx.x * 256;
    const int g0 = batch[min(blk0, N - 1)];
    bf16x8 w1[4][8], w2[4][2];
    #pragma unroll
    for (int kc = 0; kc < 4; ++kc) {
        #pragma unroll
        for (int t = 0; t < 8; ++t)
            w1[kc][t] = *(const bf16x8*)(Wf1t + ((t * 16 + m16) * 128 + kc * 32 + q * 8));
        #pragma unroll
        for (int t = 0; t < 2; ++t)
            w2[kc][t] = *(const bf16x8*)(Wf2t + ((t * 16 + m16) * 128 + kc * 32 + q * 8));
    }
    float b1v[8];
    #pragma unroll
    for (int t = 0; t < 8; ++t) b1v[t] = bf1[t * 16 + m16];
    const float b2lo = bf2[m16], b2hi = bf2[m16 + 16];
    const float w3lo = Wf3[m16], w3hi = Wf3[m16 + 16];
    const float bf3v = bf3[0];
    __syncthreads();  // gsum init visible before tile atomics
    unsigned short* h2s = H2[wave];
    const int wbase = blk0 + wave * 64;
    bf16x8 a[4];
    {
        int ar = wbase + m16;
        if (ar >= N) ar = N - 1;
        const bf16x8* arow = (const bf16x8*)(H + (size_t)ar * U + q * 8);
        #pragma unroll
        for (int kc = 0; kc < 4; ++kc) a[kc] = arow[kc * 4];
    }
    for (int tile = 0; tile < 4; ++tile) {
        const int row0 = wbase + tile * 16;
        bf16x8 an[4];
        if (tile < 3) {
            int ar = row0 + 16 + m16;
            if (ar >= N) ar = N - 1;
            const bf16x8* arow = (const bf16x8*)(H + (size_t)ar * U + q * 8);
            #pragma unroll
            for (int kc = 0; kc < 4; ++kc) an[kc] = arow[kc * 4];
        }
        f32x4 acc[8];
        #pragma unroll
        for (int t = 0; t < 8; ++t) acc[t] = (f32x4){0.f, 0.f, 0.f, 0.f};
        #pragma unroll
        for (int kc = 0; kc < 4; ++kc) {
            #pragma unroll
            for (int t = 0; t < 8; ++t)
                acc[t] = __builtin_amdgcn_mfma_f32_16x16x32_bf16(a[kc], w1[kc][t], acc[t], 0, 0, 0);
        }
        #pragma unroll
        for (int t = 0; t < 8; ++t) {
            #pragma unroll
            for (int r = 0; r < 4; ++r) {
                int lr = q * 4 + r;
                h2s[lr * LDA + t * 16 + m16] = f2bf(tanhf(acc[t][r] + b1v[t]));
            }
        }
        f32x4 acc2[2];
        acc2[0] = (f32x4){0.f, 0.f, 0.f, 0.f};
        acc2[1] = (f32x4){0.f, 0.f, 0.f, 0.f};
        const unsigned short* h2row = h2s + m16 * LDA + q * 8;
        #pragma unroll
        for (int kc = 0; kc < 4; ++kc) {
            bf16x8 af = *(const bf16x8*)(h2row + kc * 32);
            #pragma unroll
            for (int t = 0; t < 2; ++t)
                acc2[t] = __builtin_amdgcn_mfma_f32_16x16x32_bf16(af, w2[kc][t], acc2[t], 0, 0, 0);
        }
        #pragma unroll
        for (int r = 0; r < 4; ++r) {
            float t0 = tanhf(acc2[0][r] + b2lo);
            float t1 = tanhf(acc2[1][r] + b2hi);
            float v = t0 * w3lo + t1 * w3hi;
            v += __shfl_xor(v, 1);
            v += __shfl_xor(v, 2);
            v += __shfl_xor(v, 4);
            v += __shfl_xor(v, 8);
            if (m16 == 0) {
                int n = row0 + q * 4 + r;
                if (n < N) atomicAdd(&gsum[batch[n] - g0], v + bf3v);
            }
        }
        #pragma unroll
        for (int kc = 0; kc < 4; ++kc) a[kc] = an[kc];
    }
    __syncthreads();
    if (tid < 8) {
        int g = g0 + tid;
        if (g < G) {
            float s = gsum[tid];
            if (s != 0.0f) atomicAdd(&util_sum[g], s);
        }
    }
}

// ---------------- fused output: util + pair sigmoid ----------------
__global__ void k_out(const float* __restrict__ us, const int* __restrict__ cnt,
                      const int* __restrict__ ia, const int* __restrict__ ib,
                      float* __restrict__ out, int P, int G) {
    int t = blockIdx.x * 256 + threadIdx.x;
    if (t < G) out[P + t] = us[t] / fmaxf((float)cnt[t], 1.0f);
    if (t < P) {
        int a = ia[t], b = ib[t];
        float ua = us[a] / fmaxf((float)cnt[a], 1.0f);
        float ub = us[b] / fmaxf((float)cnt[b], 1.0f);
        out[t] = 1.0f / (1.0f + expf(-(ub - ua)));
    }
}

extern "C" void kernel_launch(void* const* d_in, const int* in_sizes, int n_in,
                              void* d_out, int out_size, void* d_ws, size_t ws_size,
                              hipStream_t stream) {
    const float* x     = (const float*)d_in[0];
    const int*   eidx  = (const int*)d_in[1];
    const int*   batch = (const int*)d_in[2];
    const int*   idx_a = (const int*)d_in[3];
    const int*   idx_b = (const int*)d_in[4];
    const float* W_in  = (const float*)d_in[5];
    const float* b_in  = (const float*)d_in[6];
    const float* W1    = (const float*)d_in[7];
    const float* b1    = (const float*)d_in[8];
    const float* W2    = (const float*)d_in[9];
    const float* b2    = (const float*)d_in[10];
    const float* Wf1   = (const float*)d_in[11];
    const float* bf1   = (const float*)d_in[12];
    const float* Wf2   = (const float*)d_in[13];
    const float* bf2   = (const float*)d_in[14];
    const float* Wf3   = (const float*)d_in[15];
    const float* bf3   = (const float*)d_in[16];
    float* out = (float*)d_out;

    const int N = in_sizes[0] / 9;
    const int E = in_sizes[1] / 2;
    const int P = in_sizes[3];
    const int G = out_size - P;

    const int* src = eidx;
    const int* dst = eidx + E;

    const int nw = (N + WSZ - 1) >> WB;  // level-2 windows (196 for N=100k)
    const int nb = (N + 1023) / 1024;
    const int nh = nw * NJ1;             // hist_g size
    const int nbh = (nh + 1023) / 1024;  // scan blocks for hist_g

    // ---- workspace carve-out ----
    char* ws = (char*)d_ws;
    size_t off = 0;
    auto take = [&](size_t bytes) -> void* {
        void* p = ws + off;
        off = (off + bytes + 255) & ~(size_t)255;
        return p;
    };
    int*   deg      = (int*)  take((size_t)N * 4);
    float* dinv     = (float*)take((size_t)N * 4);
    int*   rowptr   = (int*)  take((size_t)(N + 1) * 4);
    int*   bsum     = (int*)  take(256 * 4);
    int*   bsum2    = (int*)  take(256 * 4);
    int*   hist_g   = (int*)  take((size_t)nh * 4);
    int2*  eb       = (int2*) take((size_t)E * 8);
    int*   csr_src  = (int*)  take((size_t)E * 4);
    float* xs       = (float*)take((size_t)N * 16 * 4);  // 64B-padded rows
    float* xa       = (float*)take((size_t)N * 9 * 4);
    unsigned short* bufA = (unsigned short*)take((size_t)N * U * 2);  // bf16 acts
    unsigned char*  Tb   = (unsigned char*) take((size_t)N * U);      // fp8 table
    unsigned short* W1t  = (unsigned short*)take(128 * 128 * 2);
    unsigned short* W2t  = (unsigned short*)take(128 * 128 * 2);
    unsigned short* Wf1t = (unsigned short*)take(128 * 128 * 2);
    unsigned short* Wf2t = (unsigned short*)take(32 * 128 * 2);
    // zero-region: util_sum + cnt contiguous, single memset
    float* util_sum = (float*)take((size_t)G * 4 + (size_t)G * 4);
    int*   cnt      = (int*)(util_sum + G);
    (void)ws_size;

    hipMemsetAsync(util_sum, 0, (size_t)G * 8, stream);

    // ---- CSR build: two-level counting sort ----
    k_hist1<<<NJ1, 256, 0, stream>>>(dst, hist_g, E, nw);
    k_escan1<<<nbh, 256, 0, stream>>>(hist_g, bsum2, nh);
    k_escan2<<<nbh, 256, 0, stream>>>(hist_g, bsum2, nbh, nh);
    k_bucket<<<NJ1, 256, 0, stream>>>(src, dst, hist_g, eb, E, nw);
    k_deg2<<<nw, 256, 0, stream>>>(eb, hist_g, deg, E, nw, N);
    k_prep<<<(N + 255) / 256, 256, 0, stream>>>(deg, x, batch, W1, W2, Wf1, Wf2,
                                                dinv, xs, cnt, W1t, W2t, Wf1t, Wf2t, N);
    k_scan1<<<nb, 256, 0, stream>>>(deg, rowptr + 1, bsum, N);
    k_scan23<<<(N + 255) / 256, 256, 0, stream>>>(rowptr, bsum, nb, N);
    k_scatter2<<<nw, 256, 0, stream>>>(eb, hist_g, rowptr, csr_src, E, nw, N);

    const int aggGrid  = (N + 3) / 4;
    const int gemmGrid = (N + 63) / 64;

    // ---- GCN layer 1: aggregate xs (64B rows), then GEMM+bias+tanh -> bf16 --
    k_aggx<<<(N + 15) / 16, 256, 0, stream>>>(xs, rowptr, csr_src, dinv, xa, N);
    k_gemm_in9<<<((size_t)N * U + 255) / 256, 256, 0, stream>>>(xa, W_in, b_in, bufA, N);

    // ---- GCN layer 2 ----
    k_gemm_mfma<<<gemmGrid, 256, 0, stream>>>(bufA, W1t, dinv, Tb, N);
    k_aggb<<<aggGrid, 256, 0, stream>>>(Tb, rowptr, csr_src, dinv, b1, bufA, N);
    // ---- GCN layer 3 ----
    k_gemm_mfma<<<gemmGrid, 256, 0, stream>>>(bufA, W2t, dinv, Tb, N);
    k_aggb<<<aggGrid, 256, 0, stream>>>(Tb, rowptr, csr_src, dinv, b2, bufA, N);

    // ---- MLP head + pooled sums (256 nodes/block) ----
    k_mlp<<<(N + 255) / 256, 256, 0, stream>>>(bufA, Wf1t, bf1, Wf2t, bf2, Wf3, bf3,
                                               batch, util_sum, N, G);

    // ---- fused util + pairs ----
    int mx = (P > G ? P : G);
    k_out<<<(mx + 255) / 256, 256, 0, stream>>>(util_sum, cnt, idx_a, idx_b, out, P, G);
}